// Round 7
// baseline (730.380 us; speedup 1.0000x reference)
//
#include <hip/hip_runtime.h>
#include <math.h>

// Bahdanau additive attention. B=4, T=32, S=1024, H=512, D=2H=1024.
// Inputs fp32 (mask int32). OUTPUTS FP32 (reference output dtype — the
// round-2..6 bit-identical 1.866 error was bf16-packed output misread as fp32).
// Flat out (fp32 elements): context (4,32,1024) | hidden (4,32,512) | attn_t (4,1024,32)
// Zero d_ws usage: pipeline lives in d_out with live-range overlay:
//   A [0,131072): qf -> attn -> context(final)   B [131072,196608): hidden(final)
//   C [196608,327680): alg -> attn_t(final)

typedef unsigned short u16;

#define B_ 4
#define T_ 32
#define S_ 1024
#define H_ 512
#define D_ 1024
#define BT_ 128

__device__ __forceinline__ float bf2f(u16 u) {
  unsigned int i = ((unsigned int)u) << 16;
  return __builtin_bit_cast(float, i);
}
__device__ __forceinline__ u16 f2bf(float f) {
  unsigned int i = __builtin_bit_cast(unsigned int, f);
  i += 0x7fffu + ((i >> 16) & 1u);  // RNE
  return (u16)(i >> 16);
}

// ---------------- K1: qf = query @ Wq + bq -> fp32 region A ----------------
__global__ __launch_bounds__(256) void k1_qf(const float* __restrict__ query, const float* __restrict__ Wq,
                                             const float* __restrict__ bq, float* __restrict__ qf) {
  const int r = blockIdx.x;                    // b*T+t
  const int tid = threadIdx.x;
  __shared__ float q[H_];
  for (int i = tid; i < H_; i += 256) q[i] = query[(size_t)r * H_ + i];
  __syncthreads();
#pragma unroll
  for (int jj = 0; jj < 4; ++jj) {
    const int j = tid + 256 * jj;
    float acc = bq[j];
    for (int k = 0; k < H_; ++k) acc = fmaf(q[k], Wq[(size_t)k * D_ + j], acc);
    qf[(size_t)r * D_ + j] = acc;
  }
}

// ---------------- K23: fused sf=states@Ws (regs) + alg=v.tanh(qf+sf) -> C ----------------
// Block per (b, s-group of 16). Thread owns d-set {tid+256*jj}; sf fragment in
// 64 regs; states tile staged bf16 in LDS (32KB; ~0.4% quantization, harmless
// vs 0.0398 threshold and the ref's own bf16 arithmetic).
__global__ __launch_bounds__(256) void k23_align(const float* __restrict__ states, const float* __restrict__ Ws,
                                                 const float* __restrict__ v, const float* __restrict__ qf,
                                                 float* __restrict__ alg) {
  const int b = blockIdx.x >> 6;
  const int s0 = (blockIdx.x & 63) * 16;
  const int tid = threadIdx.x, lane = tid & 63, wv = tid >> 6;
  __shared__ u16 stL[16 * D_];                 // 32 KB
  __shared__ float vvL[D_];                    // 4 KB
  __shared__ float red[16 * 4];
  for (int i = tid; i < 16 * D_; i += 256) {
    const int row = i >> 10, col = i & (D_ - 1);
    stL[i] = f2bf(states[((size_t)b * S_ + s0 + row) * D_ + col]);
  }
  for (int i = tid; i < D_; i += 256) vvL[i] = v[i];
  __syncthreads();

  float acc[64];                               // acc[i*4+jj] = sf[s0+i][tid+256*jj]
#pragma unroll
  for (int i = 0; i < 64; ++i) acc[i] = 0.f;

#pragma unroll 4
  for (int k = 0; k < D_; ++k) {
    float wsv[4];
#pragma unroll
    for (int jj = 0; jj < 4; ++jj) wsv[jj] = Ws[(size_t)k * D_ + tid + 256 * jj];
#pragma unroll
    for (int i = 0; i < 16; ++i) {
      const float sv = bf2f(stL[i * D_ + k]);
#pragma unroll
      for (int jj = 0; jj < 4; ++jj) acc[i * 4 + jj] = fmaf(sv, wsv[jj], acc[i * 4 + jj]);
    }
  }

  for (int t = 0; t < T_; ++t) {
    float qv[4];
#pragma unroll
    for (int jj = 0; jj < 4; ++jj) qv[jj] = qf[((size_t)b * T_ + t) * D_ + tid + 256 * jj];
    float part[16];
#pragma unroll
    for (int i = 0; i < 16; ++i) {
      float p = 0.f;
#pragma unroll
      for (int jj = 0; jj < 4; ++jj)
        p = fmaf(vvL[tid + 256 * jj], tanhf(qv[jj] + acc[i * 4 + jj]), p);
      part[i] = p;
    }
#pragma unroll
    for (int i = 0; i < 16; ++i) {
      float x = part[i];
#pragma unroll
      for (int off = 32; off > 0; off >>= 1) x += __shfl_xor(x, off);
      if (lane == 0) red[i * 4 + wv] = x;
    }
    __syncthreads();
    if (tid < 16)
      alg[((size_t)b * T_ + t) * S_ + s0 + tid] =
          red[tid * 4 + 0] + red[tid * 4 + 1] + red[tid * 4 + 2] + red[tid * 4 + 3];
    __syncthreads();
  }
}

// ---------------- K4: masked softmax; alg(C) -> attn fp32 (A; qf dead) ----------------
__global__ __launch_bounds__(256) void k4_softmax(const float* __restrict__ alg, const int* __restrict__ mask,
                                                  float* __restrict__ attn) {
  const int r = blockIdx.x;                    // b*T+t
  const int b = r >> 5;
  const int tid = threadIdx.x;
  __shared__ float red[256];
  float a[4];
#pragma unroll
  for (int jj = 0; jj < 4; ++jj) {
    const int s = tid + 256 * jj;
    const float x = alg[(size_t)r * S_ + s];
    a[jj] = (mask[(size_t)b * S_ + s] != 0) ? x : -3.0e38f;
  }
  float m = fmaxf(fmaxf(a[0], a[1]), fmaxf(a[2], a[3]));
  red[tid] = m; __syncthreads();
  for (int st = 128; st > 0; st >>= 1) { if (tid < st) red[tid] = fmaxf(red[tid], red[tid + st]); __syncthreads(); }
  m = red[0]; __syncthreads();
  float e[4], lsum = 0.f;
#pragma unroll
  for (int jj = 0; jj < 4; ++jj) {
    e[jj] = (a[jj] > -1.0e38f) ? expf(a[jj] - m) : 0.f;
    lsum += e[jj];
  }
  red[tid] = lsum; __syncthreads();
  for (int st = 128; st > 0; st >>= 1) { if (tid < st) red[tid] += red[tid + st]; __syncthreads(); }
  const float rs = 1.f / red[0];
#pragma unroll
  for (int jj = 0; jj < 4; ++jj)
    attn[(size_t)r * S_ + tid + 256 * jj] = e[jj] * rs;
}

// ---------------- K56: context + out-proj + attn_t (all fp32) ----------------
// Block per r=(b,t). Reads ONLY attn row r from A, then overwrites that row
// with context. Writes hidden (B) and attn_t (C; alg dead after k4).
__global__ __launch_bounds__(256) void k56_ctx_proj(const float* __restrict__ attn, const float* __restrict__ states,
                                                    const float* __restrict__ query, const float* __restrict__ Wc,
                                                    const float* __restrict__ bc,
                                                    float* __restrict__ out_ctx, float* __restrict__ out_hid,
                                                    float* __restrict__ out_at) {
  const int r = blockIdx.x;                    // b*T+t
  const int b = r >> 5, t = r & (T_ - 1);
  const int tid = threadIdx.x;
  __shared__ float pr[S_];                     // 4 KB
  __shared__ float cq[D_ + H_];                // 6 KB
  for (int s = tid; s < S_; s += 256) pr[s] = attn[(size_t)r * S_ + s];
  __syncthreads();
  // attentions_t: (B,S,T)
  for (int s = tid; s < S_; s += 256) out_at[((size_t)b * S_ + s) * T_ + t] = pr[s];
  // context
  float acc[4] = {0.f, 0.f, 0.f, 0.f};
  for (int s = 0; s < S_; ++s) {
    const float w = pr[s];
    const float* srow = states + ((size_t)b * S_ + s) * D_ + tid;
#pragma unroll
    for (int jj = 0; jj < 4; ++jj) acc[jj] = fmaf(w, srow[256 * jj], acc[jj]);
  }
#pragma unroll
  for (int jj = 0; jj < 4; ++jj) {
    cq[tid + 256 * jj] = acc[jj];
    out_ctx[(size_t)r * D_ + tid + 256 * jj] = acc[jj];   // own row: safe overwrite
  }
  for (int i = tid; i < H_; i += 256) cq[D_ + i] = query[(size_t)r * H_ + i];
  __syncthreads();
  // hidden = [ctx, query] @ Wc + bc
#pragma unroll
  for (int jj = 0; jj < 2; ++jj) {
    const int n = tid + 256 * jj;
    float h = bc[n];
    for (int k = 0; k < D_ + H_; ++k) h = fmaf(cq[k], Wc[(size_t)k * H_ + n], h);
    out_hid[(size_t)r * H_ + n] = h;
  }
}

extern "C" void kernel_launch(void* const* d_in, const int* in_sizes, int n_in,
                              void* d_out, int out_size, void* d_ws, size_t ws_size,
                              hipStream_t stream) {
  const float* query  = (const float*)d_in[0];
  const float* states = (const float*)d_in[1];
  const int*   mask   = (const int*)d_in[2];
  const float* Wq     = (const float*)d_in[3];
  const float* bq     = (const float*)d_in[4];
  const float* Ws     = (const float*)d_in[5];
  const float* v      = (const float*)d_in[6];
  const float* Wc     = (const float*)d_in[7];
  const float* bc     = (const float*)d_in[8];

  float* A  = (float*)d_out;               // qf -> attn -> context
  float* Bh = A + (size_t)BT_ * D_;        // hidden
  float* C  = Bh + (size_t)BT_ * H_;       // alg -> attn_t

  k1_qf<<<BT_, 256, 0, stream>>>(query, Wq, bq, A);
  k23_align<<<B_ * (S_ / 16), 256, 0, stream>>>(states, Ws, v, A, C);
  k4_softmax<<<BT_, 256, 0, stream>>>(C, mask, A);
  k56_ctx_proj<<<BT_, 256, 0, stream>>>(A, states, query, Wc, bc, A, Bh, C);
}

// Round 8
// 339.262 us; speedup vs baseline: 2.1529x; 2.1529x over previous
//
#include <hip/hip_runtime.h>
#include <math.h>

// Bahdanau additive attention. B=4, T=32, S=1024, H=512, D=2H=1024.
// Inputs fp32 (mask int32), OUTPUT fp32 flat:
//   context (4,32,1024) | hidden (4,32,512) | attn_t (4,1024,32)
// Round 8: fast path (ws_size >= 11 MB): MFMA sf-GEMM + high-occupancy align
// kernel + t-shared context + tiled projections. Fallback = round-7 kernels.
// d_out overlay: A[0,131072): qf -> (memset) -> ctx(final)
//                B[131072,196608): hidden(final)   C[196608,327680): alg -> attn_t(final)

typedef unsigned short u16;
typedef __bf16 bf16x8 __attribute__((ext_vector_type(8)));
typedef float floatx4 __attribute__((ext_vector_type(4)));

#define B_ 4
#define T_ 32
#define S_ 1024
#define H_ 512
#define D_ 1024
#define BT_ 128
#define TWO_LOG2E 2.8853900817779268f   // tanh(y) = 1 - 2/(exp2(2*log2e*y)+1)

__device__ __forceinline__ float bf2f(u16 u) {
  unsigned int i = ((unsigned int)u) << 16;
  return __builtin_bit_cast(float, i);
}
__device__ __forceinline__ u16 f2bf(float f) {
  unsigned int i = __builtin_bit_cast(unsigned int, f);
  i += 0x7fffu + ((i >> 16) & 1u);  // RNE
  return (u16)(i >> 16);
}

// ================= FAST PATH =================

// ---- F1: qf = 2log2e*(query @ Wq + bq). Grid (4 colchunks of 256, 16 rowgroups of 8) ----
__global__ __launch_bounds__(256) void f1_qf(const float* __restrict__ query, const float* __restrict__ Wq,
                                             const float* __restrict__ bq, float* __restrict__ qf) {
  __shared__ float q[8][512];
  const int c0 = blockIdx.x * 256, r0 = blockIdx.y * 8;
  const int tid = threadIdx.x;
  for (int i = tid; i < 8 * 512; i += 256) {
    const int rl = i >> 9, k = i & 511;
    q[rl][k] = query[(size_t)(r0 + rl) * H_ + k];
  }
  __syncthreads();
  const int col = c0 + tid;
  float acc[8] = {};
  for (int k = 0; k < 512; ++k) {
    const float w = Wq[(size_t)k * D_ + col];
#pragma unroll
    for (int r = 0; r < 8; ++r) acc[r] = fmaf(q[r][k], w, acc[r]);
  }
  const float bb = bq[col];
#pragma unroll
  for (int r = 0; r < 8; ++r) qf[(size_t)(r0 + r) * D_ + col] = TWO_LOG2E * (acc[r] + bb);
}

// ---- F0: transpose Ws fp32 (k x n) -> WsT bf16 (n-major, k-contig) ----
__global__ __launch_bounds__(256) void f0_transpose(const float* __restrict__ Ws, u16* __restrict__ WsT) {
  __shared__ u16 tile[32][65];
  const int n0 = blockIdx.x * 64, k0 = blockIdx.y * 32;
  const int t = threadIdx.x;
  {
    const int kr = t >> 3, nc = (t & 7) * 8;
    const float* p = Ws + (size_t)(k0 + kr) * D_ + n0 + nc;
    float4 a = *(const float4*)p, b = *(const float4*)(p + 4);
    tile[kr][nc + 0] = f2bf(a.x); tile[kr][nc + 1] = f2bf(a.y);
    tile[kr][nc + 2] = f2bf(a.z); tile[kr][nc + 3] = f2bf(a.w);
    tile[kr][nc + 4] = f2bf(b.x); tile[kr][nc + 5] = f2bf(b.y);
    tile[kr][nc + 6] = f2bf(b.z); tile[kr][nc + 7] = f2bf(b.w);
  }
  __syncthreads();
  {
    const int nr = t >> 2, kc = (t & 3) * 8;
    union { uint4 v; u16 s[8]; } st;
#pragma unroll
    for (int i = 0; i < 8; ++i) st.s[i] = tile[kc + i][nr];
    *(uint4*)(WsT + (size_t)(n0 + nr) * D_ + k0 + kc) = st.v;
  }
}

// ---- F2: sfb = 2log2e * (states @ Ws) as bf16. MFMA 16x16x32. 64x64 tile, 4 waves ----
__global__ __launch_bounds__(256) void f2_sfgemm(const float* __restrict__ A, const u16* __restrict__ BT,
                                                 u16* __restrict__ Cb) {
  __shared__ __align__(16) u16 sA[64 * 40];
  __shared__ __align__(16) u16 sB[64 * 40];
  const int bm0 = blockIdx.y * 64, bn0 = blockIdx.x * 64;
  const int t = threadIdx.x;
  const int lrow = t >> 2, lk = (t & 3) * 8;
  const int wid = t >> 6, lane = t & 63;
  const int wm = (wid >> 1) * 32, wn = (wid & 1) * 32;
  const int fm = lane & 15, fq = lane >> 4;

  floatx4 acc[2][2];
  const floatx4 fz = {0.f, 0.f, 0.f, 0.f};
  acc[0][0] = fz; acc[0][1] = fz; acc[1][0] = fz; acc[1][1] = fz;

  const float* gA = A + (size_t)(bm0 + lrow) * D_ + lk;
  const uint4* gB = (const uint4*)(BT + (size_t)(bn0 + lrow) * D_ + lk);

  for (int k0 = 0; k0 < D_; k0 += 32) {
    float4 a0 = *(const float4*)(gA + k0);
    float4 a1 = *(const float4*)(gA + k0 + 4);
    uint4 vb = gB[k0 >> 3];
    union { uint4 v; u16 s[8]; } pa;
    pa.s[0] = f2bf(a0.x); pa.s[1] = f2bf(a0.y); pa.s[2] = f2bf(a0.z); pa.s[3] = f2bf(a0.w);
    pa.s[4] = f2bf(a1.x); pa.s[5] = f2bf(a1.y); pa.s[6] = f2bf(a1.z); pa.s[7] = f2bf(a1.w);
    __syncthreads();
    *(uint4*)&sA[lrow * 40 + lk] = pa.v;
    *(uint4*)&sB[lrow * 40 + lk] = vb;
    __syncthreads();
    bf16x8 af[2], bfr[2];
#pragma unroll
    for (int i = 0; i < 2; ++i) af[i] = *(const bf16x8*)&sA[(wm + i * 16 + fm) * 40 + fq * 8];
#pragma unroll
    for (int j = 0; j < 2; ++j) bfr[j] = *(const bf16x8*)&sB[(wn + j * 16 + fm) * 40 + fq * 8];
#pragma unroll
    for (int i = 0; i < 2; ++i)
#pragma unroll
      for (int j = 0; j < 2; ++j)
        acc[i][j] = __builtin_amdgcn_mfma_f32_16x16x32_bf16(af[i], bfr[j], acc[i][j], 0, 0, 0);
  }
#pragma unroll
  for (int i = 0; i < 2; ++i)
#pragma unroll
    for (int j = 0; j < 2; ++j)
#pragma unroll
      for (int r = 0; r < 4; ++r) {
        const int row = bm0 + wm + i * 16 + fq * 4 + r;   // col=lane&15, row=quad*4+reg (m89)
        const int col = bn0 + wn + j * 16 + fm;
        Cb[(size_t)row * D_ + col] = f2bf(TWO_LOG2E * acc[i][j][r]);
      }
}

// ---- F3: alg[b,t,s] = sum_d v[d]*tanh-of-prescaled(qf+sf). Wave per (b,s) ----
__global__ __launch_bounds__(256) void f3_align(const float* __restrict__ qf, const u16* __restrict__ sfb,
                                                const float* __restrict__ v, float* __restrict__ alg) {
  const int wid = (blockIdx.x * 256 + threadIdx.x) >> 6;  // b*1024+s
  const int lane = threadIdx.x & 63;
  const int b = wid >> 10, s = wid & 1023;
  float vr[16], sr[16];
  const u16* sfrow = sfb + (size_t)wid * D_;
#pragma unroll
  for (int j = 0; j < 16; ++j) {
    vr[j] = v[lane + 64 * j];
    sr[j] = bf2f(sfrow[lane + 64 * j]);
  }
  for (int t = 0; t < T_; ++t) {
    const float* qrow = qf + (size_t)(b * T_ + t) * D_ + lane;
    float acc = 0.f;
#pragma unroll
    for (int j = 0; j < 16; ++j) {
      const float x = qrow[64 * j] + sr[j];                        // = 2log2e * y
      const float e = __builtin_amdgcn_exp2f(x);
      const float th = fmaf(-2.f, __builtin_amdgcn_rcpf(e + 1.f), 1.f);
      acc = fmaf(vr[j], th, acc);
    }
#pragma unroll
    for (int off = 32; off > 0; off >>= 1) acc += __shfl_xor(acc, off);
    if (lane == 0) alg[(size_t)(b * T_ + t) * S_ + s] = acc;
  }
}

// ---- F4: masked softmax; alg(C) -> attn fp32 (ws) ----
__global__ __launch_bounds__(256) void f4_softmax(const float* __restrict__ alg, const int* __restrict__ mask,
                                                  float* __restrict__ attn) {
  const int r = blockIdx.x;
  const int b = r >> 5;
  const int tid = threadIdx.x;
  __shared__ float red[256];
  float a[4];
#pragma unroll
  for (int jj = 0; jj < 4; ++jj) {
    const int s = tid + 256 * jj;
    const float x = alg[(size_t)r * S_ + s];
    a[jj] = (mask[(size_t)b * S_ + s] != 0) ? x : -3.0e38f;
  }
  float m = fmaxf(fmaxf(a[0], a[1]), fmaxf(a[2], a[3]));
  red[tid] = m; __syncthreads();
  for (int st = 128; st > 0; st >>= 1) { if (tid < st) red[tid] = fmaxf(red[tid], red[tid + st]); __syncthreads(); }
  m = red[0]; __syncthreads();
  float e[4], lsum = 0.f;
#pragma unroll
  for (int jj = 0; jj < 4; ++jj) {
    e[jj] = (a[jj] > -1.0e38f) ? expf(a[jj] - m) : 0.f;
    lsum += e[jj];
  }
  red[tid] = lsum; __syncthreads();
  for (int st = 128; st > 0; st >>= 1) { if (tid < st) red[tid] += red[tid + st]; __syncthreads(); }
  const float rs = 1.f / red[0];
#pragma unroll
  for (int jj = 0; jj < 4; ++jj)
    attn[(size_t)r * S_ + tid + 256 * jj] = e[jj] * rs;
}

// ---- F5: ctx += attn @ states (t-shared tiles, fp32 atomics); also write attn_t ----
// Grid (8 s-chunks of 128, 2 t-halves of 16, 4 b).
__global__ __launch_bounds__(256) void f5_context(const float* __restrict__ attn, const float* __restrict__ states,
                                                  float* __restrict__ ctx, float* __restrict__ out_at) {
  __shared__ float at[16][128];
  const int s0 = blockIdx.x * 128, t0 = blockIdx.y * 16, b = blockIdx.z;
  const int tid = threadIdx.x;
  for (int i = tid; i < 16 * 128; i += 256) {
    const int tl = i >> 7, sl = i & 127;
    at[tl][sl] = attn[(size_t)(b * T_ + t0 + tl) * S_ + s0 + sl];
  }
  __syncthreads();
  // attn_t (B,S,T): each (s,t) cell covered exactly once across grid
  for (int i = tid; i < 128 * 16; i += 256) {
    const int sl = i >> 4, tl = i & 15;
    out_at[((size_t)b * S_ + s0 + sl) * T_ + t0 + tl] = at[tl][sl];
  }
  float acc[16][4] = {};
  for (int sl = 0; sl < 128; ++sl) {
    const float* srow = states + ((size_t)b * S_ + s0 + sl) * D_ + tid;
    float sv[4];
#pragma unroll
    for (int jj = 0; jj < 4; ++jj) sv[jj] = srow[256 * jj];
#pragma unroll
    for (int tl = 0; tl < 16; ++tl) {
      const float w = at[tl][sl];
#pragma unroll
      for (int jj = 0; jj < 4; ++jj) acc[tl][jj] = fmaf(w, sv[jj], acc[tl][jj]);
    }
  }
#pragma unroll
  for (int tl = 0; tl < 16; ++tl)
#pragma unroll
    for (int jj = 0; jj < 4; ++jj)
      atomicAdd(&ctx[(size_t)(b * T_ + t0 + tl) * D_ + tid + 256 * jj], acc[tl][jj]);
}

// ---- F6: hidden = [ctx, query] @ Wc + bc. Grid (4 colchunks of 128, 8 rowgroups of 16) ----
__global__ __launch_bounds__(256) void f6_outproj(const float* __restrict__ ctx, const float* __restrict__ query,
                                                  const float* __restrict__ Wc, const float* __restrict__ bc,
                                                  float* __restrict__ out_hid) {
  __shared__ float cq[16][128];
  const int c0 = blockIdx.x * 128, r0 = blockIdx.y * 16;
  const int tid = threadIdx.x;
  const int cl = tid & 127, rh = tid >> 7;      // rh in {0,1}: rows rh*8..rh*8+7
  float acc[8] = {};
  for (int kc = 0; kc < 12; ++kc) {
    const int k0 = kc * 128;
    for (int i = tid; i < 16 * 128; i += 256) {
      const int rl = i >> 7, kk = i & 127;
      const int k = k0 + kk, row = r0 + rl;
      cq[rl][kk] = (k < D_) ? ctx[(size_t)row * D_ + k] : query[(size_t)row * H_ + k - D_];
    }
    __syncthreads();
    for (int kk = 0; kk < 128; ++kk) {
      const float w = Wc[(size_t)(k0 + kk) * H_ + c0 + cl];
#pragma unroll
      for (int rr = 0; rr < 8; ++rr) acc[rr] = fmaf(cq[rh * 8 + rr][kk], w, acc[rr]);
    }
    __syncthreads();
  }
  const float bb = bc[c0 + cl];
#pragma unroll
  for (int rr = 0; rr < 8; ++rr)
    out_hid[(size_t)(r0 + rh * 8 + rr) * H_ + c0 + cl] = acc[rr] + bb;
}

// ================= FALLBACK (round-7, passing) =================

__global__ __launch_bounds__(256) void k1_qf(const float* __restrict__ query, const float* __restrict__ Wq,
                                             const float* __restrict__ bq, float* __restrict__ qf) {
  const int r = blockIdx.x;
  const int tid = threadIdx.x;
  __shared__ float q[H_];
  for (int i = tid; i < H_; i += 256) q[i] = query[(size_t)r * H_ + i];
  __syncthreads();
#pragma unroll
  for (int jj = 0; jj < 4; ++jj) {
    const int j = tid + 256 * jj;
    float acc = bq[j];
    for (int k = 0; k < H_; ++k) acc = fmaf(q[k], Wq[(size_t)k * D_ + j], acc);
    qf[(size_t)r * D_ + j] = acc;
  }
}

__global__ __launch_bounds__(256) void k23_align(const float* __restrict__ states, const float* __restrict__ Ws,
                                                 const float* __restrict__ v, const float* __restrict__ qf,
                                                 float* __restrict__ alg) {
  const int b = blockIdx.x >> 6;
  const int s0 = (blockIdx.x & 63) * 16;
  const int tid = threadIdx.x, lane = tid & 63, wv = tid >> 6;
  __shared__ u16 stL[16 * D_];
  __shared__ float vvL[D_];
  __shared__ float red[16 * 4];
  for (int i = tid; i < 16 * D_; i += 256) {
    const int row = i >> 10, col = i & (D_ - 1);
    stL[i] = f2bf(states[((size_t)b * S_ + s0 + row) * D_ + col]);
  }
  for (int i = tid; i < D_; i += 256) vvL[i] = v[i];
  __syncthreads();
  float acc[64];
#pragma unroll
  for (int i = 0; i < 64; ++i) acc[i] = 0.f;
#pragma unroll 4
  for (int k = 0; k < D_; ++k) {
    float wsv[4];
#pragma unroll
    for (int jj = 0; jj < 4; ++jj) wsv[jj] = Ws[(size_t)k * D_ + tid + 256 * jj];
#pragma unroll
    for (int i = 0; i < 16; ++i) {
      const float sv = bf2f(stL[i * D_ + k]);
#pragma unroll
      for (int jj = 0; jj < 4; ++jj) acc[i * 4 + jj] = fmaf(sv, wsv[jj], acc[i * 4 + jj]);
    }
  }
  for (int t = 0; t < T_; ++t) {
    float qv[4];
#pragma unroll
    for (int jj = 0; jj < 4; ++jj) qv[jj] = qf[((size_t)b * T_ + t) * D_ + tid + 256 * jj];
    float part[16];
#pragma unroll
    for (int i = 0; i < 16; ++i) {
      float p = 0.f;
#pragma unroll
      for (int jj = 0; jj < 4; ++jj)
        p = fmaf(vvL[tid + 256 * jj], tanhf(qv[jj] + acc[i * 4 + jj]), p);
      part[i] = p;
    }
#pragma unroll
    for (int i = 0; i < 16; ++i) {
      float x = part[i];
#pragma unroll
      for (int off = 32; off > 0; off >>= 1) x += __shfl_xor(x, off);
      if (lane == 0) red[i * 4 + wv] = x;
    }
    __syncthreads();
    if (tid < 16)
      alg[((size_t)b * T_ + t) * S_ + s0 + tid] =
          red[tid * 4 + 0] + red[tid * 4 + 1] + red[tid * 4 + 2] + red[tid * 4 + 3];
    __syncthreads();
  }
}

__global__ __launch_bounds__(256) void k4_softmax(const float* __restrict__ alg, const int* __restrict__ mask,
                                                  float* __restrict__ attn) {
  const int r = blockIdx.x;
  const int b = r >> 5;
  const int tid = threadIdx.x;
  __shared__ float red[256];
  float a[4];
#pragma unroll
  for (int jj = 0; jj < 4; ++jj) {
    const int s = tid + 256 * jj;
    const float x = alg[(size_t)r * S_ + s];
    a[jj] = (mask[(size_t)b * S_ + s] != 0) ? x : -3.0e38f;
  }
  float m = fmaxf(fmaxf(a[0], a[1]), fmaxf(a[2], a[3]));
  red[tid] = m; __syncthreads();
  for (int st = 128; st > 0; st >>= 1) { if (tid < st) red[tid] = fmaxf(red[tid], red[tid + st]); __syncthreads(); }
  m = red[0]; __syncthreads();
  float e[4], lsum = 0.f;
#pragma unroll
  for (int jj = 0; jj < 4; ++jj) {
    e[jj] = (a[jj] > -1.0e38f) ? expf(a[jj] - m) : 0.f;
    lsum += e[jj];
  }
  red[tid] = lsum; __syncthreads();
  for (int st = 128; st > 0; st >>= 1) { if (tid < st) red[tid] += red[tid + st]; __syncthreads(); }
  const float rs = 1.f / red[0];
#pragma unroll
  for (int jj = 0; jj < 4; ++jj)
    attn[(size_t)r * S_ + tid + 256 * jj] = e[jj] * rs;
}

__global__ __launch_bounds__(256) void k56_ctx_proj(const float* __restrict__ attn, const float* __restrict__ states,
                                                    const float* __restrict__ query, const float* __restrict__ Wc,
                                                    const float* __restrict__ bc,
                                                    float* __restrict__ out_ctx, float* __restrict__ out_hid,
                                                    float* __restrict__ out_at) {
  const int r = blockIdx.x;
  const int b = r >> 5, t = r & (T_ - 1);
  const int tid = threadIdx.x;
  __shared__ float pr[S_];
  __shared__ float cq[D_ + H_];
  for (int s = tid; s < S_; s += 256) pr[s] = attn[(size_t)r * S_ + s];
  __syncthreads();
  for (int s = tid; s < S_; s += 256) out_at[((size_t)b * S_ + s) * T_ + t] = pr[s];
  float acc[4] = {0.f, 0.f, 0.f, 0.f};
  for (int s = 0; s < S_; ++s) {
    const float w = pr[s];
    const float* srow = states + ((size_t)b * S_ + s) * D_ + tid;
#pragma unroll
    for (int jj = 0; jj < 4; ++jj) acc[jj] = fmaf(w, srow[256 * jj], acc[jj]);
  }
#pragma unroll
  for (int jj = 0; jj < 4; ++jj) {
    cq[tid + 256 * jj] = acc[jj];
    out_ctx[(size_t)r * D_ + tid + 256 * jj] = acc[jj];
  }
  for (int i = tid; i < H_; i += 256) cq[D_ + i] = query[(size_t)r * H_ + i];
  __syncthreads();
#pragma unroll
  for (int jj = 0; jj < 2; ++jj) {
    const int n = tid + 256 * jj;
    float h = bc[n];
    for (int k = 0; k < D_ + H_; ++k) h = fmaf(cq[k], Wc[(size_t)k * H_ + n], h);
    out_hid[(size_t)r * H_ + n] = h;
  }
}

extern "C" void kernel_launch(void* const* d_in, const int* in_sizes, int n_in,
                              void* d_out, int out_size, void* d_ws, size_t ws_size,
                              hipStream_t stream) {
  const float* query  = (const float*)d_in[0];
  const float* states = (const float*)d_in[1];
  const int*   mask   = (const int*)d_in[2];
  const float* Wq     = (const float*)d_in[3];
  const float* bq     = (const float*)d_in[4];
  const float* Ws     = (const float*)d_in[5];
  const float* v      = (const float*)d_in[6];
  const float* Wc     = (const float*)d_in[7];
  const float* bc     = (const float*)d_in[8];

  float* A  = (float*)d_out;               // qf -> ctx(final)
  float* Bh = A + (size_t)BT_ * D_;        // hidden
  float* C  = Bh + (size_t)BT_ * H_;       // alg -> attn_t

  const size_t WS_NEED = 8388608 + 2097152 + 524288;   // sfb + WsT + attn
  if (ws_size >= WS_NEED) {
    char* ws = (char*)d_ws;
    u16*   sfb  = (u16*)(ws + 0);              // 8 MB
    u16*   WsT  = (u16*)(ws + 8388608);        // 2 MB
    float* attn = (float*)(ws + 10485760);     // 512 KB

    f1_qf<<<dim3(4, 16), 256, 0, stream>>>(query, Wq, bq, A);
    f0_transpose<<<dim3(16, 32), 256, 0, stream>>>(Ws, WsT);
    f2_sfgemm<<<dim3(16, 64), 256, 0, stream>>>(states, WsT, sfb);
    f3_align<<<1024, 256, 0, stream>>>(A, sfb, v, C);
    (void)hipMemsetAsync(A, 0, (size_t)BT_ * D_ * 4, stream);   // ctx zero (qf dead)
    f4_softmax<<<BT_, 256, 0, stream>>>(C, mask, attn);
    f5_context<<<dim3(8, 2, 4), 256, 0, stream>>>(attn, states, A, C);
    f6_outproj<<<dim3(4, 8), 256, 0, stream>>>(A, query, Wc, bc, Bh);
  } else {
    k1_qf<<<BT_, 256, 0, stream>>>(query, Wq, bq, A);
    k23_align<<<B_ * (S_ / 16), 256, 0, stream>>>(states, Ws, v, A, C);
    k4_softmax<<<BT_, 256, 0, stream>>>(C, mask, A);
    k56_ctx_proj<<<BT_, 256, 0, stream>>>(A, states, query, Wc, bc, A, Bh, C);
  }
}

// Round 9
// 228.065 us; speedup vs baseline: 3.2025x; 1.4876x over previous
//
#include <hip/hip_runtime.h>
#include <math.h>

// Bahdanau additive attention. B=4, T=32, S=1024, H=512, D=2H=1024.
// Inputs fp32 (mask int32), OUTPUT fp32 flat:
//   context (4,32,1024) | hidden (4,32,512) | attn_t (4,1024,32)
// Round 9: f6 was latency-bound (32 blocks, 145us, VALUBusy 2%). Split-K
// rewrite: 384 blocks + fp32 atomics. Everything else = round 8.
// d_out overlay: A[0,131072): qf -> (memset) -> ctx(final)
//                B[131072,196608): (memset) -> hidden(final)
//                C[196608,327680): alg -> attn_t(final)

typedef unsigned short u16;
typedef __bf16 bf16x8 __attribute__((ext_vector_type(8)));
typedef float floatx4 __attribute__((ext_vector_type(4)));

#define B_ 4
#define T_ 32
#define S_ 1024
#define H_ 512
#define D_ 1024
#define BT_ 128
#define TWO_LOG2E 2.8853900817779268f   // tanh(y) = 1 - 2/(exp2(2*log2e*y)+1)

__device__ __forceinline__ float bf2f(u16 u) {
  unsigned int i = ((unsigned int)u) << 16;
  return __builtin_bit_cast(float, i);
}
__device__ __forceinline__ u16 f2bf(float f) {
  unsigned int i = __builtin_bit_cast(unsigned int, f);
  i += 0x7fffu + ((i >> 16) & 1u);  // RNE
  return (u16)(i >> 16);
}

// ================= FAST PATH =================

// ---- F1: qf = 2log2e*(query @ Wq + bq). Grid (4 colchunks of 256, 16 rowgroups of 8) ----
__global__ __launch_bounds__(256) void f1_qf(const float* __restrict__ query, const float* __restrict__ Wq,
                                             const float* __restrict__ bq, float* __restrict__ qf) {
  __shared__ float q[8][512];
  const int c0 = blockIdx.x * 256, r0 = blockIdx.y * 8;
  const int tid = threadIdx.x;
  for (int i = tid; i < 8 * 512; i += 256) {
    const int rl = i >> 9, k = i & 511;
    q[rl][k] = query[(size_t)(r0 + rl) * H_ + k];
  }
  __syncthreads();
  const int col = c0 + tid;
  float acc[8] = {};
  for (int k = 0; k < 512; ++k) {
    const float w = Wq[(size_t)k * D_ + col];
#pragma unroll
    for (int r = 0; r < 8; ++r) acc[r] = fmaf(q[r][k], w, acc[r]);
  }
  const float bb = bq[col];
#pragma unroll
  for (int r = 0; r < 8; ++r) qf[(size_t)(r0 + r) * D_ + col] = TWO_LOG2E * (acc[r] + bb);
}

// ---- F0: transpose Ws fp32 (k x n) -> WsT bf16 (n-major, k-contig) ----
__global__ __launch_bounds__(256) void f0_transpose(const float* __restrict__ Ws, u16* __restrict__ WsT) {
  __shared__ u16 tile[32][65];
  const int n0 = blockIdx.x * 64, k0 = blockIdx.y * 32;
  const int t = threadIdx.x;
  {
    const int kr = t >> 3, nc = (t & 7) * 8;
    const float* p = Ws + (size_t)(k0 + kr) * D_ + n0 + nc;
    float4 a = *(const float4*)p, b = *(const float4*)(p + 4);
    tile[kr][nc + 0] = f2bf(a.x); tile[kr][nc + 1] = f2bf(a.y);
    tile[kr][nc + 2] = f2bf(a.z); tile[kr][nc + 3] = f2bf(a.w);
    tile[kr][nc + 4] = f2bf(b.x); tile[kr][nc + 5] = f2bf(b.y);
    tile[kr][nc + 6] = f2bf(b.z); tile[kr][nc + 7] = f2bf(b.w);
  }
  __syncthreads();
  {
    const int nr = t >> 2, kc = (t & 3) * 8;
    union { uint4 v; u16 s[8]; } st;
#pragma unroll
    for (int i = 0; i < 8; ++i) st.s[i] = tile[kc + i][nr];
    *(uint4*)(WsT + (size_t)(n0 + nr) * D_ + k0 + kc) = st.v;
  }
}

// ---- F2: sfb = 2log2e * (states @ Ws) as bf16. MFMA 16x16x32. 64x64 tile, 4 waves ----
__global__ __launch_bounds__(256) void f2_sfgemm(const float* __restrict__ A, const u16* __restrict__ BT,
                                                 u16* __restrict__ Cb) {
  __shared__ __align__(16) u16 sA[64 * 40];
  __shared__ __align__(16) u16 sB[64 * 40];
  const int bm0 = blockIdx.y * 64, bn0 = blockIdx.x * 64;
  const int t = threadIdx.x;
  const int lrow = t >> 2, lk = (t & 3) * 8;
  const int wid = t >> 6, lane = t & 63;
  const int wm = (wid >> 1) * 32, wn = (wid & 1) * 32;
  const int fm = lane & 15, fq = lane >> 4;

  floatx4 acc[2][2];
  const floatx4 fz = {0.f, 0.f, 0.f, 0.f};
  acc[0][0] = fz; acc[0][1] = fz; acc[1][0] = fz; acc[1][1] = fz;

  const float* gA = A + (size_t)(bm0 + lrow) * D_ + lk;
  const uint4* gB = (const uint4*)(BT + (size_t)(bn0 + lrow) * D_ + lk);

  for (int k0 = 0; k0 < D_; k0 += 32) {
    float4 a0 = *(const float4*)(gA + k0);
    float4 a1 = *(const float4*)(gA + k0 + 4);
    uint4 vb = gB[k0 >> 3];
    union { uint4 v; u16 s[8]; } pa;
    pa.s[0] = f2bf(a0.x); pa.s[1] = f2bf(a0.y); pa.s[2] = f2bf(a0.z); pa.s[3] = f2bf(a0.w);
    pa.s[4] = f2bf(a1.x); pa.s[5] = f2bf(a1.y); pa.s[6] = f2bf(a1.z); pa.s[7] = f2bf(a1.w);
    __syncthreads();
    *(uint4*)&sA[lrow * 40 + lk] = pa.v;
    *(uint4*)&sB[lrow * 40 + lk] = vb;
    __syncthreads();
    bf16x8 af[2], bfr[2];
#pragma unroll
    for (int i = 0; i < 2; ++i) af[i] = *(const bf16x8*)&sA[(wm + i * 16 + fm) * 40 + fq * 8];
#pragma unroll
    for (int j = 0; j < 2; ++j) bfr[j] = *(const bf16x8*)&sB[(wn + j * 16 + fm) * 40 + fq * 8];
#pragma unroll
    for (int i = 0; i < 2; ++i)
#pragma unroll
      for (int j = 0; j < 2; ++j)
        acc[i][j] = __builtin_amdgcn_mfma_f32_16x16x32_bf16(af[i], bfr[j], acc[i][j], 0, 0, 0);
  }
#pragma unroll
  for (int i = 0; i < 2; ++i)
#pragma unroll
    for (int j = 0; j < 2; ++j)
#pragma unroll
      for (int r = 0; r < 4; ++r) {
        const int row = bm0 + wm + i * 16 + fq * 4 + r;   // col=lane&15, row=quad*4+reg (m89)
        const int col = bn0 + wn + j * 16 + fm;
        Cb[(size_t)row * D_ + col] = f2bf(TWO_LOG2E * acc[i][j][r]);
      }
}

// ---- F3: alg[b,t,s] = sum_d v[d]*tanh-of-prescaled(qf+sf). Wave per (b,s) ----
__global__ __launch_bounds__(256) void f3_align(const float* __restrict__ qf, const u16* __restrict__ sfb,
                                                const float* __restrict__ v, float* __restrict__ alg) {
  const int wid = (blockIdx.x * 256 + threadIdx.x) >> 6;  // b*1024+s
  const int lane = threadIdx.x & 63;
  const int b = wid >> 10, s = wid & 1023;
  float vr[16], sr[16];
  const u16* sfrow = sfb + (size_t)wid * D_;
#pragma unroll
  for (int j = 0; j < 16; ++j) {
    vr[j] = v[lane + 64 * j];
    sr[j] = bf2f(sfrow[lane + 64 * j]);
  }
  for (int t = 0; t < T_; ++t) {
    const float* qrow = qf + (size_t)(b * T_ + t) * D_ + lane;
    float acc = 0.f;
#pragma unroll
    for (int j = 0; j < 16; ++j) {
      const float x = qrow[64 * j] + sr[j];                        // = 2log2e * y
      const float e = __builtin_amdgcn_exp2f(x);
      const float th = fmaf(-2.f, __builtin_amdgcn_rcpf(e + 1.f), 1.f);
      acc = fmaf(vr[j], th, acc);
    }
#pragma unroll
    for (int off = 32; off > 0; off >>= 1) acc += __shfl_xor(acc, off);
    if (lane == 0) alg[(size_t)(b * T_ + t) * S_ + s] = acc;
  }
}

// ---- F4: masked softmax; alg(C) -> attn fp32 (ws) ----
__global__ __launch_bounds__(256) void f4_softmax(const float* __restrict__ alg, const int* __restrict__ mask,
                                                  float* __restrict__ attn) {
  const int r = blockIdx.x;
  const int b = r >> 5;
  const int tid = threadIdx.x;
  __shared__ float red[256];
  float a[4];
#pragma unroll
  for (int jj = 0; jj < 4; ++jj) {
    const int s = tid + 256 * jj;
    const float x = alg[(size_t)r * S_ + s];
    a[jj] = (mask[(size_t)b * S_ + s] != 0) ? x : -3.0e38f;
  }
  float m = fmaxf(fmaxf(a[0], a[1]), fmaxf(a[2], a[3]));
  red[tid] = m; __syncthreads();
  for (int st = 128; st > 0; st >>= 1) { if (tid < st) red[tid] = fmaxf(red[tid], red[tid + st]); __syncthreads(); }
  m = red[0]; __syncthreads();
  float e[4], lsum = 0.f;
#pragma unroll
  for (int jj = 0; jj < 4; ++jj) {
    e[jj] = (a[jj] > -1.0e38f) ? expf(a[jj] - m) : 0.f;
    lsum += e[jj];
  }
  red[tid] = lsum; __syncthreads();
  for (int st = 128; st > 0; st >>= 1) { if (tid < st) red[tid] += red[tid + st]; __syncthreads(); }
  const float rs = 1.f / red[0];
#pragma unroll
  for (int jj = 0; jj < 4; ++jj)
    attn[(size_t)r * S_ + tid + 256 * jj] = e[jj] * rs;
}

// ---- F5: ctx += attn @ states (t-shared tiles, fp32 atomics); also write attn_t ----
// Grid (8 s-chunks of 128, 2 t-halves of 16, 4 b).
__global__ __launch_bounds__(256) void f5_context(const float* __restrict__ attn, const float* __restrict__ states,
                                                  float* __restrict__ ctx, float* __restrict__ out_at) {
  __shared__ float at[16][128];
  const int s0 = blockIdx.x * 128, t0 = blockIdx.y * 16, b = blockIdx.z;
  const int tid = threadIdx.x;
  for (int i = tid; i < 16 * 128; i += 256) {
    const int tl = i >> 7, sl = i & 127;
    at[tl][sl] = attn[(size_t)(b * T_ + t0 + tl) * S_ + s0 + sl];
  }
  __syncthreads();
  for (int i = tid; i < 128 * 16; i += 256) {
    const int sl = i >> 4, tl = i & 15;
    out_at[((size_t)b * S_ + s0 + sl) * T_ + t0 + tl] = at[tl][sl];
  }
  float acc[16][4] = {};
  for (int sl = 0; sl < 128; ++sl) {
    const float* srow = states + ((size_t)b * S_ + s0 + sl) * D_ + tid;
    float sv[4];
#pragma unroll
    for (int jj = 0; jj < 4; ++jj) sv[jj] = srow[256 * jj];
#pragma unroll
    for (int tl = 0; tl < 16; ++tl) {
      const float w = at[tl][sl];
#pragma unroll
      for (int jj = 0; jj < 4; ++jj) acc[tl][jj] = fmaf(w, sv[jj], acc[tl][jj]);
    }
  }
#pragma unroll
  for (int tl = 0; tl < 16; ++tl)
#pragma unroll
    for (int jj = 0; jj < 4; ++jj)
      atomicAdd(&ctx[(size_t)(b * T_ + t0 + tl) * D_ + tid + 256 * jj], acc[tl][jj]);
}

// ---- F6b: hidden += [ctx, query]_kslice @ Wc (+bc on slice 0). Split-K atomics. ----
// Grid (4 colchunks of 128, 8 rowgroups of 16, 12 kchunks of 128) = 384 blocks.
__global__ __launch_bounds__(256) void f6b_outproj(const float* __restrict__ ctx, const float* __restrict__ query,
                                                   const float* __restrict__ Wc, const float* __restrict__ bc,
                                                   float* __restrict__ out_hid) {
  __shared__ float cq[16][128];
  const int c0 = blockIdx.x * 128, r0 = blockIdx.y * 16, k0 = blockIdx.z * 128;
  const int tid = threadIdx.x;
  const int cl = tid & 127, rh = tid >> 7;      // rh in {0,1}: rows rh*8..rh*8+7
  for (int i = tid; i < 16 * 128; i += 256) {
    const int rl = i >> 7, kk = i & 127;
    const int k = k0 + kk, row = r0 + rl;
    cq[rl][kk] = (k < D_) ? ctx[(size_t)row * D_ + k] : query[(size_t)row * H_ + k - D_];
  }
  __syncthreads();
  float acc[8] = {};
  for (int kk = 0; kk < 128; ++kk) {
    const float w = Wc[(size_t)(k0 + kk) * H_ + c0 + cl];   // wave-coalesced; cq broadcast
#pragma unroll
    for (int rr = 0; rr < 8; ++rr) acc[rr] = fmaf(cq[rh * 8 + rr][kk], w, acc[rr]);
  }
  const float bb = (blockIdx.z == 0) ? bc[c0 + cl] : 0.f;
#pragma unroll
  for (int rr = 0; rr < 8; ++rr)
    atomicAdd(&out_hid[(size_t)(r0 + rh * 8 + rr) * H_ + c0 + cl], acc[rr] + bb);
}

// ================= FALLBACK (round-7, passing) =================

__global__ __launch_bounds__(256) void k1_qf(const float* __restrict__ query, const float* __restrict__ Wq,
                                             const float* __restrict__ bq, float* __restrict__ qf) {
  const int r = blockIdx.x;
  const int tid = threadIdx.x;
  __shared__ float q[H_];
  for (int i = tid; i < H_; i += 256) q[i] = query[(size_t)r * H_ + i];
  __syncthreads();
#pragma unroll
  for (int jj = 0; jj < 4; ++jj) {
    const int j = tid + 256 * jj;
    float acc = bq[j];
    for (int k = 0; k < H_; ++k) acc = fmaf(q[k], Wq[(size_t)k * D_ + j], acc);
    qf[(size_t)r * D_ + j] = acc;
  }
}

__global__ __launch_bounds__(256) void k23_align(const float* __restrict__ states, const float* __restrict__ Ws,
                                                 const float* __restrict__ v, const float* __restrict__ qf,
                                                 float* __restrict__ alg) {
  const int b = blockIdx.x >> 6;
  const int s0 = (blockIdx.x & 63) * 16;
  const int tid = threadIdx.x, lane = tid & 63, wv = tid >> 6;
  __shared__ u16 stL[16 * D_];
  __shared__ float vvL[D_];
  __shared__ float red[16 * 4];
  for (int i = tid; i < 16 * D_; i += 256) {
    const int row = i >> 10, col = i & (D_ - 1);
    stL[i] = f2bf(states[((size_t)b * S_ + s0 + row) * D_ + col]);
  }
  for (int i = tid; i < D_; i += 256) vvL[i] = v[i];
  __syncthreads();
  float acc[64];
#pragma unroll
  for (int i = 0; i < 64; ++i) acc[i] = 0.f;
#pragma unroll 4
  for (int k = 0; k < D_; ++k) {
    float wsv[4];
#pragma unroll
    for (int jj = 0; jj < 4; ++jj) wsv[jj] = Ws[(size_t)k * D_ + tid + 256 * jj];
#pragma unroll
    for (int i = 0; i < 16; ++i) {
      const float sv = bf2f(stL[i * D_ + k]);
#pragma unroll
      for (int jj = 0; jj < 4; ++jj) acc[i * 4 + jj] = fmaf(sv, wsv[jj], acc[i * 4 + jj]);
    }
  }
  for (int t = 0; t < T_; ++t) {
    float qv[4];
#pragma unroll
    for (int jj = 0; jj < 4; ++jj) qv[jj] = qf[((size_t)b * T_ + t) * D_ + tid + 256 * jj];
    float part[16];
#pragma unroll
    for (int i = 0; i < 16; ++i) {
      float p = 0.f;
#pragma unroll
      for (int jj = 0; jj < 4; ++jj)
        p = fmaf(vvL[tid + 256 * jj], tanhf(qv[jj] + acc[i * 4 + jj]), p);
      part[i] = p;
    }
#pragma unroll
    for (int i = 0; i < 16; ++i) {
      float x = part[i];
#pragma unroll
      for (int off = 32; off > 0; off >>= 1) x += __shfl_xor(x, off);
      if (lane == 0) red[i * 4 + wv] = x;
    }
    __syncthreads();
    if (tid < 16)
      alg[((size_t)b * T_ + t) * S_ + s0 + tid] =
          red[tid * 4 + 0] + red[tid * 4 + 1] + red[tid * 4 + 2] + red[tid * 4 + 3];
    __syncthreads();
  }
}

__global__ __launch_bounds__(256) void k4_softmax(const float* __restrict__ alg, const int* __restrict__ mask,
                                                  float* __restrict__ attn) {
  const int r = blockIdx.x;
  const int b = r >> 5;
  const int tid = threadIdx.x;
  __shared__ float red[256];
  float a[4];
#pragma unroll
  for (int jj = 0; jj < 4; ++jj) {
    const int s = tid + 256 * jj;
    const float x = alg[(size_t)r * S_ + s];
    a[jj] = (mask[(size_t)b * S_ + s] != 0) ? x : -3.0e38f;
  }
  float m = fmaxf(fmaxf(a[0], a[1]), fmaxf(a[2], a[3]));
  red[tid] = m; __syncthreads();
  for (int st = 128; st > 0; st >>= 1) { if (tid < st) red[tid] = fmaxf(red[tid], red[tid + st]); __syncthreads(); }
  m = red[0]; __syncthreads();
  float e[4], lsum = 0.f;
#pragma unroll
  for (int jj = 0; jj < 4; ++jj) {
    e[jj] = (a[jj] > -1.0e38f) ? expf(a[jj] - m) : 0.f;
    lsum += e[jj];
  }
  red[tid] = lsum; __syncthreads();
  for (int st = 128; st > 0; st >>= 1) { if (tid < st) red[tid] += red[tid + st]; __syncthreads(); }
  const float rs = 1.f / red[0];
#pragma unroll
  for (int jj = 0; jj < 4; ++jj)
    attn[(size_t)r * S_ + tid + 256 * jj] = e[jj] * rs;
}

__global__ __launch_bounds__(256) void k56_ctx_proj(const float* __restrict__ attn, const float* __restrict__ states,
                                                    const float* __restrict__ query, const float* __restrict__ Wc,
                                                    const float* __restrict__ bc,
                                                    float* __restrict__ out_ctx, float* __restrict__ out_hid,
                                                    float* __restrict__ out_at) {
  const int r = blockIdx.x;
  const int b = r >> 5, t = r & (T_ - 1);
  const int tid = threadIdx.x;
  __shared__ float pr[S_];
  __shared__ float cq[D_ + H_];
  for (int s = tid; s < S_; s += 256) pr[s] = attn[(size_t)r * S_ + s];
  __syncthreads();
  for (int s = tid; s < S_; s += 256) out_at[((size_t)b * S_ + s) * T_ + t] = pr[s];
  float acc[4] = {0.f, 0.f, 0.f, 0.f};
  for (int s = 0; s < S_; ++s) {
    const float w = pr[s];
    const float* srow = states + ((size_t)b * S_ + s) * D_ + tid;
#pragma unroll
    for (int jj = 0; jj < 4; ++jj) acc[jj] = fmaf(w, srow[256 * jj], acc[jj]);
  }
#pragma unroll
  for (int jj = 0; jj < 4; ++jj) {
    cq[tid + 256 * jj] = acc[jj];
    out_ctx[(size_t)r * D_ + tid + 256 * jj] = acc[jj];
  }
  for (int i = tid; i < H_; i += 256) cq[D_ + i] = query[(size_t)r * H_ + i];
  __syncthreads();
#pragma unroll
  for (int jj = 0; jj < 2; ++jj) {
    const int n = tid + 256 * jj;
    float h = bc[n];
    for (int k = 0; k < D_ + H_; ++k) h = fmaf(cq[k], Wc[(size_t)k * H_ + n], h);
    out_hid[(size_t)r * H_ + n] = h;
  }
}

extern "C" void kernel_launch(void* const* d_in, const int* in_sizes, int n_in,
                              void* d_out, int out_size, void* d_ws, size_t ws_size,
                              hipStream_t stream) {
  const float* query  = (const float*)d_in[0];
  const float* states = (const float*)d_in[1];
  const int*   mask   = (const int*)d_in[2];
  const float* Wq     = (const float*)d_in[3];
  const float* bq     = (const float*)d_in[4];
  const float* Ws     = (const float*)d_in[5];
  const float* v      = (const float*)d_in[6];
  const float* Wc     = (const float*)d_in[7];
  const float* bc     = (const float*)d_in[8];

  float* A  = (float*)d_out;               // qf -> ctx(final)
  float* Bh = A + (size_t)BT_ * D_;        // hidden
  float* C  = Bh + (size_t)BT_ * H_;       // alg -> attn_t

  const size_t WS_NEED = 8388608 + 2097152 + 524288;   // sfb + WsT + attn
  if (ws_size >= WS_NEED) {
    char* ws = (char*)d_ws;
    u16*   sfb  = (u16*)(ws + 0);              // 8 MB
    u16*   WsT  = (u16*)(ws + 8388608);        // 2 MB
    float* attn = (float*)(ws + 10485760);     // 512 KB

    f1_qf<<<dim3(4, 16), 256, 0, stream>>>(query, Wq, bq, A);
    f0_transpose<<<dim3(16, 32), 256, 0, stream>>>(Ws, WsT);
    f2_sfgemm<<<dim3(16, 64), 256, 0, stream>>>(states, WsT, sfb);
    f3_align<<<1024, 256, 0, stream>>>(A, sfb, v, C);
    (void)hipMemsetAsync(A, 0, (size_t)BT_ * D_ * 4, stream);    // ctx zero (qf dead)
    (void)hipMemsetAsync(Bh, 0, (size_t)BT_ * H_ * 4, stream);   // hidden zero (split-K)
    f4_softmax<<<BT_, 256, 0, stream>>>(C, mask, attn);
    f5_context<<<dim3(8, 2, 4), 256, 0, stream>>>(attn, states, A, C);
    f6b_outproj<<<dim3(4, 8, 12), 256, 0, stream>>>(A, query, Wc, bc, Bh);
  } else {
    k1_qf<<<BT_, 256, 0, stream>>>(query, Wq, bq, A);
    k23_align<<<B_ * (S_ / 16), 256, 0, stream>>>(states, Ws, v, A, C);
    k4_softmax<<<BT_, 256, 0, stream>>>(C, mask, A);
    k56_ctx_proj<<<BT_, 256, 0, stream>>>(A, states, query, Wc, bc, A, Bh, C);
  }
}

// Round 10
// 220.766 us; speedup vs baseline: 3.3084x; 1.0331x over previous
//
#include <hip/hip_runtime.h>
#include <math.h>

// Bahdanau additive attention. B=4, T=32, S=1024, H=512, D=2H=1024.
// Inputs fp32 (mask int32), OUTPUT fp32 flat:
//   context (4,32,1024) | hidden (4,32,512) | attn_t (4,1024,32)
// Round 10: f3 rewrite (q/v in regs, bf16 sf stream, 2048 waves);
// f1 split-K (256 blocks + atomics); f5 denser grid. f2/f0/f4/f6b unchanged.
// d_out overlay: A[0,131072): (memset)->qf -> (memset)->ctx(final)
//                B[131072,196608): (memset)->hidden(final)
//                C[196608,327680): alg -> attn_t(final)

typedef unsigned short u16;
typedef __bf16 bf16x8 __attribute__((ext_vector_type(8)));
typedef float floatx4 __attribute__((ext_vector_type(4)));

#define B_ 4
#define T_ 32
#define S_ 1024
#define H_ 512
#define D_ 1024
#define BT_ 128
#define TWO_LOG2E 2.8853900817779268f   // tanh(y) = 1 - 2/(exp2(2*log2e*y)+1)

__device__ __forceinline__ float bf2f(u16 u) {
  unsigned int i = ((unsigned int)u) << 16;
  return __builtin_bit_cast(float, i);
}
__device__ __forceinline__ u16 f2bf(float f) {
  unsigned int i = __builtin_bit_cast(unsigned int, f);
  i += 0x7fffu + ((i >> 16) & 1u);  // RNE
  return (u16)(i >> 16);
}

// ================= FAST PATH =================

// ---- F1b: qf += 2log2e*(query_kslice @ Wq) (+2log2e*bq on slice 0). Split-K atomics. ----
// Grid (4 colchunks of 256, 16 rowgroups of 8, 4 kchunks of 128) = 256 blocks.
__global__ __launch_bounds__(256) void f1b_qf(const float* __restrict__ query, const float* __restrict__ Wq,
                                              const float* __restrict__ bq, float* __restrict__ qf) {
  __shared__ float q[8][128];
  const int c0 = blockIdx.x * 256, r0 = blockIdx.y * 8, k0 = blockIdx.z * 128;
  const int tid = threadIdx.x;
  for (int i = tid; i < 8 * 128; i += 256) {
    const int rl = i >> 7, kk = i & 127;
    q[rl][kk] = query[(size_t)(r0 + rl) * H_ + k0 + kk];
  }
  __syncthreads();
  const int col = c0 + tid;
  float acc[8] = {};
  for (int kk = 0; kk < 128; ++kk) {
    const float w = Wq[(size_t)(k0 + kk) * D_ + col];
#pragma unroll
    for (int r = 0; r < 8; ++r) acc[r] = fmaf(q[r][kk], w, acc[r]);
  }
  const float bb = (blockIdx.z == 0) ? bq[col] : 0.f;
#pragma unroll
  for (int r = 0; r < 8; ++r)
    atomicAdd(&qf[(size_t)(r0 + r) * D_ + col], TWO_LOG2E * (acc[r] + bb));
}

// ---- F0: transpose Ws fp32 (k x n) -> WsT bf16 (n-major, k-contig) ----
__global__ __launch_bounds__(256) void f0_transpose(const float* __restrict__ Ws, u16* __restrict__ WsT) {
  __shared__ u16 tile[32][65];
  const int n0 = blockIdx.x * 64, k0 = blockIdx.y * 32;
  const int t = threadIdx.x;
  {
    const int kr = t >> 3, nc = (t & 7) * 8;
    const float* p = Ws + (size_t)(k0 + kr) * D_ + n0 + nc;
    float4 a = *(const float4*)p, b = *(const float4*)(p + 4);
    tile[kr][nc + 0] = f2bf(a.x); tile[kr][nc + 1] = f2bf(a.y);
    tile[kr][nc + 2] = f2bf(a.z); tile[kr][nc + 3] = f2bf(a.w);
    tile[kr][nc + 4] = f2bf(b.x); tile[kr][nc + 5] = f2bf(b.y);
    tile[kr][nc + 6] = f2bf(b.z); tile[kr][nc + 7] = f2bf(b.w);
  }
  __syncthreads();
  {
    const int nr = t >> 2, kc = (t & 3) * 8;
    union { uint4 v; u16 s[8]; } st;
#pragma unroll
    for (int i = 0; i < 8; ++i) st.s[i] = tile[kc + i][nr];
    *(uint4*)(WsT + (size_t)(n0 + nr) * D_ + k0 + kc) = st.v;
  }
}

// ---- F2: sfb = 2log2e * (states @ Ws) as bf16. MFMA 16x16x32. 64x64 tile, 4 waves ----
__global__ __launch_bounds__(256) void f2_sfgemm(const float* __restrict__ A, const u16* __restrict__ BT,
                                                 u16* __restrict__ Cb) {
  __shared__ __align__(16) u16 sA[64 * 40];
  __shared__ __align__(16) u16 sB[64 * 40];
  const int bm0 = blockIdx.y * 64, bn0 = blockIdx.x * 64;
  const int t = threadIdx.x;
  const int lrow = t >> 2, lk = (t & 3) * 8;
  const int wid = t >> 6, lane = t & 63;
  const int wm = (wid >> 1) * 32, wn = (wid & 1) * 32;
  const int fm = lane & 15, fq = lane >> 4;

  floatx4 acc[2][2];
  const floatx4 fz = {0.f, 0.f, 0.f, 0.f};
  acc[0][0] = fz; acc[0][1] = fz; acc[1][0] = fz; acc[1][1] = fz;

  const float* gA = A + (size_t)(bm0 + lrow) * D_ + lk;
  const uint4* gB = (const uint4*)(BT + (size_t)(bn0 + lrow) * D_ + lk);

  for (int k0 = 0; k0 < D_; k0 += 32) {
    float4 a0 = *(const float4*)(gA + k0);
    float4 a1 = *(const float4*)(gA + k0 + 4);
    uint4 vb = gB[k0 >> 3];
    union { uint4 v; u16 s[8]; } pa;
    pa.s[0] = f2bf(a0.x); pa.s[1] = f2bf(a0.y); pa.s[2] = f2bf(a0.z); pa.s[3] = f2bf(a0.w);
    pa.s[4] = f2bf(a1.x); pa.s[5] = f2bf(a1.y); pa.s[6] = f2bf(a1.z); pa.s[7] = f2bf(a1.w);
    __syncthreads();
    *(uint4*)&sA[lrow * 40 + lk] = pa.v;
    *(uint4*)&sB[lrow * 40 + lk] = vb;
    __syncthreads();
    bf16x8 af[2], bfr[2];
#pragma unroll
    for (int i = 0; i < 2; ++i) af[i] = *(const bf16x8*)&sA[(wm + i * 16 + fm) * 40 + fq * 8];
#pragma unroll
    for (int j = 0; j < 2; ++j) bfr[j] = *(const bf16x8*)&sB[(wn + j * 16 + fm) * 40 + fq * 8];
#pragma unroll
    for (int i = 0; i < 2; ++i)
#pragma unroll
      for (int j = 0; j < 2; ++j)
        acc[i][j] = __builtin_amdgcn_mfma_f32_16x16x32_bf16(af[i], bfr[j], acc[i][j], 0, 0, 0);
  }
#pragma unroll
  for (int i = 0; i < 2; ++i)
#pragma unroll
    for (int j = 0; j < 2; ++j)
#pragma unroll
      for (int r = 0; r < 4; ++r) {
        const int row = bm0 + wm + i * 16 + fq * 4 + r;   // col=lane&15, row=quad*4+reg (m89)
        const int col = bn0 + wn + j * 16 + fm;
        Cb[(size_t)row * D_ + col] = f2bf(TWO_LOG2E * acc[i][j][r]);
      }
}

// ---- F3b: alg[b,t,s] = sum_d v[d]*tanh-of-prescaled(qf+sf). ----
// Grid (128 bt, 4 s-chunks of 256); wave handles 64 s. q-row + v in REGISTERS
// (lane owns d in [16*lane, 16*lane+16)); sf streamed bf16; LDS result stage.
__global__ __launch_bounds__(256) void f3b_align(const float* __restrict__ qf, const u16* __restrict__ sfb,
                                                 const float* __restrict__ v, float* __restrict__ alg) {
  const int bt = blockIdx.x;                   // b*T+t
  const int b = bt >> 5;
  const int chunk = blockIdx.y;
  const int tid = threadIdx.x, lane = tid & 63, wv = tid >> 6;
  const int s0 = chunk * 256 + wv * 64;        // this wave's s range
  __shared__ float res[256];

  float qv[16], vr[16];
  {
    const float* qp = qf + (size_t)bt * D_ + lane * 16;
    const float* vp = v + lane * 16;
#pragma unroll
    for (int c = 0; c < 4; ++c) {
      float4 a = *(const float4*)(qp + 4 * c);
      float4 w = *(const float4*)(vp + 4 * c);
      qv[4 * c + 0] = a.x; qv[4 * c + 1] = a.y; qv[4 * c + 2] = a.z; qv[4 * c + 3] = a.w;
      vr[4 * c + 0] = w.x; vr[4 * c + 1] = w.y; vr[4 * c + 2] = w.z; vr[4 * c + 3] = w.w;
    }
  }

  for (int i = 0; i < 64; ++i) {
    union { uint4 v[2]; u16 s[16]; } u;
    const uint4* sp = (const uint4*)(sfb + ((size_t)b * S_ + s0 + i) * D_ + lane * 16);
    u.v[0] = sp[0];
    u.v[1] = sp[1];
    float sum = 0.f;
#pragma unroll
    for (int j = 0; j < 16; ++j) {
      const float x = qv[j] + bf2f(u.s[j]);                    // prescaled by 2log2e
      const float e = __builtin_amdgcn_exp2f(x);
      sum = fmaf(vr[j], fmaf(-2.f, __builtin_amdgcn_rcpf(e + 1.f), 1.f), sum);
    }
#pragma unroll
    for (int off = 32; off > 0; off >>= 1) sum += __shfl_xor(sum, off);
    if (lane == 0) res[wv * 64 + i] = sum;
  }
  __syncthreads();
  alg[(size_t)bt * S_ + chunk * 256 + tid] = res[tid];
}

// ---- F4: masked softmax; alg(C) -> attn fp32 (ws) ----
__global__ __launch_bounds__(256) void f4_softmax(const float* __restrict__ alg, const int* __restrict__ mask,
                                                  float* __restrict__ attn) {
  const int r = blockIdx.x;
  const int b = r >> 5;
  const int tid = threadIdx.x;
  __shared__ float red[256];
  float a[4];
#pragma unroll
  for (int jj = 0; jj < 4; ++jj) {
    const int s = tid + 256 * jj;
    const float x = alg[(size_t)r * S_ + s];
    a[jj] = (mask[(size_t)b * S_ + s] != 0) ? x : -3.0e38f;
  }
  float m = fmaxf(fmaxf(a[0], a[1]), fmaxf(a[2], a[3]));
  red[tid] = m; __syncthreads();
  for (int st = 128; st > 0; st >>= 1) { if (tid < st) red[tid] = fmaxf(red[tid], red[tid + st]); __syncthreads(); }
  m = red[0]; __syncthreads();
  float e[4], lsum = 0.f;
#pragma unroll
  for (int jj = 0; jj < 4; ++jj) {
    e[jj] = (a[jj] > -1.0e38f) ? expf(a[jj] - m) : 0.f;
    lsum += e[jj];
  }
  red[tid] = lsum; __syncthreads();
  for (int st = 128; st > 0; st >>= 1) { if (tid < st) red[tid] += red[tid + st]; __syncthreads(); }
  const float rs = 1.f / red[0];
#pragma unroll
  for (int jj = 0; jj < 4; ++jj)
    attn[(size_t)r * S_ + tid + 256 * jj] = e[jj] * rs;
}

// ---- F5: ctx += attn @ states (t-shared tiles, fp32 atomics); also write attn_t ----
// Grid (16 s-chunks of 64, 2 t-halves of 16, 4 b) = 128 blocks.
__global__ __launch_bounds__(256) void f5_context(const float* __restrict__ attn, const float* __restrict__ states,
                                                  float* __restrict__ ctx, float* __restrict__ out_at) {
  __shared__ float at[16][64];
  const int s0 = blockIdx.x * 64, t0 = blockIdx.y * 16, b = blockIdx.z;
  const int tid = threadIdx.x;
  for (int i = tid; i < 16 * 64; i += 256) {
    const int tl = i >> 6, sl = i & 63;
    at[tl][sl] = attn[(size_t)(b * T_ + t0 + tl) * S_ + s0 + sl];
  }
  __syncthreads();
  for (int i = tid; i < 64 * 16; i += 256) {
    const int sl = i >> 4, tl = i & 15;
    out_at[((size_t)b * S_ + s0 + sl) * T_ + t0 + tl] = at[tl][sl];
  }
  float acc[16][4] = {};
  for (int sl = 0; sl < 64; ++sl) {
    const float* srow = states + ((size_t)b * S_ + s0 + sl) * D_ + tid;
    float sv[4];
#pragma unroll
    for (int jj = 0; jj < 4; ++jj) sv[jj] = srow[256 * jj];
#pragma unroll
    for (int tl = 0; tl < 16; ++tl) {
      const float w = at[tl][sl];
#pragma unroll
      for (int jj = 0; jj < 4; ++jj) acc[tl][jj] = fmaf(w, sv[jj], acc[tl][jj]);
    }
  }
#pragma unroll
  for (int tl = 0; tl < 16; ++tl)
#pragma unroll
    for (int jj = 0; jj < 4; ++jj)
      atomicAdd(&ctx[(size_t)(b * T_ + t0 + tl) * D_ + tid + 256 * jj], acc[tl][jj]);
}

// ---- F6b: hidden += [ctx, query]_kslice @ Wc (+bc on slice 0). Split-K atomics. ----
__global__ __launch_bounds__(256) void f6b_outproj(const float* __restrict__ ctx, const float* __restrict__ query,
                                                   const float* __restrict__ Wc, const float* __restrict__ bc,
                                                   float* __restrict__ out_hid) {
  __shared__ float cq[16][128];
  const int c0 = blockIdx.x * 128, r0 = blockIdx.y * 16, k0 = blockIdx.z * 128;
  const int tid = threadIdx.x;
  const int cl = tid & 127, rh = tid >> 7;
  for (int i = tid; i < 16 * 128; i += 256) {
    const int rl = i >> 7, kk = i & 127;
    const int k = k0 + kk, row = r0 + rl;
    cq[rl][kk] = (k < D_) ? ctx[(size_t)row * D_ + k] : query[(size_t)row * H_ + k - D_];
  }
  __syncthreads();
  float acc[8] = {};
  for (int kk = 0; kk < 128; ++kk) {
    const float w = Wc[(size_t)(k0 + kk) * H_ + c0 + cl];
#pragma unroll
    for (int rr = 0; rr < 8; ++rr) acc[rr] = fmaf(cq[rh * 8 + rr][kk], w, acc[rr]);
  }
  const float bb = (blockIdx.z == 0) ? bc[c0 + cl] : 0.f;
#pragma unroll
  for (int rr = 0; rr < 8; ++rr)
    atomicAdd(&out_hid[(size_t)(r0 + rh * 8 + rr) * H_ + c0 + cl], acc[rr] + bb);
}

// ================= FALLBACK (round-7, passing) =================

__global__ __launch_bounds__(256) void k1_qf(const float* __restrict__ query, const float* __restrict__ Wq,
                                             const float* __restrict__ bq, float* __restrict__ qf) {
  const int r = blockIdx.x;
  const int tid = threadIdx.x;
  __shared__ float q[H_];
  for (int i = tid; i < H_; i += 256) q[i] = query[(size_t)r * H_ + i];
  __syncthreads();
#pragma unroll
  for (int jj = 0; jj < 4; ++jj) {
    const int j = tid + 256 * jj;
    float acc = bq[j];
    for (int k = 0; k < H_; ++k) acc = fmaf(q[k], Wq[(size_t)k * D_ + j], acc);
    qf[(size_t)r * D_ + j] = acc;
  }
}

__global__ __launch_bounds__(256) void k23_align(const float* __restrict__ states, const float* __restrict__ Ws,
                                                 const float* __restrict__ v, const float* __restrict__ qf,
                                                 float* __restrict__ alg) {
  const int b = blockIdx.x >> 6;
  const int s0 = (blockIdx.x & 63) * 16;
  const int tid = threadIdx.x, lane = tid & 63, wv = tid >> 6;
  __shared__ u16 stL[16 * D_];
  __shared__ float vvL[D_];
  __shared__ float red[16 * 4];
  for (int i = tid; i < 16 * D_; i += 256) {
    const int row = i >> 10, col = i & (D_ - 1);
    stL[i] = f2bf(states[((size_t)b * S_ + s0 + row) * D_ + col]);
  }
  for (int i = tid; i < D_; i += 256) vvL[i] = v[i];
  __syncthreads();
  float acc[64];
#pragma unroll
  for (int i = 0; i < 64; ++i) acc[i] = 0.f;
#pragma unroll 4
  for (int k = 0; k < D_; ++k) {
    float wsv[4];
#pragma unroll
    for (int jj = 0; jj < 4; ++jj) wsv[jj] = Ws[(size_t)k * D_ + tid + 256 * jj];
#pragma unroll
    for (int i = 0; i < 16; ++i) {
      const float sv = bf2f(stL[i * D_ + k]);
#pragma unroll
      for (int jj = 0; jj < 4; ++jj) acc[i * 4 + jj] = fmaf(sv, wsv[jj], acc[i * 4 + jj]);
    }
  }
  for (int t = 0; t < T_; ++t) {
    float qv[4];
#pragma unroll
    for (int jj = 0; jj < 4; ++jj) qv[jj] = qf[((size_t)b * T_ + t) * D_ + tid + 256 * jj];
    float part[16];
#pragma unroll
    for (int i = 0; i < 16; ++i) {
      float p = 0.f;
#pragma unroll
      for (int jj = 0; jj < 4; ++jj)
        p = fmaf(vvL[tid + 256 * jj], tanhf(qv[jj] + acc[i * 4 + jj]), p);
      part[i] = p;
    }
#pragma unroll
    for (int i = 0; i < 16; ++i) {
      float x = part[i];
#pragma unroll
      for (int off = 32; off > 0; off >>= 1) x += __shfl_xor(x, off);
      if (lane == 0) red[i * 4 + wv] = x;
    }
    __syncthreads();
    if (tid < 16)
      alg[((size_t)b * T_ + t) * S_ + s0 + tid] =
          red[tid * 4 + 0] + red[tid * 4 + 1] + red[tid * 4 + 2] + red[tid * 4 + 3];
    __syncthreads();
  }
}

__global__ __launch_bounds__(256) void k4_softmax(const float* __restrict__ alg, const int* __restrict__ mask,
                                                  float* __restrict__ attn) {
  const int r = blockIdx.x;
  const int b = r >> 5;
  const int tid = threadIdx.x;
  __shared__ float red[256];
  float a[4];
#pragma unroll
  for (int jj = 0; jj < 4; ++jj) {
    const int s = tid + 256 * jj;
    const float x = alg[(size_t)r * S_ + s];
    a[jj] = (mask[(size_t)b * S_ + s] != 0) ? x : -3.0e38f;
  }
  float m = fmaxf(fmaxf(a[0], a[1]), fmaxf(a[2], a[3]));
  red[tid] = m; __syncthreads();
  for (int st = 128; st > 0; st >>= 1) { if (tid < st) red[tid] = fmaxf(red[tid], red[tid + st]); __syncthreads(); }
  m = red[0]; __syncthreads();
  float e[4], lsum = 0.f;
#pragma unroll
  for (int jj = 0; jj < 4; ++jj) {
    e[jj] = (a[jj] > -1.0e38f) ? expf(a[jj] - m) : 0.f;
    lsum += e[jj];
  }
  red[tid] = lsum; __syncthreads();
  for (int st = 128; st > 0; st >>= 1) { if (tid < st) red[tid] += red[tid + st]; __syncthreads(); }
  const float rs = 1.f / red[0];
#pragma unroll
  for (int jj = 0; jj < 4; ++jj)
    attn[(size_t)r * S_ + tid + 256 * jj] = e[jj] * rs;
}

__global__ __launch_bounds__(256) void k56_ctx_proj(const float* __restrict__ attn, const float* __restrict__ states,
                                                    const float* __restrict__ query, const float* __restrict__ Wc,
                                                    const float* __restrict__ bc,
                                                    float* __restrict__ out_ctx, float* __restrict__ out_hid,
                                                    float* __restrict__ out_at) {
  const int r = blockIdx.x;
  const int b = r >> 5, t = r & (T_ - 1);
  const int tid = threadIdx.x;
  __shared__ float pr[S_];
  __shared__ float cq[D_ + H_];
  for (int s = tid; s < S_; s += 256) pr[s] = attn[(size_t)r * S_ + s];
  __syncthreads();
  for (int s = tid; s < S_; s += 256) out_at[((size_t)b * S_ + s) * T_ + t] = pr[s];
  float acc[4] = {0.f, 0.f, 0.f, 0.f};
  for (int s = 0; s < S_; ++s) {
    const float w = pr[s];
    const float* srow = states + ((size_t)b * S_ + s) * D_ + tid;
#pragma unroll
    for (int jj = 0; jj < 4; ++jj) acc[jj] = fmaf(w, srow[256 * jj], acc[jj]);
  }
#pragma unroll
  for (int jj = 0; jj < 4; ++jj) {
    cq[tid + 256 * jj] = acc[jj];
    out_ctx[(size_t)r * D_ + tid + 256 * jj] = acc[jj];
  }
  for (int i = tid; i < H_; i += 256) cq[D_ + i] = query[(size_t)r * H_ + i];
  __syncthreads();
#pragma unroll
  for (int jj = 0; jj < 2; ++jj) {
    const int n = tid + 256 * jj;
    float h = bc[n];
    for (int k = 0; k < D_ + H_; ++k) h = fmaf(cq[k], Wc[(size_t)k * H_ + n], h);
    out_hid[(size_t)r * H_ + n] = h;
  }
}

extern "C" void kernel_launch(void* const* d_in, const int* in_sizes, int n_in,
                              void* d_out, int out_size, void* d_ws, size_t ws_size,
                              hipStream_t stream) {
  const float* query  = (const float*)d_in[0];
  const float* states = (const float*)d_in[1];
  const int*   mask   = (const int*)d_in[2];
  const float* Wq     = (const float*)d_in[3];
  const float* bq     = (const float*)d_in[4];
  const float* Ws     = (const float*)d_in[5];
  const float* v      = (const float*)d_in[6];
  const float* Wc     = (const float*)d_in[7];
  const float* bc     = (const float*)d_in[8];

  float* A  = (float*)d_out;               // qf -> ctx(final)
  float* Bh = A + (size_t)BT_ * D_;        // hidden
  float* C  = Bh + (size_t)BT_ * H_;       // alg -> attn_t

  const size_t WS_NEED = 8388608 + 2097152 + 524288;   // sfb + WsT + attn
  if (ws_size >= WS_NEED) {
    char* ws = (char*)d_ws;
    u16*   sfb  = (u16*)(ws + 0);              // 8 MB
    u16*   WsT  = (u16*)(ws + 8388608);        // 2 MB
    float* attn = (float*)(ws + 10485760);     // 512 KB

    (void)hipMemsetAsync(A, 0, (size_t)BT_ * D_ * 4, stream);    // qf zero (split-K f1)
    (void)hipMemsetAsync(Bh, 0, (size_t)BT_ * H_ * 4, stream);   // hidden zero (split-K f6)
    f1b_qf<<<dim3(4, 16, 4), 256, 0, stream>>>(query, Wq, bq, A);
    f0_transpose<<<dim3(16, 32), 256, 0, stream>>>(Ws, WsT);
    f2_sfgemm<<<dim3(16, 64), 256, 0, stream>>>(states, WsT, sfb);
    f3b_align<<<dim3(BT_, 4), 256, 0, stream>>>(A, sfb, v, C);
    (void)hipMemsetAsync(A, 0, (size_t)BT_ * D_ * 4, stream);    // ctx zero (qf dead)
    f4_softmax<<<BT_, 256, 0, stream>>>(C, mask, attn);
    f5_context<<<dim3(16, 2, 4), 256, 0, stream>>>(attn, states, A, C);
    f6b_outproj<<<dim3(4, 8, 12), 256, 0, stream>>>(A, query, Wc, bc, Bh);
  } else {
    k1_qf<<<BT_, 256, 0, stream>>>(query, Wq, bq, A);
    k23_align<<<B_ * (S_ / 16), 256, 0, stream>>>(states, Ws, v, A, C);
    k4_softmax<<<BT_, 256, 0, stream>>>(C, mask, A);
    k56_ctx_proj<<<BT_, 256, 0, stream>>>(A, states, query, Wc, bc, A, Bh, C);
  }
}

// Round 11
// 211.453 us; speedup vs baseline: 3.4541x; 1.0440x over previous
//
#include <hip/hip_runtime.h>
#include <math.h>

// Bahdanau additive attention. B=4, T=32, S=1024, H=512, D=2H=1024.
// Inputs fp32 (mask int32), OUTPUT fp32 flat:
//   context (4,32,1024) | hidden (4,32,512) | attn_t (4,1024,32)
// Round 11: f3c (16 waves/CU + reg double-buffer prefetch); tier-2 ws path:
// states pre-converted to bf16 so f2b stages A without VALU converts.
// d_out overlay: A[0,131072): (memset)->qf -> (memset)->ctx(final)
//                B[131072,196608): (memset)->hidden(final)
//                C[196608,327680): alg -> attn_t(final)

typedef unsigned short u16;
typedef __bf16 bf16x8 __attribute__((ext_vector_type(8)));
typedef float floatx4 __attribute__((ext_vector_type(4)));

#define B_ 4
#define T_ 32
#define S_ 1024
#define H_ 512
#define D_ 1024
#define BT_ 128
#define TWO_LOG2E 2.8853900817779268f   // tanh(y) = 1 - 2/(exp2(2*log2e*y)+1)

__device__ __forceinline__ float bf2f(u16 u) {
  unsigned int i = ((unsigned int)u) << 16;
  return __builtin_bit_cast(float, i);
}
__device__ __forceinline__ u16 f2bf(float f) {
  unsigned int i = __builtin_bit_cast(unsigned int, f);
  i += 0x7fffu + ((i >> 16) & 1u);  // RNE
  return (u16)(i >> 16);
}

// ================= FAST PATH =================

// ---- KC: states fp32 -> bf16 (sbf). 4M elems, 8/thread ----
__global__ __launch_bounds__(256) void kc_cvt(const float* __restrict__ in, u16* __restrict__ out) {
  const size_t i0 = ((size_t)blockIdx.x * 256 + threadIdx.x) * 8;
  float4 a = *(const float4*)(in + i0);
  float4 b = *(const float4*)(in + i0 + 4);
  union { uint4 v; u16 s[8]; } r;
  r.s[0] = f2bf(a.x); r.s[1] = f2bf(a.y); r.s[2] = f2bf(a.z); r.s[3] = f2bf(a.w);
  r.s[4] = f2bf(b.x); r.s[5] = f2bf(b.y); r.s[6] = f2bf(b.z); r.s[7] = f2bf(b.w);
  *(uint4*)(out + i0) = r.v;
}

// ---- F1b: qf += 2log2e*(query_kslice @ Wq) (+2log2e*bq on slice 0). Split-K atomics. ----
__global__ __launch_bounds__(256) void f1b_qf(const float* __restrict__ query, const float* __restrict__ Wq,
                                              const float* __restrict__ bq, float* __restrict__ qf) {
  __shared__ float q[8][128];
  const int c0 = blockIdx.x * 256, r0 = blockIdx.y * 8, k0 = blockIdx.z * 128;
  const int tid = threadIdx.x;
  for (int i = tid; i < 8 * 128; i += 256) {
    const int rl = i >> 7, kk = i & 127;
    q[rl][kk] = query[(size_t)(r0 + rl) * H_ + k0 + kk];
  }
  __syncthreads();
  const int col = c0 + tid;
  float acc[8] = {};
  for (int kk = 0; kk < 128; ++kk) {
    const float w = Wq[(size_t)(k0 + kk) * D_ + col];
#pragma unroll
    for (int r = 0; r < 8; ++r) acc[r] = fmaf(q[r][kk], w, acc[r]);
  }
  const float bb = (blockIdx.z == 0) ? bq[col] : 0.f;
#pragma unroll
  for (int r = 0; r < 8; ++r)
    atomicAdd(&qf[(size_t)(r0 + r) * D_ + col], TWO_LOG2E * (acc[r] + bb));
}

// ---- F0: transpose Ws fp32 (k x n) -> WsT bf16 (n-major, k-contig) ----
__global__ __launch_bounds__(256) void f0_transpose(const float* __restrict__ Ws, u16* __restrict__ WsT) {
  __shared__ u16 tile[32][65];
  const int n0 = blockIdx.x * 64, k0 = blockIdx.y * 32;
  const int t = threadIdx.x;
  {
    const int kr = t >> 3, nc = (t & 7) * 8;
    const float* p = Ws + (size_t)(k0 + kr) * D_ + n0 + nc;
    float4 a = *(const float4*)p, b = *(const float4*)(p + 4);
    tile[kr][nc + 0] = f2bf(a.x); tile[kr][nc + 1] = f2bf(a.y);
    tile[kr][nc + 2] = f2bf(a.z); tile[kr][nc + 3] = f2bf(a.w);
    tile[kr][nc + 4] = f2bf(b.x); tile[kr][nc + 5] = f2bf(b.y);
    tile[kr][nc + 6] = f2bf(b.z); tile[kr][nc + 7] = f2bf(b.w);
  }
  __syncthreads();
  {
    const int nr = t >> 2, kc = (t & 3) * 8;
    union { uint4 v; u16 s[8]; } st;
#pragma unroll
    for (int i = 0; i < 8; ++i) st.s[i] = tile[kc + i][nr];
    *(uint4*)(WsT + (size_t)(n0 + nr) * D_ + k0 + kc) = st.v;
  }
}

// ---- F2 (tier1): sfb = 2log2e*(states_fp32 @ Ws) bf16 out. MFMA, 64x64 tile ----
__global__ __launch_bounds__(256) void f2_sfgemm(const float* __restrict__ A, const u16* __restrict__ BT,
                                                 u16* __restrict__ Cb) {
  __shared__ __align__(16) u16 sA[64 * 40];
  __shared__ __align__(16) u16 sB[64 * 40];
  const int bm0 = blockIdx.y * 64, bn0 = blockIdx.x * 64;
  const int t = threadIdx.x;
  const int lrow = t >> 2, lk = (t & 3) * 8;
  const int wid = t >> 6, lane = t & 63;
  const int wm = (wid >> 1) * 32, wn = (wid & 1) * 32;
  const int fm = lane & 15, fq = lane >> 4;

  floatx4 acc[2][2];
  const floatx4 fz = {0.f, 0.f, 0.f, 0.f};
  acc[0][0] = fz; acc[0][1] = fz; acc[1][0] = fz; acc[1][1] = fz;

  const float* gA = A + (size_t)(bm0 + lrow) * D_ + lk;
  const uint4* gB = (const uint4*)(BT + (size_t)(bn0 + lrow) * D_ + lk);

  for (int k0 = 0; k0 < D_; k0 += 32) {
    float4 a0 = *(const float4*)(gA + k0);
    float4 a1 = *(const float4*)(gA + k0 + 4);
    uint4 vb = gB[k0 >> 3];
    union { uint4 v; u16 s[8]; } pa;
    pa.s[0] = f2bf(a0.x); pa.s[1] = f2bf(a0.y); pa.s[2] = f2bf(a0.z); pa.s[3] = f2bf(a0.w);
    pa.s[4] = f2bf(a1.x); pa.s[5] = f2bf(a1.y); pa.s[6] = f2bf(a1.z); pa.s[7] = f2bf(a1.w);
    __syncthreads();
    *(uint4*)&sA[lrow * 40 + lk] = pa.v;
    *(uint4*)&sB[lrow * 40 + lk] = vb;
    __syncthreads();
    bf16x8 af[2], bfr[2];
#pragma unroll
    for (int i = 0; i < 2; ++i) af[i] = *(const bf16x8*)&sA[(wm + i * 16 + fm) * 40 + fq * 8];
#pragma unroll
    for (int j = 0; j < 2; ++j) bfr[j] = *(const bf16x8*)&sB[(wn + j * 16 + fm) * 40 + fq * 8];
#pragma unroll
    for (int i = 0; i < 2; ++i)
#pragma unroll
      for (int j = 0; j < 2; ++j)
        acc[i][j] = __builtin_amdgcn_mfma_f32_16x16x32_bf16(af[i], bfr[j], acc[i][j], 0, 0, 0);
  }
#pragma unroll
  for (int i = 0; i < 2; ++i)
#pragma unroll
    for (int j = 0; j < 2; ++j)
#pragma unroll
      for (int r = 0; r < 4; ++r) {
        const int row = bm0 + wm + i * 16 + fq * 4 + r;   // col=lane&15, row=quad*4+reg (m89)
        const int col = bn0 + wn + j * 16 + fm;
        Cb[(size_t)row * D_ + col] = f2bf(TWO_LOG2E * acc[i][j][r]);
      }
}

// ---- F2b (tier2): same but A pre-converted bf16 -> raw uint4 staging, no cvt ----
__global__ __launch_bounds__(256) void f2b_sfgemm(const u16* __restrict__ A, const u16* __restrict__ BT,
                                                  u16* __restrict__ Cb) {
  __shared__ __align__(16) u16 sA[64 * 40];
  __shared__ __align__(16) u16 sB[64 * 40];
  const int bm0 = blockIdx.y * 64, bn0 = blockIdx.x * 64;
  const int t = threadIdx.x;
  const int lrow = t >> 2, lk = (t & 3) * 8;
  const int wid = t >> 6, lane = t & 63;
  const int wm = (wid >> 1) * 32, wn = (wid & 1) * 32;
  const int fm = lane & 15, fq = lane >> 4;

  floatx4 acc[2][2];
  const floatx4 fz = {0.f, 0.f, 0.f, 0.f};
  acc[0][0] = fz; acc[0][1] = fz; acc[1][0] = fz; acc[1][1] = fz;

  const uint4* gA = (const uint4*)(A + (size_t)(bm0 + lrow) * D_ + lk);
  const uint4* gB = (const uint4*)(BT + (size_t)(bn0 + lrow) * D_ + lk);

  for (int k0 = 0; k0 < D_; k0 += 32) {
    uint4 va = gA[k0 >> 3];
    uint4 vb = gB[k0 >> 3];
    __syncthreads();
    *(uint4*)&sA[lrow * 40 + lk] = va;
    *(uint4*)&sB[lrow * 40 + lk] = vb;
    __syncthreads();
    bf16x8 af[2], bfr[2];
#pragma unroll
    for (int i = 0; i < 2; ++i) af[i] = *(const bf16x8*)&sA[(wm + i * 16 + fm) * 40 + fq * 8];
#pragma unroll
    for (int j = 0; j < 2; ++j) bfr[j] = *(const bf16x8*)&sB[(wn + j * 16 + fm) * 40 + fq * 8];
#pragma unroll
    for (int i = 0; i < 2; ++i)
#pragma unroll
      for (int j = 0; j < 2; ++j)
        acc[i][j] = __builtin_amdgcn_mfma_f32_16x16x32_bf16(af[i], bfr[j], acc[i][j], 0, 0, 0);
  }
#pragma unroll
  for (int i = 0; i < 2; ++i)
#pragma unroll
    for (int j = 0; j < 2; ++j)
#pragma unroll
      for (int r = 0; r < 4; ++r) {
        const int row = bm0 + wm + i * 16 + fq * 4 + r;
        const int col = bn0 + wn + j * 16 + fm;
        Cb[(size_t)row * D_ + col] = f2bf(TWO_LOG2E * acc[i][j][r]);
      }
}

// ---- F3c: alg = v . tanh(qf+sf). Grid (128 bt, 8 s-chunks of 128) = 1024 blocks. ----
// Wave owns 32 s-rows; q/v in regs (lane owns d in [16*lane,16*lane+16));
// sf rows streamed bf16 with register double-buffer prefetch.
__global__ __launch_bounds__(256) void f3c_align(const float* __restrict__ qf, const u16* __restrict__ sfb,
                                                 const float* __restrict__ v, float* __restrict__ alg) {
  const int bt = blockIdx.x;                   // b*T+t
  const int b = bt >> 5;
  const int chunk = blockIdx.y;                // 0..7
  const int tid = threadIdx.x, lane = tid & 63, wv = tid >> 6;
  const int s0 = chunk * 128 + wv * 32;        // this wave's 32 s-rows
  __shared__ float res[128];

  float qv[16], vr[16];
  {
    const float* qp = qf + (size_t)bt * D_ + lane * 16;
    const float* vp = v + lane * 16;
#pragma unroll
    for (int c = 0; c < 4; ++c) {
      float4 a = *(const float4*)(qp + 4 * c);
      float4 w = *(const float4*)(vp + 4 * c);
      qv[4 * c + 0] = a.x; qv[4 * c + 1] = a.y; qv[4 * c + 2] = a.z; qv[4 * c + 3] = a.w;
      vr[4 * c + 0] = w.x; vr[4 * c + 1] = w.y; vr[4 * c + 2] = w.z; vr[4 * c + 3] = w.w;
    }
  }

  // sf row = 1024 u16 = 128 uint4; this lane's 32B slice at uint4 index lane*2.
  const uint4* sp = (const uint4*)(sfb + ((size_t)b * S_ + s0) * D_ + lane * 16);
  union { uint4 v[2]; u16 s[16]; } cur, nxt;
  cur.v[0] = sp[0]; cur.v[1] = sp[1];
  for (int i = 0; i < 32; ++i) {
    // Prefetch next row (i=31 strays one row past: lands in WsT region, allocated in d_ws).
    nxt.v[0] = sp[(size_t)(i + 1) * 128];
    nxt.v[1] = sp[(size_t)(i + 1) * 128 + 1];
    float sum = 0.f;
#pragma unroll
    for (int j = 0; j < 16; ++j) {
      const float x = qv[j] + bf2f(cur.s[j]);                  // prescaled by 2log2e
      const float e = __builtin_amdgcn_exp2f(x);
      sum = fmaf(vr[j], fmaf(-2.f, __builtin_amdgcn_rcpf(e + 1.f), 1.f), sum);
    }
#pragma unroll
    for (int off = 32; off > 0; off >>= 1) sum += __shfl_xor(sum, off);
    if (lane == 0) res[wv * 32 + i] = sum;
    cur.v[0] = nxt.v[0]; cur.v[1] = nxt.v[1];
  }
  __syncthreads();
  if (tid < 128) alg[(size_t)bt * S_ + chunk * 128 + tid] = res[tid];
}

// ---- F4: masked softmax; alg(C) -> attn fp32 (ws) ----
__global__ __launch_bounds__(256) void f4_softmax(const float* __restrict__ alg, const int* __restrict__ mask,
                                                  float* __restrict__ attn) {
  const int r = blockIdx.x;
  const int b = r >> 5;
  const int tid = threadIdx.x;
  __shared__ float red[256];
  float a[4];
#pragma unroll
  for (int jj = 0; jj < 4; ++jj) {
    const int s = tid + 256 * jj;
    const float x = alg[(size_t)r * S_ + s];
    a[jj] = (mask[(size_t)b * S_ + s] != 0) ? x : -3.0e38f;
  }
  float m = fmaxf(fmaxf(a[0], a[1]), fmaxf(a[2], a[3]));
  red[tid] = m; __syncthreads();
  for (int st = 128; st > 0; st >>= 1) { if (tid < st) red[tid] = fmaxf(red[tid], red[tid + st]); __syncthreads(); }
  m = red[0]; __syncthreads();
  float e[4], lsum = 0.f;
#pragma unroll
  for (int jj = 0; jj < 4; ++jj) {
    e[jj] = (a[jj] > -1.0e38f) ? expf(a[jj] - m) : 0.f;
    lsum += e[jj];
  }
  red[tid] = lsum; __syncthreads();
  for (int st = 128; st > 0; st >>= 1) { if (tid < st) red[tid] += red[tid + st]; __syncthreads(); }
  const float rs = 1.f / red[0];
#pragma unroll
  for (int jj = 0; jj < 4; ++jj)
    attn[(size_t)r * S_ + tid + 256 * jj] = e[jj] * rs;
}

// ---- F5: ctx += attn @ states (t-shared tiles, fp32 atomics); also write attn_t ----
__global__ __launch_bounds__(256) void f5_context(const float* __restrict__ attn, const float* __restrict__ states,
                                                  float* __restrict__ ctx, float* __restrict__ out_at) {
  __shared__ float at[16][64];
  const int s0 = blockIdx.x * 64, t0 = blockIdx.y * 16, b = blockIdx.z;
  const int tid = threadIdx.x;
  for (int i = tid; i < 16 * 64; i += 256) {
    const int tl = i >> 6, sl = i & 63;
    at[tl][sl] = attn[(size_t)(b * T_ + t0 + tl) * S_ + s0 + sl];
  }
  __syncthreads();
  for (int i = tid; i < 64 * 16; i += 256) {
    const int sl = i >> 4, tl = i & 15;
    out_at[((size_t)b * S_ + s0 + sl) * T_ + t0 + tl] = at[tl][sl];
  }
  float acc[16][4] = {};
  for (int sl = 0; sl < 64; ++sl) {
    const float* srow = states + ((size_t)b * S_ + s0 + sl) * D_ + tid;
    float sv[4];
#pragma unroll
    for (int jj = 0; jj < 4; ++jj) sv[jj] = srow[256 * jj];
#pragma unroll
    for (int tl = 0; tl < 16; ++tl) {
      const float w = at[tl][sl];
#pragma unroll
      for (int jj = 0; jj < 4; ++jj) acc[tl][jj] = fmaf(w, sv[jj], acc[tl][jj]);
    }
  }
#pragma unroll
  for (int tl = 0; tl < 16; ++tl)
#pragma unroll
    for (int jj = 0; jj < 4; ++jj)
      atomicAdd(&ctx[(size_t)(b * T_ + t0 + tl) * D_ + tid + 256 * jj], acc[tl][jj]);
}

// ---- F6b: hidden += [ctx, query]_kslice @ Wc (+bc on slice 0). Split-K atomics. ----
__global__ __launch_bounds__(256) void f6b_outproj(const float* __restrict__ ctx, const float* __restrict__ query,
                                                   const float* __restrict__ Wc, const float* __restrict__ bc,
                                                   float* __restrict__ out_hid) {
  __shared__ float cq[16][128];
  const int c0 = blockIdx.x * 128, r0 = blockIdx.y * 16, k0 = blockIdx.z * 128;
  const int tid = threadIdx.x;
  const int cl = tid & 127, rh = tid >> 7;
  for (int i = tid; i < 16 * 128; i += 256) {
    const int rl = i >> 7, kk = i & 127;
    const int k = k0 + kk, row = r0 + rl;
    cq[rl][kk] = (k < D_) ? ctx[(size_t)row * D_ + k] : query[(size_t)row * H_ + k - D_];
  }
  __syncthreads();
  float acc[8] = {};
  for (int kk = 0; kk < 128; ++kk) {
    const float w = Wc[(size_t)(k0 + kk) * H_ + c0 + cl];
#pragma unroll
    for (int rr = 0; rr < 8; ++rr) acc[rr] = fmaf(cq[rh * 8 + rr][kk], w, acc[rr]);
  }
  const float bb = (blockIdx.z == 0) ? bc[c0 + cl] : 0.f;
#pragma unroll
  for (int rr = 0; rr < 8; ++rr)
    atomicAdd(&out_hid[(size_t)(r0 + rh * 8 + rr) * H_ + c0 + cl], acc[rr] + bb);
}

// ================= FALLBACK (round-7, passing) =================

__global__ __launch_bounds__(256) void k1_qf(const float* __restrict__ query, const float* __restrict__ Wq,
                                             const float* __restrict__ bq, float* __restrict__ qf) {
  const int r = blockIdx.x;
  const int tid = threadIdx.x;
  __shared__ float q[H_];
  for (int i = tid; i < H_; i += 256) q[i] = query[(size_t)r * H_ + i];
  __syncthreads();
#pragma unroll
  for (int jj = 0; jj < 4; ++jj) {
    const int j = tid + 256 * jj;
    float acc = bq[j];
    for (int k = 0; k < H_; ++k) acc = fmaf(q[k], Wq[(size_t)k * D_ + j], acc);
    qf[(size_t)r * D_ + j] = acc;
  }
}

__global__ __launch_bounds__(256) void k23_align(const float* __restrict__ states, const float* __restrict__ Ws,
                                                 const float* __restrict__ v, const float* __restrict__ qf,
                                                 float* __restrict__ alg) {
  const int b = blockIdx.x >> 6;
  const int s0 = (blockIdx.x & 63) * 16;
  const int tid = threadIdx.x, lane = tid & 63, wv = tid >> 6;
  __shared__ u16 stL[16 * D_];
  __shared__ float vvL[D_];
  __shared__ float red[16 * 4];
  for (int i = tid; i < 16 * D_; i += 256) {
    const int row = i >> 10, col = i & (D_ - 1);
    stL[i] = f2bf(states[((size_t)b * S_ + s0 + row) * D_ + col]);
  }
  for (int i = tid; i < D_; i += 256) vvL[i] = v[i];
  __syncthreads();
  float acc[64];
#pragma unroll
  for (int i = 0; i < 64; ++i) acc[i] = 0.f;
#pragma unroll 4
  for (int k = 0; k < D_; ++k) {
    float wsv[4];
#pragma unroll
    for (int jj = 0; jj < 4; ++jj) wsv[jj] = Ws[(size_t)k * D_ + tid + 256 * jj];
#pragma unroll
    for (int i = 0; i < 16; ++i) {
      const float sv = bf2f(stL[i * D_ + k]);
#pragma unroll
      for (int jj = 0; jj < 4; ++jj) acc[i * 4 + jj] = fmaf(sv, wsv[jj], acc[i * 4 + jj]);
    }
  }
  for (int t = 0; t < T_; ++t) {
    float qv[4];
#pragma unroll
    for (int jj = 0; jj < 4; ++jj) qv[jj] = qf[((size_t)b * T_ + t) * D_ + tid + 256 * jj];
    float part[16];
#pragma unroll
    for (int i = 0; i < 16; ++i) {
      float p = 0.f;
#pragma unroll
      for (int jj = 0; jj < 4; ++jj)
        p = fmaf(vvL[tid + 256 * jj], tanhf(qv[jj] + acc[i * 4 + jj]), p);
      part[i] = p;
    }
#pragma unroll
    for (int i = 0; i < 16; ++i) {
      float x = part[i];
#pragma unroll
      for (int off = 32; off > 0; off >>= 1) x += __shfl_xor(x, off);
      if (lane == 0) red[i * 4 + wv] = x;
    }
    __syncthreads();
    if (tid < 16)
      alg[((size_t)b * T_ + t) * S_ + s0 + tid] =
          red[tid * 4 + 0] + red[tid * 4 + 1] + red[tid * 4 + 2] + red[tid * 4 + 3];
    __syncthreads();
  }
}

__global__ __launch_bounds__(256) void k4_softmax(const float* __restrict__ alg, const int* __restrict__ mask,
                                                  float* __restrict__ attn) {
  const int r = blockIdx.x;
  const int b = r >> 5;
  const int tid = threadIdx.x;
  __shared__ float red[256];
  float a[4];
#pragma unroll
  for (int jj = 0; jj < 4; ++jj) {
    const int s = tid + 256 * jj;
    const float x = alg[(size_t)r * S_ + s];
    a[jj] = (mask[(size_t)b * S_ + s] != 0) ? x : -3.0e38f;
  }
  float m = fmaxf(fmaxf(a[0], a[1]), fmaxf(a[2], a[3]));
  red[tid] = m; __syncthreads();
  for (int st = 128; st > 0; st >>= 1) { if (tid < st) red[tid] = fmaxf(red[tid], red[tid + st]); __syncthreads(); }
  m = red[0]; __syncthreads();
  float e[4], lsum = 0.f;
#pragma unroll
  for (int jj = 0; jj < 4; ++jj) {
    e[jj] = (a[jj] > -1.0e38f) ? expf(a[jj] - m) : 0.f;
    lsum += e[jj];
  }
  red[tid] = lsum; __syncthreads();
  for (int st = 128; st > 0; st >>= 1) { if (tid < st) red[tid] += red[tid + st]; __syncthreads(); }
  const float rs = 1.f / red[0];
#pragma unroll
  for (int jj = 0; jj < 4; ++jj)
    attn[(size_t)r * S_ + tid + 256 * jj] = e[jj] * rs;
}

__global__ __launch_bounds__(256) void k56_ctx_proj(const float* __restrict__ attn, const float* __restrict__ states,
                                                    const float* __restrict__ query, const float* __restrict__ Wc,
                                                    const float* __restrict__ bc,
                                                    float* __restrict__ out_ctx, float* __restrict__ out_hid,
                                                    float* __restrict__ out_at) {
  const int r = blockIdx.x;
  const int b = r >> 5, t = r & (T_ - 1);
  const int tid = threadIdx.x;
  __shared__ float pr[S_];
  __shared__ float cq[D_ + H_];
  for (int s = tid; s < S_; s += 256) pr[s] = attn[(size_t)r * S_ + s];
  __syncthreads();
  for (int s = tid; s < S_; s += 256) out_at[((size_t)b * S_ + s) * T_ + t] = pr[s];
  float acc[4] = {0.f, 0.f, 0.f, 0.f};
  for (int s = 0; s < S_; ++s) {
    const float w = pr[s];
    const float* srow = states + ((size_t)b * S_ + s) * D_ + tid;
#pragma unroll
    for (int jj = 0; jj < 4; ++jj) acc[jj] = fmaf(w, srow[256 * jj], acc[jj]);
  }
#pragma unroll
  for (int jj = 0; jj < 4; ++jj) {
    cq[tid + 256 * jj] = acc[jj];
    out_ctx[(size_t)r * D_ + tid + 256 * jj] = acc[jj];
  }
  for (int i = tid; i < H_; i += 256) cq[D_ + i] = query[(size_t)r * H_ + i];
  __syncthreads();
#pragma unroll
  for (int jj = 0; jj < 2; ++jj) {
    const int n = tid + 256 * jj;
    float h = bc[n];
    for (int k = 0; k < D_ + H_; ++k) h = fmaf(cq[k], Wc[(size_t)k * H_ + n], h);
    out_hid[(size_t)r * H_ + n] = h;
  }
}

extern "C" void kernel_launch(void* const* d_in, const int* in_sizes, int n_in,
                              void* d_out, int out_size, void* d_ws, size_t ws_size,
                              hipStream_t stream) {
  const float* query  = (const float*)d_in[0];
  const float* states = (const float*)d_in[1];
  const int*   mask   = (const int*)d_in[2];
  const float* Wq     = (const float*)d_in[3];
  const float* bq     = (const float*)d_in[4];
  const float* Ws     = (const float*)d_in[5];
  const float* v      = (const float*)d_in[6];
  const float* Wc     = (const float*)d_in[7];
  const float* bc     = (const float*)d_in[8];

  float* A  = (float*)d_out;               // qf -> ctx(final)
  float* Bh = A + (size_t)BT_ * D_;        // hidden
  float* C  = Bh + (size_t)BT_ * H_;       // alg -> attn_t

  const size_t WS_T1 = 8388608 + 2097152 + 524288;            // sfb + WsT + attn = 11 MB
  const size_t WS_T2 = WS_T1 + 8388608;                       // + sbf = 19.4 MB
  if (ws_size >= WS_T1) {
    char* ws = (char*)d_ws;
    u16*   sfb  = (u16*)(ws + 0);              // 8 MB
    u16*   WsT  = (u16*)(ws + 8388608);        // 2 MB
    float* attn = (float*)(ws + 10485760);     // 512 KB
    u16*   sbf  = (u16*)(ws + 11010048);       // 8 MB (tier2 only)

    (void)hipMemsetAsync(A, 0, (size_t)BT_ * D_ * 4, stream);    // qf zero (split-K f1)
    (void)hipMemsetAsync(Bh, 0, (size_t)BT_ * H_ * 4, stream);   // hidden zero (split-K f6)
    f1b_qf<<<dim3(4, 16, 4), 256, 0, stream>>>(query, Wq, bq, A);
    f0_transpose<<<dim3(16, 32), 256, 0, stream>>>(Ws, WsT);
    if (ws_size >= WS_T2) {
      kc_cvt<<<2048, 256, 0, stream>>>(states, sbf);
      f2b_sfgemm<<<dim3(16, 64), 256, 0, stream>>>(sbf, WsT, sfb);
    } else {
      f2_sfgemm<<<dim3(16, 64), 256, 0, stream>>>(states, WsT, sfb);
    }
    f3c_align<<<dim3(BT_, 8), 256, 0, stream>>>(A, sfb, v, C);
    (void)hipMemsetAsync(A, 0, (size_t)BT_ * D_ * 4, stream);    // ctx zero (qf dead)
    f4_softmax<<<BT_, 256, 0, stream>>>(C, mask, attn);
    f5_context<<<dim3(16, 2, 4), 256, 0, stream>>>(attn, states, A, C);
    f6b_outproj<<<dim3(4, 8, 12), 256, 0, stream>>>(A, query, Wc, bc, Bh);
  } else {
    k1_qf<<<BT_, 256, 0, stream>>>(query, Wq, bq, A);
    k23_align<<<B_ * (S_ / 16), 256, 0, stream>>>(states, Ws, v, A, C);
    k4_softmax<<<BT_, 256, 0, stream>>>(C, mask, A);
    k56_ctx_proj<<<BT_, 256, 0, stream>>>(A, states, query, Wc, bc, A, Bh, C);
  }
}

// Round 12
// 207.118 us; speedup vs baseline: 3.5264x; 1.0209x over previous
//
#include <hip/hip_runtime.h>
#include <math.h>

// Bahdanau additive attention. B=4, T=32, S=1024, H=512, D=2H=1024.
// Inputs fp32 (mask int32), OUTPUT fp32 flat:
//   context (4,32,1024) | hidden (4,32,512) | attn_t (4,1024,32)
// Round 12: f3d = t-loop (sf read ONCE) + contiguous reg slices + float4 qf;
// f2 -> 128x64 MFMA tile (512 blocks); tier2 reads bf16 states everywhere.
// d_out overlay: A[0,131072): (memset)->qf -> (memset)->ctx(final)
//                B[131072,196608): (memset)->hidden(final)
//                C[196608,327680): alg -> attn_t(final)

typedef unsigned short u16;
typedef __bf16 bf16x8 __attribute__((ext_vector_type(8)));
typedef float floatx4 __attribute__((ext_vector_type(4)));

#define B_ 4
#define T_ 32
#define S_ 1024
#define H_ 512
#define D_ 1024
#define BT_ 128
#define TWO_LOG2E 2.8853900817779268f   // tanh(y) = 1 - 2/(exp2(2*log2e*y)+1)

__device__ __forceinline__ float bf2f(u16 u) {
  unsigned int i = ((unsigned int)u) << 16;
  return __builtin_bit_cast(float, i);
}
__device__ __forceinline__ u16 f2bf(float f) {
  unsigned int i = __builtin_bit_cast(unsigned int, f);
  i += 0x7fffu + ((i >> 16) & 1u);  // RNE
  return (u16)(i >> 16);
}

// ================= FAST PATH =================

// ---- KC: states fp32 -> bf16 (sbf) ----
__global__ __launch_bounds__(256) void kc_cvt(const float* __restrict__ in, u16* __restrict__ out) {
  const size_t i0 = ((size_t)blockIdx.x * 256 + threadIdx.x) * 8;
  float4 a = *(const float4*)(in + i0);
  float4 b = *(const float4*)(in + i0 + 4);
  union { uint4 v; u16 s[8]; } r;
  r.s[0] = f2bf(a.x); r.s[1] = f2bf(a.y); r.s[2] = f2bf(a.z); r.s[3] = f2bf(a.w);
  r.s[4] = f2bf(b.x); r.s[5] = f2bf(b.y); r.s[6] = f2bf(b.z); r.s[7] = f2bf(b.w);
  *(uint4*)(out + i0) = r.v;
}

// ---- F1b: qf += 2log2e*(query_kslice @ Wq) (+2log2e*bq on slice 0). Split-K atomics. ----
__global__ __launch_bounds__(256) void f1b_qf(const float* __restrict__ query, const float* __restrict__ Wq,
                                              const float* __restrict__ bq, float* __restrict__ qf) {
  __shared__ float q[8][128];
  const int c0 = blockIdx.x * 256, r0 = blockIdx.y * 8, k0 = blockIdx.z * 128;
  const int tid = threadIdx.x;
  for (int i = tid; i < 8 * 128; i += 256) {
    const int rl = i >> 7, kk = i & 127;
    q[rl][kk] = query[(size_t)(r0 + rl) * H_ + k0 + kk];
  }
  __syncthreads();
  const int col = c0 + tid;
  float acc[8] = {};
  for (int kk = 0; kk < 128; ++kk) {
    const float w = Wq[(size_t)(k0 + kk) * D_ + col];
#pragma unroll
    for (int r = 0; r < 8; ++r) acc[r] = fmaf(q[r][kk], w, acc[r]);
  }
  const float bb = (blockIdx.z == 0) ? bq[col] : 0.f;
#pragma unroll
  for (int r = 0; r < 8; ++r)
    atomicAdd(&qf[(size_t)(r0 + r) * D_ + col], TWO_LOG2E * (acc[r] + bb));
}

// ---- F0: transpose Ws fp32 (k x n) -> WsT bf16 (n-major, k-contig) ----
__global__ __launch_bounds__(256) void f0_transpose(const float* __restrict__ Ws, u16* __restrict__ WsT) {
  __shared__ u16 tile[32][65];
  const int n0 = blockIdx.x * 64, k0 = blockIdx.y * 32;
  const int t = threadIdx.x;
  {
    const int kr = t >> 3, nc = (t & 7) * 8;
    const float* p = Ws + (size_t)(k0 + kr) * D_ + n0 + nc;
    float4 a = *(const float4*)p, b = *(const float4*)(p + 4);
    tile[kr][nc + 0] = f2bf(a.x); tile[kr][nc + 1] = f2bf(a.y);
    tile[kr][nc + 2] = f2bf(a.z); tile[kr][nc + 3] = f2bf(a.w);
    tile[kr][nc + 4] = f2bf(b.x); tile[kr][nc + 5] = f2bf(b.y);
    tile[kr][nc + 6] = f2bf(b.z); tile[kr][nc + 7] = f2bf(b.w);
  }
  __syncthreads();
  {
    const int nr = t >> 2, kc = (t & 3) * 8;
    union { uint4 v; u16 s[8]; } st;
#pragma unroll
    for (int i = 0; i < 8; ++i) st.s[i] = tile[kc + i][nr];
    *(uint4*)(WsT + (size_t)(n0 + nr) * D_ + k0 + kc) = st.v;
  }
}

// ---- F2c (tier2): sfb = 2log2e*(sbf @ Ws), both bf16. 128m x 64n tile, 512 blocks ----
// Wave: 64m x 32n = 4x2 MFMA 16x16x32 tiles; 8 MFMA + 6 ds_read_b128 per k-step.
__global__ __launch_bounds__(256) void f2c_sfgemm(const u16* __restrict__ A, const u16* __restrict__ BT,
                                                  u16* __restrict__ Cb) {
  __shared__ __align__(16) u16 sA[128 * 40];
  __shared__ __align__(16) u16 sB[64 * 40];
  const int bm0 = blockIdx.y * 128, bn0 = blockIdx.x * 64;
  const int t = threadIdx.x;
  const int wv = t >> 6, lane = t & 63;
  const int wm = (wv >> 1) * 64, wn = (wv & 1) * 32;
  const int fm = lane & 15, fq = lane >> 4;
  const int arow = t >> 1, akc = (t & 1) * 16;   // A: 128 rows x 32 k, 16 u16/thread
  const int brow = t >> 2, bkc = (t & 3) * 8;    // B: 64 rows x 32 k, 8 u16/thread

  floatx4 acc[4][2];
  const floatx4 fz = {0.f, 0.f, 0.f, 0.f};
#pragma unroll
  for (int i = 0; i < 4; ++i) { acc[i][0] = fz; acc[i][1] = fz; }

  const uint4* gA = (const uint4*)(A + (size_t)(bm0 + arow) * D_ + akc);
  const uint4* gB = (const uint4*)(BT + (size_t)(bn0 + brow) * D_ + bkc);

  for (int k0 = 0; k0 < D_; k0 += 32) {
    uint4 va0 = gA[k0 >> 3];
    uint4 va1 = gA[(k0 >> 3) + 1];
    uint4 vb = gB[k0 >> 3];
    __syncthreads();
    *(uint4*)&sA[arow * 40 + akc] = va0;
    *(uint4*)&sA[arow * 40 + akc + 8] = va1;
    *(uint4*)&sB[brow * 40 + bkc] = vb;
    __syncthreads();
    bf16x8 af[4], bfr[2];
#pragma unroll
    for (int i = 0; i < 4; ++i) af[i] = *(const bf16x8*)&sA[(wm + i * 16 + fm) * 40 + fq * 8];
#pragma unroll
    for (int j = 0; j < 2; ++j) bfr[j] = *(const bf16x8*)&sB[(wn + j * 16 + fm) * 40 + fq * 8];
#pragma unroll
    for (int i = 0; i < 4; ++i)
#pragma unroll
      for (int j = 0; j < 2; ++j)
        acc[i][j] = __builtin_amdgcn_mfma_f32_16x16x32_bf16(af[i], bfr[j], acc[i][j], 0, 0, 0);
  }
#pragma unroll
  for (int i = 0; i < 4; ++i)
#pragma unroll
    for (int j = 0; j < 2; ++j)
#pragma unroll
      for (int r = 0; r < 4; ++r) {
        const int row = bm0 + wm + i * 16 + fq * 4 + r;   // col=lane&15, row=quad*4+reg (m89)
        const int col = bn0 + wn + j * 16 + fm;
        Cb[(size_t)row * D_ + col] = f2bf(TWO_LOG2E * acc[i][j][r]);
      }
}

// ---- F2d (tier1): same tile, A fp32 with in-staging convert ----
__global__ __launch_bounds__(256) void f2d_sfgemm(const float* __restrict__ A, const u16* __restrict__ BT,
                                                  u16* __restrict__ Cb) {
  __shared__ __align__(16) u16 sA[128 * 40];
  __shared__ __align__(16) u16 sB[64 * 40];
  const int bm0 = blockIdx.y * 128, bn0 = blockIdx.x * 64;
  const int t = threadIdx.x;
  const int wv = t >> 6, lane = t & 63;
  const int wm = (wv >> 1) * 64, wn = (wv & 1) * 32;
  const int fm = lane & 15, fq = lane >> 4;
  const int arow = t >> 1, akc = (t & 1) * 16;
  const int brow = t >> 2, bkc = (t & 3) * 8;

  floatx4 acc[4][2];
  const floatx4 fz = {0.f, 0.f, 0.f, 0.f};
#pragma unroll
  for (int i = 0; i < 4; ++i) { acc[i][0] = fz; acc[i][1] = fz; }

  const float* gA = A + (size_t)(bm0 + arow) * D_ + akc;
  const uint4* gB = (const uint4*)(BT + (size_t)(bn0 + brow) * D_ + bkc);

  for (int k0 = 0; k0 < D_; k0 += 32) {
    float4 a0 = *(const float4*)(gA + k0);
    float4 a1 = *(const float4*)(gA + k0 + 4);
    float4 a2 = *(const float4*)(gA + k0 + 8);
    float4 a3 = *(const float4*)(gA + k0 + 12);
    uint4 vb = gB[k0 >> 3];
    union { uint4 v[2]; u16 s[16]; } pa;
    pa.s[0] = f2bf(a0.x); pa.s[1] = f2bf(a0.y); pa.s[2] = f2bf(a0.z); pa.s[3] = f2bf(a0.w);
    pa.s[4] = f2bf(a1.x); pa.s[5] = f2bf(a1.y); pa.s[6] = f2bf(a1.z); pa.s[7] = f2bf(a1.w);
    pa.s[8] = f2bf(a2.x); pa.s[9] = f2bf(a2.y); pa.s[10] = f2bf(a2.z); pa.s[11] = f2bf(a2.w);
    pa.s[12] = f2bf(a3.x); pa.s[13] = f2bf(a3.y); pa.s[14] = f2bf(a3.z); pa.s[15] = f2bf(a3.w);
    __syncthreads();
    *(uint4*)&sA[arow * 40 + akc] = pa.v[0];
    *(uint4*)&sA[arow * 40 + akc + 8] = pa.v[1];
    *(uint4*)&sB[brow * 40 + bkc] = vb;
    __syncthreads();
    bf16x8 af[4], bfr[2];
#pragma unroll
    for (int i = 0; i < 4; ++i) af[i] = *(const bf16x8*)&sA[(wm + i * 16 + fm) * 40 + fq * 8];
#pragma unroll
    for (int j = 0; j < 2; ++j) bfr[j] = *(const bf16x8*)&sB[(wn + j * 16 + fm) * 40 + fq * 8];
#pragma unroll
    for (int i = 0; i < 4; ++i)
#pragma unroll
      for (int j = 0; j < 2; ++j)
        acc[i][j] = __builtin_amdgcn_mfma_f32_16x16x32_bf16(af[i], bfr[j], acc[i][j], 0, 0, 0);
  }
#pragma unroll
  for (int i = 0; i < 4; ++i)
#pragma unroll
    for (int j = 0; j < 2; ++j)
#pragma unroll
      for (int r = 0; r < 4; ++r) {
        const int row = bm0 + wm + i * 16 + fq * 4 + r;
        const int col = bn0 + wn + j * 16 + fm;
        Cb[(size_t)row * D_ + col] = f2bf(TWO_LOG2E * acc[i][j][r]);
      }
}

// ---- F3d: alg = v . tanh(qf+sf). Wave per (b,s); sf read ONCE; t-loop. ----
// Lane owns d in [16*lane,16*lane+16): sf+v decoded once to regs; qf via 4 float4/t.
__global__ __launch_bounds__(256) void f3d_align(const float* __restrict__ qf, const u16* __restrict__ sfb,
                                                 const float* __restrict__ v, float* __restrict__ alg) {
  const int wid = (blockIdx.x * 256 + threadIdx.x) >> 6;  // b*1024+s
  const int lane = threadIdx.x & 63;
  const int b = wid >> 10, s = wid & 1023;
  float vr[16], sr[16];
  {
    union { uint4 v[2]; u16 s[16]; } u;
    const uint4* sp = (const uint4*)(sfb + (size_t)wid * D_ + lane * 16);
    u.v[0] = sp[0]; u.v[1] = sp[1];
    const float* vp = v + lane * 16;
#pragma unroll
    for (int c = 0; c < 4; ++c) {
      float4 w = *(const float4*)(vp + 4 * c);
      vr[4 * c + 0] = w.x; vr[4 * c + 1] = w.y; vr[4 * c + 2] = w.z; vr[4 * c + 3] = w.w;
    }
#pragma unroll
    for (int j = 0; j < 16; ++j) sr[j] = bf2f(u.s[j]);
  }
  const float* qbase = qf + (size_t)(b * T_) * D_ + lane * 16;
  for (int t = 0; t < T_; ++t) {
    const float4* qp = (const float4*)(qbase + (size_t)t * D_);
    float qv[16];
#pragma unroll
    for (int c = 0; c < 4; ++c) {
      float4 a = qp[c];
      qv[4 * c + 0] = a.x; qv[4 * c + 1] = a.y; qv[4 * c + 2] = a.z; qv[4 * c + 3] = a.w;
    }
    float sum = 0.f;
#pragma unroll
    for (int j = 0; j < 16; ++j) {
      const float x = qv[j] + sr[j];                           // prescaled by 2log2e
      const float e = __builtin_amdgcn_exp2f(x);
      sum = fmaf(vr[j], fmaf(-2.f, __builtin_amdgcn_rcpf(e + 1.f), 1.f), sum);
    }
#pragma unroll
    for (int off = 32; off > 0; off >>= 1) sum += __shfl_xor(sum, off);
    if (lane == 0) alg[(size_t)(b * T_ + t) * S_ + s] = sum;
  }
}

// ---- F4: masked softmax; alg(C) -> attn fp32 (ws) ----
__global__ __launch_bounds__(256) void f4_softmax(const float* __restrict__ alg, const int* __restrict__ mask,
                                                  float* __restrict__ attn) {
  const int r = blockIdx.x;
  const int b = r >> 5;
  const int tid = threadIdx.x;
  __shared__ float red[256];
  float a[4];
#pragma unroll
  for (int jj = 0; jj < 4; ++jj) {
    const int s = tid + 256 * jj;
    const float x = alg[(size_t)r * S_ + s];
    a[jj] = (mask[(size_t)b * S_ + s] != 0) ? x : -3.0e38f;
  }
  float m = fmaxf(fmaxf(a[0], a[1]), fmaxf(a[2], a[3]));
  red[tid] = m; __syncthreads();
  for (int st = 128; st > 0; st >>= 1) { if (tid < st) red[tid] = fmaxf(red[tid], red[tid + st]); __syncthreads(); }
  m = red[0]; __syncthreads();
  float e[4], lsum = 0.f;
#pragma unroll
  for (int jj = 0; jj < 4; ++jj) {
    e[jj] = (a[jj] > -1.0e38f) ? expf(a[jj] - m) : 0.f;
    lsum += e[jj];
  }
  red[tid] = lsum; __syncthreads();
  for (int st = 128; st > 0; st >>= 1) { if (tid < st) red[tid] += red[tid + st]; __syncthreads(); }
  const float rs = 1.f / red[0];
#pragma unroll
  for (int jj = 0; jj < 4; ++jj)
    attn[(size_t)r * S_ + tid + 256 * jj] = e[jj] * rs;
}

// ---- F5b (tier2): ctx += attn @ states_bf16; write attn_t ----
__global__ __launch_bounds__(256) void f5b_context(const float* __restrict__ attn, const u16* __restrict__ sbf,
                                                   float* __restrict__ ctx, float* __restrict__ out_at) {
  __shared__ float at[16][64];
  const int s0 = blockIdx.x * 64, t0 = blockIdx.y * 16, b = blockIdx.z;
  const int tid = threadIdx.x;
  for (int i = tid; i < 16 * 64; i += 256) {
    const int tl = i >> 6, sl = i & 63;
    at[tl][sl] = attn[(size_t)(b * T_ + t0 + tl) * S_ + s0 + sl];
  }
  __syncthreads();
  for (int i = tid; i < 64 * 16; i += 256) {
    const int sl = i >> 4, tl = i & 15;
    out_at[((size_t)b * S_ + s0 + sl) * T_ + t0 + tl] = at[tl][sl];
  }
  float acc[16][4] = {};
  for (int sl = 0; sl < 64; ++sl) {
    const u16* srow = sbf + ((size_t)b * S_ + s0 + sl) * D_ + tid;
    float sv[4];
#pragma unroll
    for (int jj = 0; jj < 4; ++jj) sv[jj] = bf2f(srow[256 * jj]);
#pragma unroll
    for (int tl = 0; tl < 16; ++tl) {
      const float w = at[tl][sl];
#pragma unroll
      for (int jj = 0; jj < 4; ++jj) acc[tl][jj] = fmaf(w, sv[jj], acc[tl][jj]);
    }
  }
#pragma unroll
  for (int tl = 0; tl < 16; ++tl)
#pragma unroll
    for (int jj = 0; jj < 4; ++jj)
      atomicAdd(&ctx[(size_t)(b * T_ + t0 + tl) * D_ + tid + 256 * jj], acc[tl][jj]);
}

// ---- F5 (tier1): fp32 states ----
__global__ __launch_bounds__(256) void f5_context(const float* __restrict__ attn, const float* __restrict__ states,
                                                  float* __restrict__ ctx, float* __restrict__ out_at) {
  __shared__ float at[16][64];
  const int s0 = blockIdx.x * 64, t0 = blockIdx.y * 16, b = blockIdx.z;
  const int tid = threadIdx.x;
  for (int i = tid; i < 16 * 64; i += 256) {
    const int tl = i >> 6, sl = i & 63;
    at[tl][sl] = attn[(size_t)(b * T_ + t0 + tl) * S_ + s0 + sl];
  }
  __syncthreads();
  for (int i = tid; i < 64 * 16; i += 256) {
    const int sl = i >> 4, tl = i & 15;
    out_at[((size_t)b * S_ + s0 + sl) * T_ + t0 + tl] = at[tl][sl];
  }
  float acc[16][4] = {};
  for (int sl = 0; sl < 64; ++sl) {
    const float* srow = states + ((size_t)b * S_ + s0 + sl) * D_ + tid;
    float sv[4];
#pragma unroll
    for (int jj = 0; jj < 4; ++jj) sv[jj] = srow[256 * jj];
#pragma unroll
    for (int tl = 0; tl < 16; ++tl) {
      const float w = at[tl][sl];
#pragma unroll
      for (int jj = 0; jj < 4; ++jj) acc[tl][jj] = fmaf(w, sv[jj], acc[tl][jj]);
    }
  }
#pragma unroll
  for (int tl = 0; tl < 16; ++tl)
#pragma unroll
    for (int jj = 0; jj < 4; ++jj)
      atomicAdd(&ctx[(size_t)(b * T_ + t0 + tl) * D_ + tid + 256 * jj], acc[tl][jj]);
}

// ---- F6b: hidden += [ctx, query]_kslice @ Wc (+bc on slice 0). Split-K atomics. ----
__global__ __launch_bounds__(256) void f6b_outproj(const float* __restrict__ ctx, const float* __restrict__ query,
                                                   const float* __restrict__ Wc, const float* __restrict__ bc,
                                                   float* __restrict__ out_hid) {
  __shared__ float cq[16][128];
  const int c0 = blockIdx.x * 128, r0 = blockIdx.y * 16, k0 = blockIdx.z * 128;
  const int tid = threadIdx.x;
  const int cl = tid & 127, rh = tid >> 7;
  for (int i = tid; i < 16 * 128; i += 256) {
    const int rl = i >> 7, kk = i & 127;
    const int k = k0 + kk, row = r0 + rl;
    cq[rl][kk] = (k < D_) ? ctx[(size_t)row * D_ + k] : query[(size_t)row * H_ + k - D_];
  }
  __syncthreads();
  float acc[8] = {};
  for (int kk = 0; kk < 128; ++kk) {
    const float w = Wc[(size_t)(k0 + kk) * H_ + c0 + cl];
#pragma unroll
    for (int rr = 0; rr < 8; ++rr) acc[rr] = fmaf(cq[rh * 8 + rr][kk], w, acc[rr]);
  }
  const float bb = (blockIdx.z == 0) ? bc[c0 + cl] : 0.f;
#pragma unroll
  for (int rr = 0; rr < 8; ++rr)
    atomicAdd(&out_hid[(size_t)(r0 + rh * 8 + rr) * H_ + c0 + cl], acc[rr] + bb);
}

// ================= FALLBACK (round-7, passing) =================

__global__ __launch_bounds__(256) void k1_qf(const float* __restrict__ query, const float* __restrict__ Wq,
                                             const float* __restrict__ bq, float* __restrict__ qf) {
  const int r = blockIdx.x;
  const int tid = threadIdx.x;
  __shared__ float q[H_];
  for (int i = tid; i < H_; i += 256) q[i] = query[(size_t)r * H_ + i];
  __syncthreads();
#pragma unroll
  for (int jj = 0; jj < 4; ++jj) {
    const int j = tid + 256 * jj;
    float acc = bq[j];
    for (int k = 0; k < H_; ++k) acc = fmaf(q[k], Wq[(size_t)k * D_ + j], acc);
    qf[(size_t)r * D_ + j] = acc;
  }
}

__global__ __launch_bounds__(256) void k23_align(const float* __restrict__ states, const float* __restrict__ Ws,
                                                 const float* __restrict__ v, const float* __restrict__ qf,
                                                 float* __restrict__ alg) {
  const int b = blockIdx.x >> 6;
  const int s0 = (blockIdx.x & 63) * 16;
  const int tid = threadIdx.x, lane = tid & 63, wv = tid >> 6;
  __shared__ u16 stL[16 * D_];
  __shared__ float vvL[D_];
  __shared__ float red[16 * 4];
  for (int i = tid; i < 16 * D_; i += 256) {
    const int row = i >> 10, col = i & (D_ - 1);
    stL[i] = f2bf(states[((size_t)b * S_ + s0 + row) * D_ + col]);
  }
  for (int i = tid; i < D_; i += 256) vvL[i] = v[i];
  __syncthreads();
  float acc[64];
#pragma unroll
  for (int i = 0; i < 64; ++i) acc[i] = 0.f;
#pragma unroll 4
  for (int k = 0; k < D_; ++k) {
    float wsv[4];
#pragma unroll
    for (int jj = 0; jj < 4; ++jj) wsv[jj] = Ws[(size_t)k * D_ + tid + 256 * jj];
#pragma unroll
    for (int i = 0; i < 16; ++i) {
      const float sv = bf2f(stL[i * D_ + k]);
#pragma unroll
      for (int jj = 0; jj < 4; ++jj) acc[i * 4 + jj] = fmaf(sv, wsv[jj], acc[i * 4 + jj]);
    }
  }
  for (int t = 0; t < T_; ++t) {
    float qv[4];
#pragma unroll
    for (int jj = 0; jj < 4; ++jj) qv[jj] = qf[((size_t)b * T_ + t) * D_ + tid + 256 * jj];
    float part[16];
#pragma unroll
    for (int i = 0; i < 16; ++i) {
      float p = 0.f;
#pragma unroll
      for (int jj = 0; jj < 4; ++jj)
        p = fmaf(vvL[tid + 256 * jj], tanhf(qv[jj] + acc[i * 4 + jj]), p);
      part[i] = p;
    }
#pragma unroll
    for (int i = 0; i < 16; ++i) {
      float x = part[i];
#pragma unroll
      for (int off = 32; off > 0; off >>= 1) x += __shfl_xor(x, off);
      if (lane == 0) red[i * 4 + wv] = x;
    }
    __syncthreads();
    if (tid < 16)
      alg[((size_t)b * T_ + t) * S_ + s0 + tid] =
          red[tid * 4 + 0] + red[tid * 4 + 1] + red[tid * 4 + 2] + red[tid * 4 + 3];
    __syncthreads();
  }
}

__global__ __launch_bounds__(256) void k4_softmax(const float* __restrict__ alg, const int* __restrict__ mask,
                                                  float* __restrict__ attn) {
  const int r = blockIdx.x;
  const int b = r >> 5;
  const int tid = threadIdx.x;
  __shared__ float red[256];
  float a[4];
#pragma unroll
  for (int jj = 0; jj < 4; ++jj) {
    const int s = tid + 256 * jj;
    const float x = alg[(size_t)r * S_ + s];
    a[jj] = (mask[(size_t)b * S_ + s] != 0) ? x : -3.0e38f;
  }
  float m = fmaxf(fmaxf(a[0], a[1]), fmaxf(a[2], a[3]));
  red[tid] = m; __syncthreads();
  for (int st = 128; st > 0; st >>= 1) { if (tid < st) red[tid] = fmaxf(red[tid], red[tid + st]); __syncthreads(); }
  m = red[0]; __syncthreads();
  float e[4], lsum = 0.f;
#pragma unroll
  for (int jj = 0; jj < 4; ++jj) {
    e[jj] = (a[jj] > -1.0e38f) ? expf(a[jj] - m) : 0.f;
    lsum += e[jj];
  }
  red[tid] = lsum; __syncthreads();
  for (int st = 128; st > 0; st >>= 1) { if (tid < st) red[tid] += red[tid + st]; __syncthreads(); }
  const float rs = 1.f / red[0];
#pragma unroll
  for (int jj = 0; jj < 4; ++jj)
    attn[(size_t)r * S_ + tid + 256 * jj] = e[jj] * rs;
}

__global__ __launch_bounds__(256) void k56_ctx_proj(const float* __restrict__ attn, const float* __restrict__ states,
                                                    const float* __restrict__ query, const float* __restrict__ Wc,
                                                    const float* __restrict__ bc,
                                                    float* __restrict__ out_ctx, float* __restrict__ out_hid,
                                                    float* __restrict__ out_at) {
  const int r = blockIdx.x;
  const int b = r >> 5, t = r & (T_ - 1);
  const int tid = threadIdx.x;
  __shared__ float pr[S_];
  __shared__ float cq[D_ + H_];
  for (int s = tid; s < S_; s += 256) pr[s] = attn[(size_t)r * S_ + s];
  __syncthreads();
  for (int s = tid; s < S_; s += 256) out_at[((size_t)b * S_ + s) * T_ + t] = pr[s];
  float acc[4] = {0.f, 0.f, 0.f, 0.f};
  for (int s = 0; s < S_; ++s) {
    const float w = pr[s];
    const float* srow = states + ((size_t)b * S_ + s) * D_ + tid;
#pragma unroll
    for (int jj = 0; jj < 4; ++jj) acc[jj] = fmaf(w, srow[256 * jj], acc[jj]);
  }
#pragma unroll
  for (int jj = 0; jj < 4; ++jj) {
    cq[tid + 256 * jj] = acc[jj];
    out_ctx[(size_t)r * D_ + tid + 256 * jj] = acc[jj];
  }
  for (int i = tid; i < H_; i += 256) cq[D_ + i] = query[(size_t)r * H_ + i];
  __syncthreads();
#pragma unroll
  for (int jj = 0; jj < 2; ++jj) {
    const int n = tid + 256 * jj;
    float h = bc[n];
    for (int k = 0; k < D_ + H_; ++k) h = fmaf(cq[k], Wc[(size_t)k * H_ + n], h);
    out_hid[(size_t)r * H_ + n] = h;
  }
}

extern "C" void kernel_launch(void* const* d_in, const int* in_sizes, int n_in,
                              void* d_out, int out_size, void* d_ws, size_t ws_size,
                              hipStream_t stream) {
  const float* query  = (const float*)d_in[0];
  const float* states = (const float*)d_in[1];
  const int*   mask   = (const int*)d_in[2];
  const float* Wq     = (const float*)d_in[3];
  const float* bq     = (const float*)d_in[4];
  const float* Ws     = (const float*)d_in[5];
  const float* v      = (const float*)d_in[6];
  const float* Wc     = (const float*)d_in[7];
  const float* bc     = (const float*)d_in[8];

  float* A  = (float*)d_out;               // qf -> ctx(final)
  float* Bh = A + (size_t)BT_ * D_;        // hidden
  float* C  = Bh + (size_t)BT_ * H_;       // alg -> attn_t

  const size_t WS_T1 = 8388608 + 2097152 + 524288;            // sfb + WsT + attn = 11 MB
  const size_t WS_T2 = WS_T1 + 8388608;                       // + sbf = 19.4 MB
  if (ws_size >= WS_T1) {
    char* ws = (char*)d_ws;
    u16*   sfb  = (u16*)(ws + 0);              // 8 MB
    u16*   WsT  = (u16*)(ws + 8388608);        // 2 MB
    float* attn = (float*)(ws + 10485760);     // 512 KB
    u16*   sbf  = (u16*)(ws + 11010048);       // 8 MB (tier2 only)

    // zero qf region (A) and hidden (Bh) in one shot (adjacent)
    (void)hipMemsetAsync(A, 0, (size_t)(BT_ * D_ + BT_ * H_) * 4, stream);
    f1b_qf<<<dim3(4, 16, 4), 256, 0, stream>>>(query, Wq, bq, A);
    f0_transpose<<<dim3(16, 32), 256, 0, stream>>>(Ws, WsT);
    const int tier2 = (ws_size >= WS_T2);
    if (tier2) {
      kc_cvt<<<2048, 256, 0, stream>>>(states, sbf);
      f2c_sfgemm<<<dim3(16, 32), 256, 0, stream>>>(sbf, WsT, sfb);
    } else {
      f2d_sfgemm<<<dim3(16, 32), 256, 0, stream>>>(states, WsT, sfb);
    }
    f3d_align<<<1024, 256, 0, stream>>>(A, sfb, v, C);
    (void)hipMemsetAsync(A, 0, (size_t)BT_ * D_ * 4, stream);    // ctx zero (qf dead)
    f4_softmax<<<BT_, 256, 0, stream>>>(C, mask, attn);
    if (tier2)
      f5b_context<<<dim3(16, 2, 4), 256, 0, stream>>>(attn, sbf, A, C);
    else
      f5_context<<<dim3(16, 2, 4), 256, 0, stream>>>(attn, states, A, C);
    f6b_outproj<<<dim3(4, 8, 12), 256, 0, stream>>>(A, query, Wc, bc, Bh);
  } else {
    k1_qf<<<BT_, 256, 0, stream>>>(query, Wq, bq, A);
    k23_align<<<B_ * (S_ / 16), 256, 0, stream>>>(states, Ws, v, A, C);
    k4_softmax<<<BT_, 256, 0, stream>>>(C, mask, A);
    k56_ctx_proj<<<BT_, 256, 0, stream>>>(A, states, query, Wc, bc, A, Bh, C);
  }
}

// Round 13
// 197.569 us; speedup vs baseline: 3.6968x; 1.0483x over previous
//
#include <hip/hip_runtime.h>
#include <math.h>

// Bahdanau additive attention. B=4, T=32, S=1024, H=512, D=2H=1024.
// Inputs fp32 (mask int32), OUTPUT fp32 flat:
//   context (4,32,1024) | hidden (4,32,512) | attn_t (4,1024,32)
// Round 13 (tier3, ws>=28MB — ws measured ~256MB from harness poison size):
//   kct: fused states->bf16 (sbf) + states^T->bf16 (sbfT) + Ws^T->bf16 (WsT)
//   f3e: qf software prefetch (t+1) to kill the 40% load-stall
//   f4b: softmax -> attn_t fp32 (C, final) + P bf16 (pbf in ws); alg lives in ws
//   f5c: context = P @ states via pure-register MFMA (no LDS/atomics/memset)
// d_out overlay: A[0,131072): (memset)->qf -> ctx(final, f5c direct write)
//                B[131072,196608): (memset)->hidden(final)
//                C[196608,327680): attn_t(final, f4b direct write)

typedef unsigned short u16;
typedef __bf16 bf16x8 __attribute__((ext_vector_type(8)));
typedef float floatx4 __attribute__((ext_vector_type(4)));

#define B_ 4
#define T_ 32
#define S_ 1024
#define H_ 512
#define D_ 1024
#define BT_ 128
#define TWO_LOG2E 2.8853900817779268f   // tanh(y) = 1 - 2/(exp2(2*log2e*y)+1)

__device__ __forceinline__ float bf2f(u16 u) {
  unsigned int i = ((unsigned int)u) << 16;
  return __builtin_bit_cast(float, i);
}
__device__ __forceinline__ u16 f2bf(float f) {
  unsigned int i = __builtin_bit_cast(unsigned int, f);
  i += 0x7fffu + ((i >> 16) & 1u);  // RNE
  return (u16)(i >> 16);
}

// ================= TIER-3 KERNELS =================

// ---- KCT: fused prep. blocks [0,512): Ws^T. blocks [512,2560): states -> sbf + sbfT (per-b transpose) ----
__global__ __launch_bounds__(256) void kct_prep(const float* __restrict__ states, const float* __restrict__ Ws,
                                                u16* __restrict__ sbf, u16* __restrict__ sbfT,
                                                u16* __restrict__ WsT) {
  __shared__ u16 tile[32][65];
  const int t = threadIdx.x;
  if (blockIdx.x < 512) {
    const int n0 = (blockIdx.x & 15) * 64, k0 = (blockIdx.x >> 4) * 32;
    const int kr = t >> 3, nc = (t & 7) * 8;
    const float* p = Ws + (size_t)(k0 + kr) * D_ + n0 + nc;
    float4 a = *(const float4*)p, b = *(const float4*)(p + 4);
    tile[kr][nc + 0] = f2bf(a.x); tile[kr][nc + 1] = f2bf(a.y);
    tile[kr][nc + 2] = f2bf(a.z); tile[kr][nc + 3] = f2bf(a.w);
    tile[kr][nc + 4] = f2bf(b.x); tile[kr][nc + 5] = f2bf(b.y);
    tile[kr][nc + 6] = f2bf(b.z); tile[kr][nc + 7] = f2bf(b.w);
    __syncthreads();
    const int nr = t >> 2, kc = (t & 3) * 8;
    union { uint4 v; u16 s[8]; } st;
#pragma unroll
    for (int i = 0; i < 8; ++i) st.s[i] = tile[kc + i][nr];
    *(uint4*)(WsT + (size_t)(n0 + nr) * D_ + k0 + kc) = st.v;
  } else {
    const int bid = blockIdx.x - 512;
    const int b = bid >> 9;                       // 512 tiles per b
    const int r2 = bid & 511;
    const int d0 = (r2 & 15) * 64, s0 = (r2 >> 4) * 32;
    const int sr = t >> 3, dc = (t & 7) * 8;
    const float* p = states + ((size_t)b * S_ + s0 + sr) * D_ + d0 + dc;
    float4 a = *(const float4*)p, bb = *(const float4*)(p + 4);
    union { uint4 v; u16 s[8]; } pk;
    pk.s[0] = f2bf(a.x); pk.s[1] = f2bf(a.y); pk.s[2] = f2bf(a.z); pk.s[3] = f2bf(a.w);
    pk.s[4] = f2bf(bb.x); pk.s[5] = f2bf(bb.y); pk.s[6] = f2bf(bb.z); pk.s[7] = f2bf(bb.w);
    *(uint4*)(sbf + ((size_t)b * S_ + s0 + sr) * D_ + d0 + dc) = pk.v;
#pragma unroll
    for (int i = 0; i < 8; ++i) tile[sr][dc + i] = pk.s[i];
    __syncthreads();
    const int dr = t >> 2, sc = (t & 3) * 8;
    union { uint4 v; u16 s[8]; } st;
#pragma unroll
    for (int i = 0; i < 8; ++i) st.s[i] = tile[sc + i][dr];
    *(uint4*)(sbfT + ((size_t)b * D_ + d0 + dr) * S_ + s0 + sc) = st.v;
  }
}

// ---- F1b: qf += 2log2e*(query_kslice @ Wq) (+2log2e*bq on slice 0). Split-K atomics. ----
__global__ __launch_bounds__(256) void f1b_qf(const float* __restrict__ query, const float* __restrict__ Wq,
                                              const float* __restrict__ bq, float* __restrict__ qf) {
  __shared__ float q[8][128];
  const int c0 = blockIdx.x * 256, r0 = blockIdx.y * 8, k0 = blockIdx.z * 128;
  const int tid = threadIdx.x;
  for (int i = tid; i < 8 * 128; i += 256) {
    const int rl = i >> 7, kk = i & 127;
    q[rl][kk] = query[(size_t)(r0 + rl) * H_ + k0 + kk];
  }
  __syncthreads();
  const int col = c0 + tid;
  float acc[8] = {};
  for (int kk = 0; kk < 128; ++kk) {
    const float w = Wq[(size_t)(k0 + kk) * D_ + col];
#pragma unroll
    for (int r = 0; r < 8; ++r) acc[r] = fmaf(q[r][kk], w, acc[r]);
  }
  const float bb = (blockIdx.z == 0) ? bq[col] : 0.f;
#pragma unroll
  for (int r = 0; r < 8; ++r)
    atomicAdd(&qf[(size_t)(r0 + r) * D_ + col], TWO_LOG2E * (acc[r] + bb));
}

// ---- F2c: sfb = 2log2e*(sbf @ Ws), both bf16. 128m x 64n tile, 512 blocks ----
__global__ __launch_bounds__(256) void f2c_sfgemm(const u16* __restrict__ A, const u16* __restrict__ BT,
                                                  u16* __restrict__ Cb) {
  __shared__ __align__(16) u16 sA[128 * 40];
  __shared__ __align__(16) u16 sB[64 * 40];
  const int bm0 = blockIdx.y * 128, bn0 = blockIdx.x * 64;
  const int t = threadIdx.x;
  const int wv = t >> 6, lane = t & 63;
  const int wm = (wv >> 1) * 64, wn = (wv & 1) * 32;
  const int fm = lane & 15, fq = lane >> 4;
  const int arow = t >> 1, akc = (t & 1) * 16;
  const int brow = t >> 2, bkc = (t & 3) * 8;

  floatx4 acc[4][2];
  const floatx4 fz = {0.f, 0.f, 0.f, 0.f};
#pragma unroll
  for (int i = 0; i < 4; ++i) { acc[i][0] = fz; acc[i][1] = fz; }

  const uint4* gA = (const uint4*)(A + (size_t)(bm0 + arow) * D_ + akc);
  const uint4* gB = (const uint4*)(BT + (size_t)(bn0 + brow) * D_ + bkc);

  for (int k0 = 0; k0 < D_; k0 += 32) {
    uint4 va0 = gA[k0 >> 3];
    uint4 va1 = gA[(k0 >> 3) + 1];
    uint4 vb = gB[k0 >> 3];
    __syncthreads();
    *(uint4*)&sA[arow * 40 + akc] = va0;
    *(uint4*)&sA[arow * 40 + akc + 8] = va1;
    *(uint4*)&sB[brow * 40 + bkc] = vb;
    __syncthreads();
    bf16x8 af[4], bfr[2];
#pragma unroll
    for (int i = 0; i < 4; ++i) af[i] = *(const bf16x8*)&sA[(wm + i * 16 + fm) * 40 + fq * 8];
#pragma unroll
    for (int j = 0; j < 2; ++j) bfr[j] = *(const bf16x8*)&sB[(wn + j * 16 + fm) * 40 + fq * 8];
#pragma unroll
    for (int i = 0; i < 4; ++i)
#pragma unroll
      for (int j = 0; j < 2; ++j)
        acc[i][j] = __builtin_amdgcn_mfma_f32_16x16x32_bf16(af[i], bfr[j], acc[i][j], 0, 0, 0);
  }
#pragma unroll
  for (int i = 0; i < 4; ++i)
#pragma unroll
    for (int j = 0; j < 2; ++j)
#pragma unroll
      for (int r = 0; r < 4; ++r) {
        const int row = bm0 + wm + i * 16 + fq * 4 + r;   // col=lane&15, row=quad*4+reg (m89)
        const int col = bn0 + wn + j * 16 + fm;
        Cb[(size_t)row * D_ + col] = f2bf(TWO_LOG2E * acc[i][j][r]);
      }
}

// ---- F3e: alg = v . tanh(qf+sf). Wave per (b,s); sf once; qf prefetched (t+1). ----
__global__ __launch_bounds__(256) void f3e_align(const float* __restrict__ qf, const u16* __restrict__ sfb,
                                                 const float* __restrict__ v, float* __restrict__ alg) {
  const int wid = (blockIdx.x * 256 + threadIdx.x) >> 6;  // b*1024+s
  const int lane = threadIdx.x & 63;
  const int b = wid >> 10, s = wid & 1023;
  float vr[16], sr[16];
  {
    union { uint4 v[2]; u16 s[16]; } u;
    const uint4* sp = (const uint4*)(sfb + (size_t)wid * D_ + lane * 16);
    u.v[0] = sp[0]; u.v[1] = sp[1];
    const float* vp = v + lane * 16;
#pragma unroll
    for (int c = 0; c < 4; ++c) {
      float4 w = *(const float4*)(vp + 4 * c);
      vr[4 * c + 0] = w.x; vr[4 * c + 1] = w.y; vr[4 * c + 2] = w.z; vr[4 * c + 3] = w.w;
    }
#pragma unroll
    for (int j = 0; j < 16; ++j) sr[j] = bf2f(u.s[j]);
  }
  const float* qbase = qf + (size_t)(b * T_) * D_ + lane * 16;
  float4 nq[4];
#pragma unroll
  for (int c = 0; c < 4; ++c) nq[c] = ((const float4*)qbase)[c];
  for (int t = 0; t < T_; ++t) {
    float4 cq[4];
#pragma unroll
    for (int c = 0; c < 4; ++c) cq[c] = nq[c];
    // prefetch t+1 (t=31 strays into the zeroed hidden region of d_out — harmless)
    const float4* qp = (const float4*)(qbase + (size_t)(t + 1) * D_);
#pragma unroll
    for (int c = 0; c < 4; ++c) nq[c] = qp[c];
    float qv[16];
#pragma unroll
    for (int c = 0; c < 4; ++c) {
      qv[4 * c + 0] = cq[c].x; qv[4 * c + 1] = cq[c].y; qv[4 * c + 2] = cq[c].z; qv[4 * c + 3] = cq[c].w;
    }
    float sum = 0.f;
#pragma unroll
    for (int j = 0; j < 16; ++j) {
      const float x = qv[j] + sr[j];                           // prescaled by 2log2e
      const float e = __builtin_amdgcn_exp2f(x);
      sum = fmaf(vr[j], fmaf(-2.f, __builtin_amdgcn_rcpf(e + 1.f), 1.f), sum);
    }
#pragma unroll
    for (int off = 32; off > 0; off >>= 1) sum += __shfl_xor(sum, off);
    if (lane == 0) alg[(size_t)(b * T_ + t) * S_ + s] = sum;
  }
}

// ---- F4b: masked softmax; alg(ws) -> attn_t fp32 (C, final) + P bf16 (ws) ----
__global__ __launch_bounds__(256) void f4b_softmax(const float* __restrict__ alg, const int* __restrict__ mask,
                                                   float* __restrict__ out_at, u16* __restrict__ pbf) {
  const int r = blockIdx.x;                    // b*T+t
  const int b = r >> 5, t = r & 31;
  const int tid = threadIdx.x;
  __shared__ float red[256];
  float a[4];
#pragma unroll
  for (int jj = 0; jj < 4; ++jj) {
    const int s = tid + 256 * jj;
    const float x = alg[(size_t)r * S_ + s];
    a[jj] = (mask[(size_t)b * S_ + s] != 0) ? x : -3.0e38f;
  }
  float m = fmaxf(fmaxf(a[0], a[1]), fmaxf(a[2], a[3]));
  red[tid] = m; __syncthreads();
  for (int st = 128; st > 0; st >>= 1) { if (tid < st) red[tid] = fmaxf(red[tid], red[tid + st]); __syncthreads(); }
  m = red[0]; __syncthreads();
  float e[4], lsum = 0.f;
#pragma unroll
  for (int jj = 0; jj < 4; ++jj) {
    e[jj] = (a[jj] > -1.0e38f) ? expf(a[jj] - m) : 0.f;
    lsum += e[jj];
  }
  red[tid] = lsum; __syncthreads();
  for (int st = 128; st > 0; st >>= 1) { if (tid < st) red[tid] += red[tid + st]; __syncthreads(); }
  const float rs = 1.f / red[0];
#pragma unroll
  for (int jj = 0; jj < 4; ++jj) {
    const int s = tid + 256 * jj;
    const float p = e[jj] * rs;
    out_at[((size_t)b * S_ + s) * T_ + t] = p;
    pbf[(size_t)r * S_ + s] = f2bf(p);
  }
}

// ---- F5c: ctx = P @ states via pure-register MFMA. 64 blocks, no LDS/atomics. ----
// Per wave: 32m(t) x 16n(d), K=S=1024. A-frags from pbf, B-frags from sbfT.
__global__ __launch_bounds__(256) void f5c_context(const u16* __restrict__ pbf, const u16* __restrict__ sbfT,
                                                   float* __restrict__ ctx) {
  const int b = blockIdx.x >> 4, dt = blockIdx.x & 15;
  const int wv = threadIdx.x >> 6, lane = threadIdx.x & 63;
  const int n0 = dt * 64 + wv * 16;
  const int fm = lane & 15, fq = lane >> 4;
  const floatx4 fz = {0.f, 0.f, 0.f, 0.f};
  floatx4 acc0 = fz, acc1 = fz;
  const u16* pa0 = pbf + ((size_t)b * T_ + fm) * S_ + fq * 8;
  const u16* pa1 = pbf + ((size_t)b * T_ + 16 + fm) * S_ + fq * 8;
  const u16* pb  = sbfT + ((size_t)b * D_ + n0 + fm) * S_ + fq * 8;
#pragma unroll 4
  for (int k0 = 0; k0 < S_; k0 += 32) {
    bf16x8 a0 = *(const bf16x8*)(pa0 + k0);
    bf16x8 a1 = *(const bf16x8*)(pa1 + k0);
    bf16x8 bb = *(const bf16x8*)(pb + k0);
    acc0 = __builtin_amdgcn_mfma_f32_16x16x32_bf16(a0, bb, acc0, 0, 0, 0);
    acc1 = __builtin_amdgcn_mfma_f32_16x16x32_bf16(a1, bb, acc1, 0, 0, 0);
  }
  const int col = n0 + fm;
#pragma unroll
  for (int r = 0; r < 4; ++r) {
    ctx[((size_t)b * T_ + fq * 4 + r) * D_ + col] = acc0[r];
    ctx[((size_t)b * T_ + 16 + fq * 4 + r) * D_ + col] = acc1[r];
  }
}

// ---- F6b: hidden += [ctx, query]_kslice @ Wc (+bc on slice 0). Split-K atomics. ----
__global__ __launch_bounds__(256) void f6b_outproj(const float* __restrict__ ctx, const float* __restrict__ query,
                                                   const float* __restrict__ Wc, const float* __restrict__ bc,
                                                   float* __restrict__ out_hid) {
  __shared__ float cq[16][128];
  const int c0 = blockIdx.x * 128, r0 = blockIdx.y * 16, k0 = blockIdx.z * 128;
  const int tid = threadIdx.x;
  const int cl = tid & 127, rh = tid >> 7;
  for (int i = tid; i < 16 * 128; i += 256) {
    const int rl = i >> 7, kk = i & 127;
    const int k = k0 + kk, row = r0 + rl;
    cq[rl][kk] = (k < D_) ? ctx[(size_t)row * D_ + k] : query[(size_t)row * H_ + k - D_];
  }
  __syncthreads();
  float acc[8] = {};
  for (int kk = 0; kk < 128; ++kk) {
    const float w = Wc[(size_t)(k0 + kk) * H_ + c0 + cl];
#pragma unroll
    for (int rr = 0; rr < 8; ++rr) acc[rr] = fmaf(cq[rh * 8 + rr][kk], w, acc[rr]);
  }
  const float bb = (blockIdx.z == 0) ? bc[c0 + cl] : 0.f;
#pragma unroll
  for (int rr = 0; rr < 8; ++rr)
    atomicAdd(&out_hid[(size_t)(r0 + rh * 8 + rr) * H_ + c0 + cl], acc[rr] + bb);
}

// ================= TIER-1/2 EXTRAS (round-12, passing at 207us) =================

__global__ __launch_bounds__(256) void kc_cvt(const float* __restrict__ in, u16* __restrict__ out) {
  const size_t i0 = ((size_t)blockIdx.x * 256 + threadIdx.x) * 8;
  float4 a = *(const float4*)(in + i0);
  float4 b = *(const float4*)(in + i0 + 4);
  union { uint4 v; u16 s[8]; } r;
  r.s[0] = f2bf(a.x); r.s[1] = f2bf(a.y); r.s[2] = f2bf(a.z); r.s[3] = f2bf(a.w);
  r.s[4] = f2bf(b.x); r.s[5] = f2bf(b.y); r.s[6] = f2bf(b.z); r.s[7] = f2bf(b.w);
  *(uint4*)(out + i0) = r.v;
}

__global__ __launch_bounds__(256) void f0_transpose(const float* __restrict__ Ws, u16* __restrict__ WsT) {
  __shared__ u16 tile[32][65];
  const int n0 = blockIdx.x * 64, k0 = blockIdx.y * 32;
  const int t = threadIdx.x;
  {
    const int kr = t >> 3, nc = (t & 7) * 8;
    const float* p = Ws + (size_t)(k0 + kr) * D_ + n0 + nc;
    float4 a = *(const float4*)p, b = *(const float4*)(p + 4);
    tile[kr][nc + 0] = f2bf(a.x); tile[kr][nc + 1] = f2bf(a.y);
    tile[kr][nc + 2] = f2bf(a.z); tile[kr][nc + 3] = f2bf(a.w);
    tile[kr][nc + 4] = f2bf(b.x); tile[kr][nc + 5] = f2bf(b.y);
    tile[kr][nc + 6] = f2bf(b.z); tile[kr][nc + 7] = f2bf(b.w);
  }
  __syncthreads();
  {
    const int nr = t >> 2, kc = (t & 3) * 8;
    union { uint4 v; u16 s[8]; } st;
#pragma unroll
    for (int i = 0; i < 8; ++i) st.s[i] = tile[kc + i][nr];
    *(uint4*)(WsT + (size_t)(n0 + nr) * D_ + k0 + kc) = st.v;
  }
}

__global__ __launch_bounds__(256) void f2d_sfgemm(const float* __restrict__ A, const u16* __restrict__ BT,
                                                  u16* __restrict__ Cb) {
  __shared__ __align__(16) u16 sA[128 * 40];
  __shared__ __align__(16) u16 sB[64 * 40];
  const int bm0 = blockIdx.y * 128, bn0 = blockIdx.x * 64;
  const int t = threadIdx.x;
  const int wv = t >> 6, lane = t & 63;
  const int wm = (wv >> 1) * 64, wn = (wv & 1) * 32;
  const int fm = lane & 15, fq = lane >> 4;
  const int arow = t >> 1, akc = (t & 1) * 16;
  const int brow = t >> 2, bkc = (t & 3) * 8;
  floatx4 acc[4][2];
  const floatx4 fz = {0.f, 0.f, 0.f, 0.f};
#pragma unroll
  for (int i = 0; i < 4; ++i) { acc[i][0] = fz; acc[i][1] = fz; }
  const float* gA = A + (size_t)(bm0 + arow) * D_ + akc;
  const uint4* gB = (const uint4*)(BT + (size_t)(bn0 + brow) * D_ + bkc);
  for (int k0 = 0; k0 < D_; k0 += 32) {
    float4 a0 = *(const float4*)(gA + k0);
    float4 a1 = *(const float4*)(gA + k0 + 4);
    float4 a2 = *(const float4*)(gA + k0 + 8);
    float4 a3 = *(const float4*)(gA + k0 + 12);
    uint4 vb = gB[k0 >> 3];
    union { uint4 v[2]; u16 s[16]; } pa;
    pa.s[0] = f2bf(a0.x); pa.s[1] = f2bf(a0.y); pa.s[2] = f2bf(a0.z); pa.s[3] = f2bf(a0.w);
    pa.s[4] = f2bf(a1.x); pa.s[5] = f2bf(a1.y); pa.s[6] = f2bf(a1.z); pa.s[7] = f2bf(a1.w);
    pa.s[8] = f2bf(a2.x); pa.s[9] = f2bf(a2.y); pa.s[10] = f2bf(a2.z); pa.s[11] = f2bf(a2.w);
    pa.s[12] = f2bf(a3.x); pa.s[13] = f2bf(a3.y); pa.s[14] = f2bf(a3.z); pa.s[15] = f2bf(a3.w);
    __syncthreads();
    *(uint4*)&sA[arow * 40 + akc] = pa.v[0];
    *(uint4*)&sA[arow * 40 + akc + 8] = pa.v[1];
    *(uint4*)&sB[brow * 40 + bkc] = vb;
    __syncthreads();
    bf16x8 af[4], bfr[2];
#pragma unroll
    for (int i = 0; i < 4; ++i) af[i] = *(const bf16x8*)&sA[(wm + i * 16 + fm) * 40 + fq * 8];
#pragma unroll
    for (int j = 0; j < 2; ++j) bfr[j] = *(const bf16x8*)&sB[(wn + j * 16 + fm) * 40 + fq * 8];
#pragma unroll
    for (int i = 0; i < 4; ++i)
#pragma unroll
      for (int j = 0; j < 2; ++j)
        acc[i][j] = __builtin_amdgcn_mfma_f32_16x16x32_bf16(af[i], bfr[j], acc[i][j], 0, 0, 0);
  }
#pragma unroll
  for (int i = 0; i < 4; ++i)
#pragma unroll
    for (int j = 0; j < 2; ++j)
#pragma unroll
      for (int r = 0; r < 4; ++r) {
        const int row = bm0 + wm + i * 16 + fq * 4 + r;
        const int col = bn0 + wn + j * 16 + fm;
        Cb[(size_t)row * D_ + col] = f2bf(TWO_LOG2E * acc[i][j][r]);
      }
}

__global__ __launch_bounds__(256) void f4_softmax(const float* __restrict__ alg, const int* __restrict__ mask,
                                                  float* __restrict__ attn) {
  const int r = blockIdx.x;
  const int b = r >> 5;
  const int tid = threadIdx.x;
  __shared__ float red[256];
  float a[4];
#pragma unroll
  for (int jj = 0; jj < 4; ++jj) {
    const int s = tid + 256 * jj;
    const float x = alg[(size_t)r * S_ + s];
    a[jj] = (mask[(size_t)b * S_ + s] != 0) ? x : -3.0e38f;
  }
  float m = fmaxf(fmaxf(a[0], a[1]), fmaxf(a[2], a[3]));
  red[tid] = m; __syncthreads();
  for (int st = 128; st > 0; st >>= 1) { if (tid < st) red[tid] = fmaxf(red[tid], red[tid + st]); __syncthreads(); }
  m = red[0]; __syncthreads();
  float e[4], lsum = 0.f;
#pragma unroll
  for (int jj = 0; jj < 4; ++jj) {
    e[jj] = (a[jj] > -1.0e38f) ? expf(a[jj] - m) : 0.f;
    lsum += e[jj];
  }
  red[tid] = lsum; __syncthreads();
  for (int st = 128; st > 0; st >>= 1) { if (tid < st) red[tid] += red[tid + st]; __syncthreads(); }
  const float rs = 1.f / red[0];
#pragma unroll
  for (int jj = 0; jj < 4; ++jj)
    attn[(size_t)r * S_ + tid + 256 * jj] = e[jj] * rs;
}

__global__ __launch_bounds__(256) void f5b_context(const float* __restrict__ attn, const u16* __restrict__ sbf,
                                                   float* __restrict__ ctx, float* __restrict__ out_at) {
  __shared__ float at[16][64];
  const int s0 = blockIdx.x * 64, t0 = blockIdx.y * 16, b = blockIdx.z;
  const int tid = threadIdx.x;
  for (int i = tid; i < 16 * 64; i += 256) {
    const int tl = i >> 6, sl = i & 63;
    at[tl][sl] = attn[(size_t)(b * T_ + t0 + tl) * S_ + s0 + sl];
  }
  __syncthreads();
  for (int i = tid; i < 64 * 16; i += 256) {
    const int sl = i >> 4, tl = i & 15;
    out_at[((size_t)b * S_ + s0 + sl) * T_ + t0 + tl] = at[tl][sl];
  }
  float acc[16][4] = {};
  for (int sl = 0; sl < 64; ++sl) {
    const u16* srow = sbf + ((size_t)b * S_ + s0 + sl) * D_ + tid;
    float sv[4];
#pragma unroll
    for (int jj = 0; jj < 4; ++jj) sv[jj] = bf2f(srow[256 * jj]);
#pragma unroll
    for (int tl = 0; tl < 16; ++tl) {
      const float w = at[tl][sl];
#pragma unroll
      for (int jj = 0; jj < 4; ++jj) acc[tl][jj] = fmaf(w, sv[jj], acc[tl][jj]);
    }
  }
#pragma unroll
  for (int tl = 0; tl < 16; ++tl)
#pragma unroll
    for (int jj = 0; jj < 4; ++jj)
      atomicAdd(&ctx[(size_t)(b * T_ + t0 + tl) * D_ + tid + 256 * jj], acc[tl][jj]);
}

__global__ __launch_bounds__(256) void f5_context(const float* __restrict__ attn, const float* __restrict__ states,
                                                  float* __restrict__ ctx, float* __restrict__ out_at) {
  __shared__ float at[16][64];
  const int s0 = blockIdx.x * 64, t0 = blockIdx.y * 16, b = blockIdx.z;
  const int tid = threadIdx.x;
  for (int i = tid; i < 16 * 64; i += 256) {
    const int tl = i >> 6, sl = i & 63;
    at[tl][sl] = attn[(size_t)(b * T_ + t0 + tl) * S_ + s0 + sl];
  }
  __syncthreads();
  for (int i = tid; i < 64 * 16; i += 256) {
    const int sl = i >> 4, tl = i & 15;
    out_at[((size_t)b * S_ + s0 + sl) * T_ + t0 + tl] = at[tl][sl];
  }
  float acc[16][4] = {};
  for (int sl = 0; sl < 64; ++sl) {
    const float* srow = states + ((size_t)b * S_ + s0 + sl) * D_ + tid;
    float sv[4];
#pragma unroll
    for (int jj = 0; jj < 4; ++jj) sv[jj] = srow[256 * jj];
#pragma unroll
    for (int tl = 0; tl < 16; ++tl) {
      const float w = at[tl][sl];
#pragma unroll
      for (int jj = 0; jj < 4; ++jj) acc[tl][jj] = fmaf(w, sv[jj], acc[tl][jj]);
    }
  }
#pragma unroll
  for (int tl = 0; tl < 16; ++tl)
#pragma unroll
    for (int jj = 0; jj < 4; ++jj)
      atomicAdd(&ctx[(size_t)(b * T_ + t0 + tl) * D_ + tid + 256 * jj], acc[tl][jj]);
}

// ================= FALLBACK (round-7, passing) =================

__global__ __launch_bounds__(256) void k1_qf(const float* __restrict__ query, const float* __restrict__ Wq,
                                             const float* __restrict__ bq, float* __restrict__ qf) {
  const int r = blockIdx.x;
  const int tid = threadIdx.x;
  __shared__ float q[H_];
  for (int i = tid; i < H_; i += 256) q[i] = query[(size_t)r * H_ + i];
  __syncthreads();
#pragma unroll
  for (int jj = 0; jj < 4; ++jj) {
    const int j = tid + 256 * jj;
    float acc = bq[j];
    for (int k = 0; k < H_; ++k) acc = fmaf(q[k], Wq[(size_t)k * D_ + j], acc);
    qf[(size_t)r * D_ + j] = acc;
  }
}

__global__ __launch_bounds__(256) void k23_align(const float* __restrict__ states, const float* __restrict__ Ws,
                                                 const float* __restrict__ v, const float* __restrict__ qf,
                                                 float* __restrict__ alg) {
  const int b = blockIdx.x >> 6;
  const int s0 = (blockIdx.x & 63) * 16;
  const int tid = threadIdx.x, lane = tid & 63, wv = tid >> 6;
  __shared__ u16 stL[16 * D_];
  __shared__ float vvL[D_];
  __shared__ float red[16 * 4];
  for (int i = tid; i < 16 * D_; i += 256) {
    const int row = i >> 10, col = i & (D_ - 1);
    stL[i] = f2bf(states[((size_t)b * S_ + s0 + row) * D_ + col]);
  }
  for (int i = tid; i < D_; i += 256) vvL[i] = v[i];
  __syncthreads();
  float acc[64];
#pragma unroll
  for (int i = 0; i < 64; ++i) acc[i] = 0.f;
#pragma unroll 4
  for (int k = 0; k < D_; ++k) {
    float wsv[4];
#pragma unroll
    for (int jj = 0; jj < 4; ++jj) wsv[jj] = Ws[(size_t)k * D_ + tid + 256 * jj];
#pragma unroll
    for (int i = 0; i < 16; ++i) {
      const float sv = bf2f(stL[i * D_ + k]);
#pragma unroll
      for (int jj = 0; jj < 4; ++jj) acc[i * 4 + jj] = fmaf(sv, wsv[jj], acc[i * 4 + jj]);
    }
  }
  for (int t = 0; t < T_; ++t) {
    float qv[4];
#pragma unroll
    for (int jj = 0; jj < 4; ++jj) qv[jj] = qf[((size_t)b * T_ + t) * D_ + tid + 256 * jj];
    float part[16];
#pragma unroll
    for (int i = 0; i < 16; ++i) {
      float p = 0.f;
#pragma unroll
      for (int jj = 0; jj < 4; ++jj)
        p = fmaf(vvL[tid + 256 * jj], tanhf(qv[jj] + acc[i * 4 + jj]), p);
      part[i] = p;
    }
#pragma unroll
    for (int i = 0; i < 16; ++i) {
      float x = part[i];
#pragma unroll
      for (int off = 32; off > 0; off >>= 1) x += __shfl_xor(x, off);
      if (lane == 0) red[i * 4 + wv] = x;
    }
    __syncthreads();
    if (tid < 16)
      alg[((size_t)b * T_ + t) * S_ + s0 + tid] =
          red[tid * 4 + 0] + red[tid * 4 + 1] + red[tid * 4 + 2] + red[tid * 4 + 3];
    __syncthreads();
  }
}

__global__ __launch_bounds__(256) void k4_softmax(const float* __restrict__ alg, const int* __restrict__ mask,
                                                  float* __restrict__ attn) {
  const int r = blockIdx.x;
  const int b = r >> 5;
  const int tid = threadIdx.x;
  __shared__ float red[256];
  float a[4];
#pragma unroll
  for (int jj = 0; jj < 4; ++jj) {
    const int s = tid + 256 * jj;
    const float x = alg[(size_t)r * S_ + s];
    a[jj] = (mask[(size_t)b * S_ + s] != 0) ? x : -3.0e38f;
  }
  float m = fmaxf(fmaxf(a[0], a[1]), fmaxf(a[2], a[3]));
  red[tid] = m; __syncthreads();
  for (int st = 128; st > 0; st >>= 1) { if (tid < st) red[tid] = fmaxf(red[tid], red[tid + st]); __syncthreads(); }
  m = red[0]; __syncthreads();
  float e[4], lsum = 0.f;
#pragma unroll
  for (int jj = 0; jj < 4; ++jj) {
    e[jj] = (a[jj] > -1.0e38f) ? expf(a[jj] - m) : 0.f;
    lsum += e[jj];
  }
  red[tid] = lsum; __syncthreads();
  for (int st = 128; st > 0; st >>= 1) { if (tid < st) red[tid] += red[tid + st]; __syncthreads(); }
  const float rs = 1.f / red[0];
#pragma unroll
  for (int jj = 0; jj < 4; ++jj)
    attn[(size_t)r * S_ + tid + 256 * jj] = e[jj] * rs;
}

__global__ __launch_bounds__(256) void k56_ctx_proj(const float* __restrict__ attn, const float* __restrict__ states,
                                                    const float* __restrict__ query, const float* __restrict__ Wc,
                                                    const float* __restrict__ bc,
                                                    float* __restrict__ out_ctx, float* __restrict__ out_hid,
                                                    float* __restrict__ out_at) {
  const int r = blockIdx.x;
  const int b = r >> 5, t = r & (T_ - 1);
  const int tid = threadIdx.x;
  __shared__ float pr[S_];
  __shared__ float cq[D_ + H_];
  for (int s = tid; s < S_; s += 256) pr[s] = attn[(size_t)r * S_ + s];
  __syncthreads();
  for (int s = tid; s < S_; s += 256) out_at[((size_t)b * S_ + s) * T_ + t] = pr[s];
  float acc[4] = {0.f, 0.f, 0.f, 0.f};
  for (int s = 0; s < S_; ++s) {
    const float w = pr[s];
    const float* srow = states + ((size_t)b * S_ + s) * D_ + tid;
#pragma unroll
    for (int jj = 0; jj < 4; ++jj) acc[jj] = fmaf(w, srow[256 * jj], acc[jj]);
  }
#pragma unroll
  for (int jj = 0; jj < 4; ++jj) {
    cq[tid + 256 * jj] = acc[jj];
    out_ctx[(size_t)r * D_ + tid + 256 * jj] = acc[jj];
  }
  for (int i = tid; i < H_; i += 256) cq[D_ + i] = query[(size_t)r * H_ + i];
  __syncthreads();
#pragma unroll
  for (int jj = 0; jj < 2; ++jj) {
    const int n = tid + 256 * jj;
    float h = bc[n];
    for (int k = 0; k < D_ + H_; ++k) h = fmaf(cq[k], Wc[(size_t)k * H_ + n], h);
    out_hid[(size_t)r * H_ + n] = h;
  }
}

extern "C" void kernel_launch(void* const* d_in, const int* in_sizes, int n_in,
                              void* d_out, int out_size, void* d_ws, size_t ws_size,
                              hipStream_t stream) {
  const float* query  = (const float*)d_in[0];
  const float* states = (const float*)d_in[1];
  const int*   mask   = (const int*)d_in[2];
  const float* Wq     = (const float*)d_in[3];
  const float* bq     = (const float*)d_in[4];
  const float* Ws     = (const float*)d_in[5];
  const float* v      = (const float*)d_in[6];
  const float* Wc     = (const float*)d_in[7];
  const float* bc     = (const float*)d_in[8];

  float* A  = (float*)d_out;               // qf -> ctx(final)
  float* Bh = A + (size_t)BT_ * D_;        // hidden
  float* C  = Bh + (size_t)BT_ * H_;       // attn_t (tier3) / alg->attn_t (tier1/2)

  // ws layout:
  //   sfb   [0, 8M)       WsT [8M, 10M)      alg/attn [10M, 10.5M)
  //   sbf   [10.5M, 18.9M)   sbfT [18.9M, 27.3M)   pbf [27.3M, 27.55M)
  char* ws = (char*)d_ws;
  u16*   sfb  = (u16*)(ws + 0);
  u16*   WsT  = (u16*)(ws + 8388608);
  float* alg  = (float*)(ws + 10485760);   // fp32 attn in tier1/2; alg in tier3
  u16*   sbf  = (u16*)(ws + 11010048);
  u16*   sbfT = (u16*)(ws + 19398656);
  u16*   pbf  = (u16*)(ws + 27787264);

  const size_t WS_T1 = 11010048;
  const size_t WS_T2 = 19398656;
  const size_t WS_T3 = 28049408;

  if (ws_size >= WS_T3) {
    // ---------- tier 3 ----------
    (void)hipMemsetAsync(A, 0, (size_t)(BT_ * D_ + BT_ * H_) * 4, stream);  // qf + hidden zero
    kct_prep<<<2560, 256, 0, stream>>>(states, Ws, sbf, sbfT, WsT);
    f1b_qf<<<dim3(4, 16, 4), 256, 0, stream>>>(query, Wq, bq, A);
    f2c_sfgemm<<<dim3(16, 32), 256, 0, stream>>>(sbf, WsT, sfb);
    f3e_align<<<1024, 256, 0, stream>>>(A, sfb, v, alg);
    f4b_softmax<<<BT_, 256, 0, stream>>>(alg, mask, C, pbf);
    f5c_context<<<64, 256, 0, stream>>>(pbf, sbfT, A);
    f6b_outproj<<<dim3(4, 8, 12), 256, 0, stream>>>(A, query, Wc, bc, Bh);
  } else if (ws_size >= WS_T1) {
    // ---------- tier 1/2 (round-12) ----------
    float* attn = alg;
    (void)hipMemsetAsync(A, 0, (size_t)(BT_ * D_ + BT_ * H_) * 4, stream);
    f1b_qf<<<dim3(4, 16, 4), 256, 0, stream>>>(query, Wq, bq, A);
    f0_transpose<<<dim3(16, 32), 256, 0, stream>>>(Ws, WsT);
    const int tier2 = (ws_size >= WS_T2);
    if (tier2) {
      kc_cvt<<<2048, 256, 0, stream>>>(states, sbf);
      f2c_sfgemm<<<dim3(16, 32), 256, 0, stream>>>(sbf, WsT, sfb);
    } else {
      f2d_sfgemm<<<dim3(16, 32), 256, 0, stream>>>(states, WsT, sfb);
    }
    f3e_align<<<1024, 256, 0, stream>>>(A, sfb, v, C);
    (void)hipMemsetAsync(A, 0, (size_t)BT_ * D_ * 4, stream);
    f4_softmax<<<BT_, 256, 0, stream>>>(C, mask, attn);
    if (tier2)
      f5b_context<<<dim3(16, 2, 4), 256, 0, stream>>>(attn, sbf, A, C);
    else
      f5_context<<<dim3(16, 2, 4), 256, 0, stream>>>(attn, states, A, C);
    f6b_outproj<<<dim3(4, 8, 12), 256, 0, stream>>>(A, query, Wc, bc, Bh);
  } else {
    // ---------- fallback ----------
    k1_qf<<<BT_, 256, 0, stream>>>(query, Wq, bq, A);
    k23_align<<<B_ * (S_ / 16), 256, 0, stream>>>(states, Ws, v, A, C);
    k4_softmax<<<BT_, 256, 0, stream>>>(C, mask, A);
    k56_ctx_proj<<<BT_, 256, 0, stream>>>(A, states, query, Wc, bc, A, Bh, C);
  }
}

// Round 14
// 193.666 us; speedup vs baseline: 3.7713x; 1.0202x over previous
//
#include <hip/hip_runtime.h>
#include <math.h>

// Bahdanau additive attention. B=4, T=32, S=1024, H=512, D=2H=1024.
// Inputs fp32 (mask int32), OUTPUT fp32 flat:
//   context (4,32,1024) | hidden (4,32,512) | attn_t (4,1024,32)
// Round 14: f3f — t-halved grid (2048 blocks), 16 in-register t-sums, single
// batched butterfly at the end (removes the per-t serial shuffle chain that
// capped VALUBusy at 60%). No prefetch (r13 showed it hurts). Rest = round 13.
// d_out overlay: A[0,131072): (memset)->qf -> ctx(final, f5c direct write)
//                B[131072,196608): (memset)->hidden(final)
//                C[196608,327680): attn_t(final, f4b direct write)

typedef unsigned short u16;
typedef __bf16 bf16x8 __attribute__((ext_vector_type(8)));
typedef float floatx4 __attribute__((ext_vector_type(4)));

#define B_ 4
#define T_ 32
#define S_ 1024
#define H_ 512
#define D_ 1024
#define BT_ 128
#define TWO_LOG2E 2.8853900817779268f   // tanh(y) = 1 - 2/(exp2(2*log2e*y)+1)

__device__ __forceinline__ float bf2f(u16 u) {
  unsigned int i = ((unsigned int)u) << 16;
  return __builtin_bit_cast(float, i);
}
__device__ __forceinline__ u16 f2bf(float f) {
  unsigned int i = __builtin_bit_cast(unsigned int, f);
  i += 0x7fffu + ((i >> 16) & 1u);  // RNE
  return (u16)(i >> 16);
}

// ================= TIER-3 KERNELS =================

// ---- KCT: fused prep. blocks [0,512): Ws^T. blocks [512,2560): states -> sbf + sbfT ----
__global__ __launch_bounds__(256) void kct_prep(const float* __restrict__ states, const float* __restrict__ Ws,
                                                u16* __restrict__ sbf, u16* __restrict__ sbfT,
                                                u16* __restrict__ WsT) {
  __shared__ u16 tile[32][65];
  const int t = threadIdx.x;
  if (blockIdx.x < 512) {
    const int n0 = (blockIdx.x & 15) * 64, k0 = (blockIdx.x >> 4) * 32;
    const int kr = t >> 3, nc = (t & 7) * 8;
    const float* p = Ws + (size_t)(k0 + kr) * D_ + n0 + nc;
    float4 a = *(const float4*)p, b = *(const float4*)(p + 4);
    tile[kr][nc + 0] = f2bf(a.x); tile[kr][nc + 1] = f2bf(a.y);
    tile[kr][nc + 2] = f2bf(a.z); tile[kr][nc + 3] = f2bf(a.w);
    tile[kr][nc + 4] = f2bf(b.x); tile[kr][nc + 5] = f2bf(b.y);
    tile[kr][nc + 6] = f2bf(b.z); tile[kr][nc + 7] = f2bf(b.w);
    __syncthreads();
    const int nr = t >> 2, kc = (t & 3) * 8;
    union { uint4 v; u16 s[8]; } st;
#pragma unroll
    for (int i = 0; i < 8; ++i) st.s[i] = tile[kc + i][nr];
    *(uint4*)(WsT + (size_t)(n0 + nr) * D_ + k0 + kc) = st.v;
  } else {
    const int bid = blockIdx.x - 512;
    const int b = bid >> 9;
    const int r2 = bid & 511;
    const int d0 = (r2 & 15) * 64, s0 = (r2 >> 4) * 32;
    const int sr = t >> 3, dc = (t & 7) * 8;
    const float* p = states + ((size_t)b * S_ + s0 + sr) * D_ + d0 + dc;
    float4 a = *(const float4*)p, bb = *(const float4*)(p + 4);
    union { uint4 v; u16 s[8]; } pk;
    pk.s[0] = f2bf(a.x); pk.s[1] = f2bf(a.y); pk.s[2] = f2bf(a.z); pk.s[3] = f2bf(a.w);
    pk.s[4] = f2bf(bb.x); pk.s[5] = f2bf(bb.y); pk.s[6] = f2bf(bb.z); pk.s[7] = f2bf(bb.w);
    *(uint4*)(sbf + ((size_t)b * S_ + s0 + sr) * D_ + d0 + dc) = pk.v;
#pragma unroll
    for (int i = 0; i < 8; ++i) tile[sr][dc + i] = pk.s[i];
    __syncthreads();
    const int dr = t >> 2, sc = (t & 3) * 8;
    union { uint4 v; u16 s[8]; } st;
#pragma unroll
    for (int i = 0; i < 8; ++i) st.s[i] = tile[sc + i][dr];
    *(uint4*)(sbfT + ((size_t)b * D_ + d0 + dr) * S_ + s0 + sc) = st.v;
  }
}

// ---- F1b: qf += 2log2e*(query_kslice @ Wq) (+2log2e*bq on slice 0). Split-K atomics. ----
__global__ __launch_bounds__(256) void f1b_qf(const float* __restrict__ query, const float* __restrict__ Wq,
                                              const float* __restrict__ bq, float* __restrict__ qf) {
  __shared__ float q[8][128];
  const int c0 = blockIdx.x * 256, r0 = blockIdx.y * 8, k0 = blockIdx.z * 128;
  const int tid = threadIdx.x;
  for (int i = tid; i < 8 * 128; i += 256) {
    const int rl = i >> 7, kk = i & 127;
    q[rl][kk] = query[(size_t)(r0 + rl) * H_ + k0 + kk];
  }
  __syncthreads();
  const int col = c0 + tid;
  float acc[8] = {};
  for (int kk = 0; kk < 128; ++kk) {
    const float w = Wq[(size_t)(k0 + kk) * D_ + col];
#pragma unroll
    for (int r = 0; r < 8; ++r) acc[r] = fmaf(q[r][kk], w, acc[r]);
  }
  const float bb = (blockIdx.z == 0) ? bq[col] : 0.f;
#pragma unroll
  for (int r = 0; r < 8; ++r)
    atomicAdd(&qf[(size_t)(r0 + r) * D_ + col], TWO_LOG2E * (acc[r] + bb));
}

// ---- F2c: sfb = 2log2e*(sbf @ Ws), both bf16. 128m x 64n tile, 512 blocks ----
__global__ __launch_bounds__(256) void f2c_sfgemm(const u16* __restrict__ A, const u16* __restrict__ BT,
                                                  u16* __restrict__ Cb) {
  __shared__ __align__(16) u16 sA[128 * 40];
  __shared__ __align__(16) u16 sB[64 * 40];
  const int bm0 = blockIdx.y * 128, bn0 = blockIdx.x * 64;
  const int t = threadIdx.x;
  const int wv = t >> 6, lane = t & 63;
  const int wm = (wv >> 1) * 64, wn = (wv & 1) * 32;
  const int fm = lane & 15, fq = lane >> 4;
  const int arow = t >> 1, akc = (t & 1) * 16;
  const int brow = t >> 2, bkc = (t & 3) * 8;

  floatx4 acc[4][2];
  const floatx4 fz = {0.f, 0.f, 0.f, 0.f};
#pragma unroll
  for (int i = 0; i < 4; ++i) { acc[i][0] = fz; acc[i][1] = fz; }

  const uint4* gA = (const uint4*)(A + (size_t)(bm0 + arow) * D_ + akc);
  const uint4* gB = (const uint4*)(BT + (size_t)(bn0 + brow) * D_ + bkc);

  for (int k0 = 0; k0 < D_; k0 += 32) {
    uint4 va0 = gA[k0 >> 3];
    uint4 va1 = gA[(k0 >> 3) + 1];
    uint4 vb = gB[k0 >> 3];
    __syncthreads();
    *(uint4*)&sA[arow * 40 + akc] = va0;
    *(uint4*)&sA[arow * 40 + akc + 8] = va1;
    *(uint4*)&sB[brow * 40 + bkc] = vb;
    __syncthreads();
    bf16x8 af[4], bfr[2];
#pragma unroll
    for (int i = 0; i < 4; ++i) af[i] = *(const bf16x8*)&sA[(wm + i * 16 + fm) * 40 + fq * 8];
#pragma unroll
    for (int j = 0; j < 2; ++j) bfr[j] = *(const bf16x8*)&sB[(wn + j * 16 + fm) * 40 + fq * 8];
#pragma unroll
    for (int i = 0; i < 4; ++i)
#pragma unroll
      for (int j = 0; j < 2; ++j)
        acc[i][j] = __builtin_amdgcn_mfma_f32_16x16x32_bf16(af[i], bfr[j], acc[i][j], 0, 0, 0);
  }
#pragma unroll
  for (int i = 0; i < 4; ++i)
#pragma unroll
    for (int j = 0; j < 2; ++j)
#pragma unroll
      for (int r = 0; r < 4; ++r) {
        const int row = bm0 + wm + i * 16 + fq * 4 + r;   // col=lane&15, row=quad*4+reg (m89)
        const int col = bn0 + wn + j * 16 + fm;
        Cb[(size_t)row * D_ + col] = f2bf(TWO_LOG2E * acc[i][j][r]);
      }
}

// ---- F3f: alg = v . tanh(qf+sf). Wave per (b,s); t-half per blockIdx.y. ----
// 16 t-sums in registers; ONE batched butterfly at the end (no per-t chain).
__global__ __launch_bounds__(256, 6) void f3f_align(const float* __restrict__ qf, const u16* __restrict__ sfb,
                                                    const float* __restrict__ v, float* __restrict__ alg) {
  const int wid = (blockIdx.x * 256 + threadIdx.x) >> 6;  // b*1024+s
  const int lane = threadIdx.x & 63;
  const int b = wid >> 10, s = wid & 1023;
  const int t0 = blockIdx.y * 16;
  float vr[16], sr[16];
  {
    union { uint4 v[2]; u16 s[16]; } u;
    const uint4* sp = (const uint4*)(sfb + (size_t)wid * D_ + lane * 16);
    u.v[0] = sp[0]; u.v[1] = sp[1];
    const float* vp = v + lane * 16;
#pragma unroll
    for (int c = 0; c < 4; ++c) {
      float4 w = *(const float4*)(vp + 4 * c);
      vr[4 * c + 0] = w.x; vr[4 * c + 1] = w.y; vr[4 * c + 2] = w.z; vr[4 * c + 3] = w.w;
    }
#pragma unroll
    for (int j = 0; j < 16; ++j) sr[j] = bf2f(u.s[j]);
  }
  float sum[16];
#pragma unroll
  for (int tt = 0; tt < 16; ++tt) sum[tt] = 0.f;

  const float* qbase = qf + ((size_t)(b * T_ + t0)) * D_ + lane * 16;
  for (int tt = 0; tt < 16; ++tt) {
    const float4* qp = (const float4*)(qbase + (size_t)tt * D_);
    float acc = 0.f;
#pragma unroll
    for (int c = 0; c < 4; ++c) {
      float4 q4 = qp[c];
      float xs[4] = {q4.x, q4.y, q4.z, q4.w};
#pragma unroll
      for (int u2 = 0; u2 < 4; ++u2) {
        const int j = 4 * c + u2;
        const float x = xs[u2] + sr[j];                        // prescaled by 2log2e
        const float e = __builtin_amdgcn_exp2f(x);
        acc = fmaf(vr[j], fmaf(-2.f, __builtin_amdgcn_rcpf(e + 1.f), 1.f), acc);
      }
    }
    sum[tt] = acc;
  }
  // batched butterfly: 16 independent 6-step chains, interleaved
#pragma unroll
  for (int off = 32; off > 0; off >>= 1)
#pragma unroll
    for (int tt = 0; tt < 16; ++tt) sum[tt] += __shfl_xor(sum[tt], off);
  if (lane == 0) {
#pragma unroll
    for (int tt = 0; tt < 16; ++tt)
      alg[((size_t)(b * T_ + t0 + tt)) * S_ + s] = sum[tt];
  }
}

// ---- F4b: masked softmax; alg(ws) -> attn_t fp32 (C, final) + P bf16 (ws) ----
__global__ __launch_bounds__(256) void f4b_softmax(const float* __restrict__ alg, const int* __restrict__ mask,
                                                   float* __restrict__ out_at, u16* __restrict__ pbf) {
  const int r = blockIdx.x;                    // b*T+t
  const int b = r >> 5, t = r & 31;
  const int tid = threadIdx.x;
  __shared__ float red[256];
  float a[4];
#pragma unroll
  for (int jj = 0; jj < 4; ++jj) {
    const int s = tid + 256 * jj;
    const float x = alg[(size_t)r * S_ + s];
    a[jj] = (mask[(size_t)b * S_ + s] != 0) ? x : -3.0e38f;
  }
  float m = fmaxf(fmaxf(a[0], a[1]), fmaxf(a[2], a[3]));
  red[tid] = m; __syncthreads();
  for (int st = 128; st > 0; st >>= 1) { if (tid < st) red[tid] = fmaxf(red[tid], red[tid + st]); __syncthreads(); }
  m = red[0]; __syncthreads();
  float e[4], lsum = 0.f;
#pragma unroll
  for (int jj = 0; jj < 4; ++jj) {
    e[jj] = (a[jj] > -1.0e38f) ? expf(a[jj] - m) : 0.f;
    lsum += e[jj];
  }
  red[tid] = lsum; __syncthreads();
  for (int st = 128; st > 0; st >>= 1) { if (tid < st) red[tid] += red[tid + st]; __syncthreads(); }
  const float rs = 1.f / red[0];
#pragma unroll
  for (int jj = 0; jj < 4; ++jj) {
    const int s = tid + 256 * jj;
    const float p = e[jj] * rs;
    out_at[((size_t)b * S_ + s) * T_ + t] = p;
    pbf[(size_t)r * S_ + s] = f2bf(p);
  }
}

// ---- F5c: ctx = P @ states via pure-register MFMA. 64 blocks, no LDS/atomics. ----
__global__ __launch_bounds__(256) void f5c_context(const u16* __restrict__ pbf, const u16* __restrict__ sbfT,
                                                   float* __restrict__ ctx) {
  const int b = blockIdx.x >> 4, dt = blockIdx.x & 15;
  const int wv = threadIdx.x >> 6, lane = threadIdx.x & 63;
  const int n0 = dt * 64 + wv * 16;
  const int fm = lane & 15, fq = lane >> 4;
  const floatx4 fz = {0.f, 0.f, 0.f, 0.f};
  floatx4 acc0 = fz, acc1 = fz;
  const u16* pa0 = pbf + ((size_t)b * T_ + fm) * S_ + fq * 8;
  const u16* pa1 = pbf + ((size_t)b * T_ + 16 + fm) * S_ + fq * 8;
  const u16* pb  = sbfT + ((size_t)b * D_ + n0 + fm) * S_ + fq * 8;
#pragma unroll 4
  for (int k0 = 0; k0 < S_; k0 += 32) {
    bf16x8 a0 = *(const bf16x8*)(pa0 + k0);
    bf16x8 a1 = *(const bf16x8*)(pa1 + k0);
    bf16x8 bb = *(const bf16x8*)(pb + k0);
    acc0 = __builtin_amdgcn_mfma_f32_16x16x32_bf16(a0, bb, acc0, 0, 0, 0);
    acc1 = __builtin_amdgcn_mfma_f32_16x16x32_bf16(a1, bb, acc1, 0, 0, 0);
  }
  const int col = n0 + fm;
#pragma unroll
  for (int r = 0; r < 4; ++r) {
    ctx[((size_t)b * T_ + fq * 4 + r) * D_ + col] = acc0[r];
    ctx[((size_t)b * T_ + 16 + fq * 4 + r) * D_ + col] = acc1[r];
  }
}

// ---- F6b: hidden += [ctx, query]_kslice @ Wc (+bc on slice 0). Split-K atomics. ----
__global__ __launch_bounds__(256) void f6b_outproj(const float* __restrict__ ctx, const float* __restrict__ query,
                                                   const float* __restrict__ Wc, const float* __restrict__ bc,
                                                   float* __restrict__ out_hid) {
  __shared__ float cq[16][128];
  const int c0 = blockIdx.x * 128, r0 = blockIdx.y * 16, k0 = blockIdx.z * 128;
  const int tid = threadIdx.x;
  const int cl = tid & 127, rh = tid >> 7;
  for (int i = tid; i < 16 * 128; i += 256) {
    const int rl = i >> 7, kk = i & 127;
    const int k = k0 + kk, row = r0 + rl;
    cq[rl][kk] = (k < D_) ? ctx[(size_t)row * D_ + k] : query[(size_t)row * H_ + k - D_];
  }
  __syncthreads();
  float acc[8] = {};
  for (int kk = 0; kk < 128; ++kk) {
    const float w = Wc[(size_t)(k0 + kk) * H_ + c0 + cl];
#pragma unroll
    for (int rr = 0; rr < 8; ++rr) acc[rr] = fmaf(cq[rh * 8 + rr][kk], w, acc[rr]);
  }
  const float bb = (blockIdx.z == 0) ? bc[c0 + cl] : 0.f;
#pragma unroll
  for (int rr = 0; rr < 8; ++rr)
    atomicAdd(&out_hid[(size_t)(r0 + rh * 8 + rr) * H_ + c0 + cl], acc[rr] + bb);
}

// ================= TIER-1/2 EXTRAS =================

__global__ __launch_bounds__(256) void kc_cvt(const float* __restrict__ in, u16* __restrict__ out) {
  const size_t i0 = ((size_t)blockIdx.x * 256 + threadIdx.x) * 8;
  float4 a = *(const float4*)(in + i0);
  float4 b = *(const float4*)(in + i0 + 4);
  union { uint4 v; u16 s[8]; } r;
  r.s[0] = f2bf(a.x); r.s[1] = f2bf(a.y); r.s[2] = f2bf(a.z); r.s[3] = f2bf(a.w);
  r.s[4] = f2bf(b.x); r.s[5] = f2bf(b.y); r.s[6] = f2bf(b.z); r.s[7] = f2bf(b.w);
  *(uint4*)(out + i0) = r.v;
}

__global__ __launch_bounds__(256) void f0_transpose(const float* __restrict__ Ws, u16* __restrict__ WsT) {
  __shared__ u16 tile[32][65];
  const int n0 = blockIdx.x * 64, k0 = blockIdx.y * 32;
  const int t = threadIdx.x;
  {
    const int kr = t >> 3, nc = (t & 7) * 8;
    const float* p = Ws + (size_t)(k0 + kr) * D_ + n0 + nc;
    float4 a = *(const float4*)p, b = *(const float4*)(p + 4);
    tile[kr][nc + 0] = f2bf(a.x); tile[kr][nc + 1] = f2bf(a.y);
    tile[kr][nc + 2] = f2bf(a.z); tile[kr][nc + 3] = f2bf(a.w);
    tile[kr][nc + 4] = f2bf(b.x); tile[kr][nc + 5] = f2bf(b.y);
    tile[kr][nc + 6] = f2bf(b.z); tile[kr][nc + 7] = f2bf(b.w);
  }
  __syncthreads();
  {
    const int nr = t >> 2, kc = (t & 3) * 8;
    union { uint4 v; u16 s[8]; } st;
#pragma unroll
    for (int i = 0; i < 8; ++i) st.s[i] = tile[kc + i][nr];
    *(uint4*)(WsT + (size_t)(n0 + nr) * D_ + k0 + kc) = st.v;
  }
}

__global__ __launch_bounds__(256) void f2d_sfgemm(const float* __restrict__ A, const u16* __restrict__ BT,
                                                  u16* __restrict__ Cb) {
  __shared__ __align__(16) u16 sA[128 * 40];
  __shared__ __align__(16) u16 sB[64 * 40];
  const int bm0 = blockIdx.y * 128, bn0 = blockIdx.x * 64;
  const int t = threadIdx.x;
  const int wv = t >> 6, lane = t & 63;
  const int wm = (wv >> 1) * 64, wn = (wv & 1) * 32;
  const int fm = lane & 15, fq = lane >> 4;
  const int arow = t >> 1, akc = (t & 1) * 16;
  const int brow = t >> 2, bkc = (t & 3) * 8;
  floatx4 acc[4][2];
  const floatx4 fz = {0.f, 0.f, 0.f, 0.f};
#pragma unroll
  for (int i = 0; i < 4; ++i) { acc[i][0] = fz; acc[i][1] = fz; }
  const float* gA = A + (size_t)(bm0 + arow) * D_ + akc;
  const uint4* gB = (const uint4*)(BT + (size_t)(bn0 + brow) * D_ + bkc);
  for (int k0 = 0; k0 < D_; k0 += 32) {
    float4 a0 = *(const float4*)(gA + k0);
    float4 a1 = *(const float4*)(gA + k0 + 4);
    float4 a2 = *(const float4*)(gA + k0 + 8);
    float4 a3 = *(const float4*)(gA + k0 + 12);
    uint4 vb = gB[k0 >> 3];
    union { uint4 v[2]; u16 s[16]; } pa;
    pa.s[0] = f2bf(a0.x); pa.s[1] = f2bf(a0.y); pa.s[2] = f2bf(a0.z); pa.s[3] = f2bf(a0.w);
    pa.s[4] = f2bf(a1.x); pa.s[5] = f2bf(a1.y); pa.s[6] = f2bf(a1.z); pa.s[7] = f2bf(a1.w);
    pa.s[8] = f2bf(a2.x); pa.s[9] = f2bf(a2.y); pa.s[10] = f2bf(a2.z); pa.s[11] = f2bf(a2.w);
    pa.s[12] = f2bf(a3.x); pa.s[13] = f2bf(a3.y); pa.s[14] = f2bf(a3.z); pa.s[15] = f2bf(a3.w);
    __syncthreads();
    *(uint4*)&sA[arow * 40 + akc] = pa.v[0];
    *(uint4*)&sA[arow * 40 + akc + 8] = pa.v[1];
    *(uint4*)&sB[brow * 40 + bkc] = vb;
    __syncthreads();
    bf16x8 af[4], bfr[2];
#pragma unroll
    for (int i = 0; i < 4; ++i) af[i] = *(const bf16x8*)&sA[(wm + i * 16 + fm) * 40 + fq * 8];
#pragma unroll
    for (int j = 0; j < 2; ++j) bfr[j] = *(const bf16x8*)&sB[(wn + j * 16 + fm) * 40 + fq * 8];
#pragma unroll
    for (int i = 0; i < 4; ++i)
#pragma unroll
      for (int j = 0; j < 2; ++j)
        acc[i][j] = __builtin_amdgcn_mfma_f32_16x16x32_bf16(af[i], bfr[j], acc[i][j], 0, 0, 0);
  }
#pragma unroll
  for (int i = 0; i < 4; ++i)
#pragma unroll
    for (int j = 0; j < 2; ++j)
#pragma unroll
      for (int r = 0; r < 4; ++r) {
        const int row = bm0 + wm + i * 16 + fq * 4 + r;
        const int col = bn0 + wn + j * 16 + fm;
        Cb[(size_t)row * D_ + col] = f2bf(TWO_LOG2E * acc[i][j][r]);
      }
}

__global__ __launch_bounds__(256) void f4_softmax(const float* __restrict__ alg, const int* __restrict__ mask,
                                                  float* __restrict__ attn) {
  const int r = blockIdx.x;
  const int b = r >> 5;
  const int tid = threadIdx.x;
  __shared__ float red[256];
  float a[4];
#pragma unroll
  for (int jj = 0; jj < 4; ++jj) {
    const int s = tid + 256 * jj;
    const float x = alg[(size_t)r * S_ + s];
    a[jj] = (mask[(size_t)b * S_ + s] != 0) ? x : -3.0e38f;
  }
  float m = fmaxf(fmaxf(a[0], a[1]), fmaxf(a[2], a[3]));
  red[tid] = m; __syncthreads();
  for (int st = 128; st > 0; st >>= 1) { if (tid < st) red[tid] = fmaxf(red[tid], red[tid + st]); __syncthreads(); }
  m = red[0]; __syncthreads();
  float e[4], lsum = 0.f;
#pragma unroll
  for (int jj = 0; jj < 4; ++jj) {
    e[jj] = (a[jj] > -1.0e38f) ? expf(a[jj] - m) : 0.f;
    lsum += e[jj];
  }
  red[tid] = lsum; __syncthreads();
  for (int st = 128; st > 0; st >>= 1) { if (tid < st) red[tid] += red[tid + st]; __syncthreads(); }
  const float rs = 1.f / red[0];
#pragma unroll
  for (int jj = 0; jj < 4; ++jj)
    attn[(size_t)r * S_ + tid + 256 * jj] = e[jj] * rs;
}

__global__ __launch_bounds__(256) void f5b_context(const float* __restrict__ attn, const u16* __restrict__ sbf,
                                                   float* __restrict__ ctx, float* __restrict__ out_at) {
  __shared__ float at[16][64];
  const int s0 = blockIdx.x * 64, t0 = blockIdx.y * 16, b = blockIdx.z;
  const int tid = threadIdx.x;
  for (int i = tid; i < 16 * 64; i += 256) {
    const int tl = i >> 6, sl = i & 63;
    at[tl][sl] = attn[(size_t)(b * T_ + t0 + tl) * S_ + s0 + sl];
  }
  __syncthreads();
  for (int i = tid; i < 64 * 16; i += 256) {
    const int sl = i >> 4, tl = i & 15;
    out_at[((size_t)b * S_ + s0 + sl) * T_ + t0 + tl] = at[tl][sl];
  }
  float acc[16][4] = {};
  for (int sl = 0; sl < 64; ++sl) {
    const u16* srow = sbf + ((size_t)b * S_ + s0 + sl) * D_ + tid;
    float sv[4];
#pragma unroll
    for (int jj = 0; jj < 4; ++jj) sv[jj] = bf2f(srow[256 * jj]);
#pragma unroll
    for (int tl = 0; tl < 16; ++tl) {
      const float w = at[tl][sl];
#pragma unroll
      for (int jj = 0; jj < 4; ++jj) acc[tl][jj] = fmaf(w, sv[jj], acc[tl][jj]);
    }
  }
#pragma unroll
  for (int tl = 0; tl < 16; ++tl)
#pragma unroll
    for (int jj = 0; jj < 4; ++jj)
      atomicAdd(&ctx[(size_t)(b * T_ + t0 + tl) * D_ + tid + 256 * jj], acc[tl][jj]);
}

__global__ __launch_bounds__(256) void f5_context(const float* __restrict__ attn, const float* __restrict__ states,
                                                  float* __restrict__ ctx, float* __restrict__ out_at) {
  __shared__ float at[16][64];
  const int s0 = blockIdx.x * 64, t0 = blockIdx.y * 16, b = blockIdx.z;
  const int tid = threadIdx.x;
  for (int i = tid; i < 16 * 64; i += 256) {
    const int tl = i >> 6, sl = i & 63;
    at[tl][sl] = attn[(size_t)(b * T_ + t0 + tl) * S_ + s0 + sl];
  }
  __syncthreads();
  for (int i = tid; i < 64 * 16; i += 256) {
    const int sl = i >> 4, tl = i & 15;
    out_at[((size_t)b * S_ + s0 + sl) * T_ + t0 + tl] = at[tl][sl];
  }
  float acc[16][4] = {};
  for (int sl = 0; sl < 64; ++sl) {
    const float* srow = states + ((size_t)b * S_ + s0 + sl) * D_ + tid;
    float sv[4];
#pragma unroll
    for (int jj = 0; jj < 4; ++jj) sv[jj] = srow[256 * jj];
#pragma unroll
    for (int tl = 0; tl < 16; ++tl) {
      const float w = at[tl][sl];
#pragma unroll
      for (int jj = 0; jj < 4; ++jj) acc[tl][jj] = fmaf(w, sv[jj], acc[tl][jj]);
    }
  }
#pragma unroll
  for (int tl = 0; tl < 16; ++tl)
#pragma unroll
    for (int jj = 0; jj < 4; ++jj)
      atomicAdd(&ctx[(size_t)(b * T_ + t0 + tl) * D_ + tid + 256 * jj], acc[tl][jj]);
}

// ================= FALLBACK (round-7, passing) =================

__global__ __launch_bounds__(256) void k1_qf(const float* __restrict__ query, const float* __restrict__ Wq,
                                             const float* __restrict__ bq, float* __restrict__ qf) {
  const int r = blockIdx.x;
  const int tid = threadIdx.x;
  __shared__ float q[H_];
  for (int i = tid; i < H_; i += 256) q[i] = query[(size_t)r * H_ + i];
  __syncthreads();
#pragma unroll
  for (int jj = 0; jj < 4; ++jj) {
    const int j = tid + 256 * jj;
    float acc = bq[j];
    for (int k = 0; k < H_; ++k) acc = fmaf(q[k], Wq[(size_t)k * D_ + j], acc);
    qf[(size_t)r * D_ + j] = acc;
  }
}

__global__ __launch_bounds__(256) void k23_align(const float* __restrict__ states, const float* __restrict__ Ws,
                                                 const float* __restrict__ v, const float* __restrict__ qf,
                                                 float* __restrict__ alg) {
  const int b = blockIdx.x >> 6;
  const int s0 = (blockIdx.x & 63) * 16;
  const int tid = threadIdx.x, lane = tid & 63, wv = tid >> 6;
  __shared__ u16 stL[16 * D_];
  __shared__ float vvL[D_];
  __shared__ float red[16 * 4];
  for (int i = tid; i < 16 * D_; i += 256) {
    const int row = i >> 10, col = i & (D_ - 1);
    stL[i] = f2bf(states[((size_t)b * S_ + s0 + row) * D_ + col]);
  }
  for (int i = tid; i < D_; i += 256) vvL[i] = v[i];
  __syncthreads();
  float acc[64];
#pragma unroll
  for (int i = 0; i < 64; ++i) acc[i] = 0.f;
#pragma unroll 4
  for (int k = 0; k < D_; ++k) {
    float wsv[4];
#pragma unroll
    for (int jj = 0; jj < 4; ++jj) wsv[jj] = Ws[(size_t)k * D_ + tid + 256 * jj];
#pragma unroll
    for (int i = 0; i < 16; ++i) {
      const float sv = bf2f(stL[i * D_ + k]);
#pragma unroll
      for (int jj = 0; jj < 4; ++jj) acc[i * 4 + jj] = fmaf(sv, wsv[jj], acc[i * 4 + jj]);
    }
  }
  for (int t = 0; t < T_; ++t) {
    float qv[4];
#pragma unroll
    for (int jj = 0; jj < 4; ++jj) qv[jj] = qf[((size_t)b * T_ + t) * D_ + tid + 256 * jj];
    float part[16];
#pragma unroll
    for (int i = 0; i < 16; ++i) {
      float p = 0.f;
#pragma unroll
      for (int jj = 0; jj < 4; ++jj)
        p = fmaf(vvL[tid + 256 * jj], tanhf(qv[jj] + acc[i * 4 + jj]), p);
      part[i] = p;
    }
#pragma unroll
    for (int i = 0; i < 16; ++i) {
      float x = part[i];
#pragma unroll
      for (int off = 32; off > 0; off >>= 1) x += __shfl_xor(x, off);
      if (lane == 0) red[i * 4 + wv] = x;
    }
    __syncthreads();
    if (tid < 16)
      alg[((size_t)b * T_ + t) * S_ + s0 + tid] =
          red[tid * 4 + 0] + red[tid * 4 + 1] + red[tid * 4 + 2] + red[tid * 4 + 3];
    __syncthreads();
  }
}

__global__ __launch_bounds__(256) void k4_softmax(const float* __restrict__ alg, const int* __restrict__ mask,
                                                  float* __restrict__ attn) {
  const int r = blockIdx.x;
  const int b = r >> 5;
  const int tid = threadIdx.x;
  __shared__ float red[256];
  float a[4];
#pragma unroll
  for (int jj = 0; jj < 4; ++jj) {
    const int s = tid + 256 * jj;
    const float x = alg[(size_t)r * S_ + s];
    a[jj] = (mask[(size_t)b * S_ + s] != 0) ? x : -3.0e38f;
  }
  float m = fmaxf(fmaxf(a[0], a[1]), fmaxf(a[2], a[3]));
  red[tid] = m; __syncthreads();
  for (int st = 128; st > 0; st >>= 1) { if (tid < st) red[tid] = fmaxf(red[tid], red[tid + st]); __syncthreads(); }
  m = red[0]; __syncthreads();
  float e[4], lsum = 0.f;
#pragma unroll
  for (int jj = 0; jj < 4; ++jj) {
    e[jj] = (a[jj] > -1.0e38f) ? expf(a[jj] - m) : 0.f;
    lsum += e[jj];
  }
  red[tid] = lsum; __syncthreads();
  for (int st = 128; st > 0; st >>= 1) { if (tid < st) red[tid] += red[tid + st]; __syncthreads(); }
  const float rs = 1.f / red[0];
#pragma unroll
  for (int jj = 0; jj < 4; ++jj)
    attn[(size_t)r * S_ + tid + 256 * jj] = e[jj] * rs;
}

__global__ __launch_bounds__(256) void k56_ctx_proj(const float* __restrict__ attn, const float* __restrict__ states,
                                                    const float* __restrict__ query, const float* __restrict__ Wc,
                                                    const float* __restrict__ bc,
                                                    float* __restrict__ out_ctx, float* __restrict__ out_hid,
                                                    float* __restrict__ out_at) {
  const int r = blockIdx.x;
  const int b = r >> 5, t = r & (T_ - 1);
  const int tid = threadIdx.x;
  __shared__ float pr[S_];
  __shared__ float cq[D_ + H_];
  for (int s = tid; s < S_; s += 256) pr[s] = attn[(size_t)r * S_ + s];
  __syncthreads();
  for (int s = tid; s < S_; s += 256) out_at[((size_t)b * S_ + s) * T_ + t] = pr[s];
  float acc[4] = {0.f, 0.f, 0.f, 0.f};
  for (int s = 0; s < S_; ++s) {
    const float w = pr[s];
    const float* srow = states + ((size_t)b * S_ + s) * D_ + tid;
#pragma unroll
    for (int jj = 0; jj < 4; ++jj) acc[jj] = fmaf(w, srow[256 * jj], acc[jj]);
  }
#pragma unroll
  for (int jj = 0; jj < 4; ++jj) {
    cq[tid + 256 * jj] = acc[jj];
    out_ctx[(size_t)r * D_ + tid + 256 * jj] = acc[jj];
  }
  for (int i = tid; i < H_; i += 256) cq[D_ + i] = query[(size_t)r * H_ + i];
  __syncthreads();
#pragma unroll
  for (int jj = 0; jj < 2; ++jj) {
    const int n = tid + 256 * jj;
    float h = bc[n];
    for (int k = 0; k < D_ + H_; ++k) h = fmaf(cq[k], Wc[(size_t)k * H_ + n], h);
    out_hid[(size_t)r * H_ + n] = h;
  }
}

extern "C" void kernel_launch(void* const* d_in, const int* in_sizes, int n_in,
                              void* d_out, int out_size, void* d_ws, size_t ws_size,
                              hipStream_t stream) {
  const float* query  = (const float*)d_in[0];
  const float* states = (const float*)d_in[1];
  const int*   mask   = (const int*)d_in[2];
  const float* Wq     = (const float*)d_in[3];
  const float* bq     = (const float*)d_in[4];
  const float* Ws     = (const float*)d_in[5];
  const float* v      = (const float*)d_in[6];
  const float* Wc     = (const float*)d_in[7];
  const float* bc     = (const float*)d_in[8];

  float* A  = (float*)d_out;               // qf -> ctx(final)
  float* Bh = A + (size_t)BT_ * D_;        // hidden
  float* C  = Bh + (size_t)BT_ * H_;       // attn_t (tier3) / alg->attn_t (tier1/2)

  char* ws = (char*)d_ws;
  u16*   sfb  = (u16*)(ws + 0);
  u16*   WsT  = (u16*)(ws + 8388608);
  float* alg  = (float*)(ws + 10485760);
  u16*   sbf  = (u16*)(ws + 11010048);
  u16*   sbfT = (u16*)(ws + 19398656);
  u16*   pbf  = (u16*)(ws + 27787264);

  const size_t WS_T1 = 11010048;
  const size_t WS_T2 = 19398656;
  const size_t WS_T3 = 28049408;

  if (ws_size >= WS_T3) {
    // ---------- tier 3 ----------
    (void)hipMemsetAsync(A, 0, (size_t)(BT_ * D_ + BT_ * H_) * 4, stream);  // qf + hidden zero
    kct_prep<<<2560, 256, 0, stream>>>(states, Ws, sbf, sbfT, WsT);
    f1b_qf<<<dim3(4, 16, 4), 256, 0, stream>>>(query, Wq, bq, A);
    f2c_sfgemm<<<dim3(16, 32), 256, 0, stream>>>(sbf, WsT, sfb);
    f3f_align<<<dim3(1024, 2), 256, 0, stream>>>(A, sfb, v, alg);
    f4b_softmax<<<BT_, 256, 0, stream>>>(alg, mask, C, pbf);
    f5c_context<<<64, 256, 0, stream>>>(pbf, sbfT, A);
    f6b_outproj<<<dim3(4, 8, 12), 256, 0, stream>>>(A, query, Wc, bc, Bh);
  } else if (ws_size >= WS_T1) {
    // ---------- tier 1/2 ----------
    float* attn = alg;
    (void)hipMemsetAsync(A, 0, (size_t)(BT_ * D_ + BT_ * H_) * 4, stream);
    f1b_qf<<<dim3(4, 16, 4), 256, 0, stream>>>(query, Wq, bq, A);
    f0_transpose<<<dim3(16, 32), 256, 0, stream>>>(Ws, WsT);
    const int tier2 = (ws_size >= WS_T2);
    if (tier2) {
      kc_cvt<<<2048, 256, 0, stream>>>(states, sbf);
      f2c_sfgemm<<<dim3(16, 32), 256, 0, stream>>>(sbf, WsT, sfb);
    } else {
      f2d_sfgemm<<<dim3(16, 32), 256, 0, stream>>>(states, WsT, sfb);
    }
    f3f_align<<<dim3(1024, 2), 256, 0, stream>>>(A, sfb, v, C);
    (void)hipMemsetAsync(A, 0, (size_t)BT_ * D_ * 4, stream);
    f4_softmax<<<BT_, 256, 0, stream>>>(C, mask, attn);
    if (tier2)
      f5b_context<<<dim3(16, 2, 4), 256, 0, stream>>>(attn, sbf, A, C);
    else
      f5_context<<<dim3(16, 2, 4), 256, 0, stream>>>(attn, states, A, C);
    f6b_outproj<<<dim3(4, 8, 12), 256, 0, stream>>>(A, query, Wc, bc, Bh);
  } else {
    // ---------- fallback ----------
    k1_qf<<<BT_, 256, 0, stream>>>(query, Wq, bq, A);
    k23_align<<<B_ * (S_ / 16), 256, 0, stream>>>(states, Ws, v, A, C);
    k4_softmax<<<BT_, 256, 0, stream>>>(C, mask, A);
    k56_ctx_proj<<<BT_, 256, 0, stream>>>(A, states, query, Wc, bc, A, Bh, C);
  }
}

// Round 15
// 186.083 us; speedup vs baseline: 3.9250x; 1.0408x over previous
//
#include <hip/hip_runtime.h>
#include <math.h>

// Bahdanau additive attention. B=4, T=32, S=1024, H=512, D=2H=1024.
// Inputs fp32 (mask int32), OUTPUT fp32 flat:
//   context (4,32,1024) | hidden (4,32,512) | attn_t (4,1024,32)
// Round 15: f2e = global_load_lds(16B) staging + BK=64 + XOR-swizzled LDS
// (bank-balanced); prep kernel fuses WsT + states-cvt/transpose + qf-GEMM.
// d_out overlay: A[0,131072): (memset)->qf -> ctx(final)
//                B[131072,196608): (memset)->hidden(final)
//                C[196608,327680): attn_t(final)

typedef unsigned short u16;
typedef __bf16 bf16x8 __attribute__((ext_vector_type(8)));
typedef float floatx4 __attribute__((ext_vector_type(4)));

#define B_ 4
#define T_ 32
#define S_ 1024
#define H_ 512
#define D_ 1024
#define BT_ 128
#define TWO_LOG2E 2.8853900817779268f   // tanh(y) = 1 - 2/(exp2(2*log2e*y)+1)

__device__ __forceinline__ float bf2f(u16 u) {
  unsigned int i = ((unsigned int)u) << 16;
  return __builtin_bit_cast(float, i);
}
__device__ __forceinline__ u16 f2bf(float f) {
  unsigned int i = __builtin_bit_cast(unsigned int, f);
  i += 0x7fffu + ((i >> 16) & 1u);  // RNE
  return (u16)(i >> 16);
}
__device__ __forceinline__ void ld_g2l_16(const u16* g, u16* l) {
  __builtin_amdgcn_global_load_lds((__attribute__((address_space(1))) void*)(u16*)g,
                                   (__attribute__((address_space(3))) void*)l, 16, 0, 0);
}

// ================= TIER-3 KERNELS =================

// ---- PREP (fused): [0,512) Ws^T -> WsT bf16; [512,2560) states -> sbf + sbfT;
//      [2560,2816) qf += 2log2e*(query_kslice @ Wq) (+bias on slice 0), split-K atomics.
__global__ __launch_bounds__(256) void prep_fused(const float* __restrict__ states, const float* __restrict__ Ws,
                                                  const float* __restrict__ query, const float* __restrict__ Wq,
                                                  const float* __restrict__ bq,
                                                  u16* __restrict__ sbf, u16* __restrict__ sbfT,
                                                  u16* __restrict__ WsT, float* __restrict__ qf) {
  __shared__ u16 tile[32][65];
  __shared__ float q[8][128];
  const int t = threadIdx.x;
  if (blockIdx.x < 512) {
    const int n0 = (blockIdx.x & 15) * 64, k0 = (blockIdx.x >> 4) * 32;
    const int kr = t >> 3, nc = (t & 7) * 8;
    const float* p = Ws + (size_t)(k0 + kr) * D_ + n0 + nc;
    float4 a = *(const float4*)p, b = *(const float4*)(p + 4);
    tile[kr][nc + 0] = f2bf(a.x); tile[kr][nc + 1] = f2bf(a.y);
    tile[kr][nc + 2] = f2bf(a.z); tile[kr][nc + 3] = f2bf(a.w);
    tile[kr][nc + 4] = f2bf(b.x); tile[kr][nc + 5] = f2bf(b.y);
    tile[kr][nc + 6] = f2bf(b.z); tile[kr][nc + 7] = f2bf(b.w);
    __syncthreads();
    const int nr = t >> 2, kc = (t & 3) * 8;
    union { uint4 v; u16 s[8]; } st;
#pragma unroll
    for (int i = 0; i < 8; ++i) st.s[i] = tile[kc + i][nr];
    *(uint4*)(WsT + (size_t)(n0 + nr) * D_ + k0 + kc) = st.v;
  } else if (blockIdx.x < 2560) {
    const int bid = blockIdx.x - 512;
    const int b = bid >> 9;
    const int r2 = bid & 511;
    const int d0 = (r2 & 15) * 64, s0 = (r2 >> 4) * 32;
    const int sr = t >> 3, dc = (t & 7) * 8;
    const float* p = states + ((size_t)b * S_ + s0 + sr) * D_ + d0 + dc;
    float4 a = *(const float4*)p, bb = *(const float4*)(p + 4);
    union { uint4 v; u16 s[8]; } pk;
    pk.s[0] = f2bf(a.x); pk.s[1] = f2bf(a.y); pk.s[2] = f2bf(a.z); pk.s[3] = f2bf(a.w);
    pk.s[4] = f2bf(bb.x); pk.s[5] = f2bf(bb.y); pk.s[6] = f2bf(bb.z); pk.s[7] = f2bf(bb.w);
    *(uint4*)(sbf + ((size_t)b * S_ + s0 + sr) * D_ + d0 + dc) = pk.v;
#pragma unroll
    for (int i = 0; i < 8; ++i) tile[sr][dc + i] = pk.s[i];
    __syncthreads();
    const int dr = t >> 2, sc = (t & 3) * 8;
    union { uint4 v; u16 s[8]; } st;
#pragma unroll
    for (int i = 0; i < 8; ++i) st.s[i] = tile[sc + i][dr];
    *(uint4*)(sbfT + ((size_t)b * D_ + d0 + dr) * S_ + s0 + sc) = st.v;
  } else {
    const int idx = blockIdx.x - 2560;            // 0..255
    const int c0 = (idx & 3) * 256, r0 = ((idx >> 2) & 15) * 8, k0 = (idx >> 6) * 128;
    for (int i = t; i < 8 * 128; i += 256) {
      const int rl = i >> 7, kk = i & 127;
      q[rl][kk] = query[(size_t)(r0 + rl) * H_ + k0 + kk];
    }
    __syncthreads();
    const int col = c0 + t;
    float acc[8] = {};
    for (int kk = 0; kk < 128; ++kk) {
      const float w = Wq[(size_t)(k0 + kk) * D_ + col];
#pragma unroll
      for (int r = 0; r < 8; ++r) acc[r] = fmaf(q[r][kk], w, acc[r]);
    }
    const float bb = (k0 == 0) ? bq[col] : 0.f;
#pragma unroll
    for (int r = 0; r < 8; ++r)
      atomicAdd(&qf[(size_t)(r0 + r) * D_ + col], TWO_LOG2E * (acc[r] + bb));
  }
}

// ---- F2e (tier3): sfb = 2log2e*(sbf @ Ws). global_load_lds 16B staging, BK=64,
// XOR-swizzled LDS (chunk c stored at c^(r&7)): bank-balanced reads. 512 blocks.
__global__ __launch_bounds__(256) void f2e_sfgemm(const u16* __restrict__ A, const u16* __restrict__ BT,
                                                  u16* __restrict__ Cb) {
  __shared__ __align__(16) u16 sA[128 * 64];   // 16 KB, row stride 64 u16
  __shared__ __align__(16) u16 sB[64 * 64];    // 8 KB
  const int bm0 = blockIdx.y * 128, bn0 = blockIdx.x * 64;
  const int t = threadIdx.x;
  const int wv = t >> 6, lane = t & 63;
  const int wm = (wv >> 1) * 64, wn = (wv & 1) * 32;
  const int fm = lane & 15, fq = lane >> 4;
  const int srow = lane >> 3, sp = lane & 7;   // staging: 8 rows x 8 chunks per inst

  floatx4 acc[4][2];
  const floatx4 fz = {0.f, 0.f, 0.f, 0.f};
#pragma unroll
  for (int i = 0; i < 4; ++i) { acc[i][0] = fz; acc[i][1] = fz; }

  for (int k0 = 0; k0 < D_; k0 += 64) {
    __syncthreads();                           // prev tile reads done
#pragma unroll
    for (int j = 0; j < 4; ++j) {              // A: rows wv*32 + j*8 + srow
      const int r = wv * 32 + j * 8 + srow;
      const int c = sp ^ (r & 7);
      ld_g2l_16(A + (size_t)(bm0 + r) * D_ + k0 + c * 8, &sA[(wv * 32 + j * 8) * 64]);
    }
#pragma unroll
    for (int j = 0; j < 2; ++j) {              // B: rows wv*16 + j*8 + srow
      const int r = wv * 16 + j * 8 + srow;
      const int c = sp ^ (r & 7);
      ld_g2l_16(BT + (size_t)(bn0 + r) * D_ + k0 + c * 8, &sB[(wv * 16 + j * 8) * 64]);
    }
    __syncthreads();                           // vmcnt(0) drains the async loads
#pragma unroll
    for (int win = 0; win < 2; ++win) {
      bf16x8 af[4], bfr[2];
#pragma unroll
      for (int i = 0; i < 4; ++i) {
        const int R = wm + i * 16 + fm;
        af[i] = *(const bf16x8*)&sA[R * 64 + ((win * 4 + fq) ^ (R & 7)) * 8];
      }
#pragma unroll
      for (int j = 0; j < 2; ++j) {
        const int R = wn + j * 16 + fm;
        bfr[j] = *(const bf16x8*)&sB[R * 64 + ((win * 4 + fq) ^ (R & 7)) * 8];
      }
#pragma unroll
      for (int i = 0; i < 4; ++i)
#pragma unroll
        for (int j = 0; j < 2; ++j)
          acc[i][j] = __builtin_amdgcn_mfma_f32_16x16x32_bf16(af[i], bfr[j], acc[i][j], 0, 0, 0);
    }
  }
#pragma unroll
  for (int i = 0; i < 4; ++i)
#pragma unroll
    for (int j = 0; j < 2; ++j)
#pragma unroll
      for (int r = 0; r < 4; ++r) {
        const int row = bm0 + wm + i * 16 + fq * 4 + r;   // col=lane&15, row=quad*4+reg (m89)
        const int col = bn0 + wn + j * 16 + fm;
        Cb[(size_t)row * D_ + col] = f2bf(TWO_LOG2E * acc[i][j][r]);
      }
}

// ---- F3f: alg = v . tanh(qf+sf). Wave per (b,s); t-half per blockIdx.y; batched butterfly. ----
__global__ __launch_bounds__(256, 6) void f3f_align(const float* __restrict__ qf, const u16* __restrict__ sfb,
                                                    const float* __restrict__ v, float* __restrict__ alg) {
  const int wid = (blockIdx.x * 256 + threadIdx.x) >> 6;  // b*1024+s
  const int lane = threadIdx.x & 63;
  const int b = wid >> 10, s = wid & 1023;
  const int t0 = blockIdx.y * 16;
  float vr[16], sr[16];
  {
    union { uint4 v[2]; u16 s[16]; } u;
    const uint4* sp = (const uint4*)(sfb + (size_t)wid * D_ + lane * 16);
    u.v[0] = sp[0]; u.v[1] = sp[1];
    const float* vp = v + lane * 16;
#pragma unroll
    for (int c = 0; c < 4; ++c) {
      float4 w = *(const float4*)(vp + 4 * c);
      vr[4 * c + 0] = w.x; vr[4 * c + 1] = w.y; vr[4 * c + 2] = w.z; vr[4 * c + 3] = w.w;
    }
#pragma unroll
    for (int j = 0; j < 16; ++j) sr[j] = bf2f(u.s[j]);
  }
  float sum[16];
#pragma unroll
  for (int tt = 0; tt < 16; ++tt) sum[tt] = 0.f;

  const float* qbase = qf + ((size_t)(b * T_ + t0)) * D_ + lane * 16;
  for (int tt = 0; tt < 16; ++tt) {
    const float4* qp = (const float4*)(qbase + (size_t)tt * D_);
    float acc = 0.f;
#pragma unroll
    for (int c = 0; c < 4; ++c) {
      float4 q4 = qp[c];
      float xs[4] = {q4.x, q4.y, q4.z, q4.w};
#pragma unroll
      for (int u2 = 0; u2 < 4; ++u2) {
        const int j = 4 * c + u2;
        const float x = xs[u2] + sr[j];                        // prescaled by 2log2e
        const float e = __builtin_amdgcn_exp2f(x);
        acc = fmaf(vr[j], fmaf(-2.f, __builtin_amdgcn_rcpf(e + 1.f), 1.f), acc);
      }
    }
    sum[tt] = acc;
  }
#pragma unroll
  for (int off = 32; off > 0; off >>= 1)
#pragma unroll
    for (int tt = 0; tt < 16; ++tt) sum[tt] += __shfl_xor(sum[tt], off);
  if (lane == 0) {
#pragma unroll
    for (int tt = 0; tt < 16; ++tt)
      alg[((size_t)(b * T_ + t0 + tt)) * S_ + s] = sum[tt];
  }
}

// ---- F4b: masked softmax; alg(ws) -> attn_t fp32 (C, final) + P bf16 (ws) ----
__global__ __launch_bounds__(256) void f4b_softmax(const float* __restrict__ alg, const int* __restrict__ mask,
                                                   float* __restrict__ out_at, u16* __restrict__ pbf) {
  const int r = blockIdx.x;                    // b*T+t
  const int b = r >> 5, t = r & 31;
  const int tid = threadIdx.x;
  __shared__ float red[256];
  float a[4];
#pragma unroll
  for (int jj = 0; jj < 4; ++jj) {
    const int s = tid + 256 * jj;
    const float x = alg[(size_t)r * S_ + s];
    a[jj] = (mask[(size_t)b * S_ + s] != 0) ? x : -3.0e38f;
  }
  float m = fmaxf(fmaxf(a[0], a[1]), fmaxf(a[2], a[3]));
  red[tid] = m; __syncthreads();
  for (int st = 128; st > 0; st >>= 1) { if (tid < st) red[tid] = fmaxf(red[tid], red[tid + st]); __syncthreads(); }
  m = red[0]; __syncthreads();
  float e[4], lsum = 0.f;
#pragma unroll
  for (int jj = 0; jj < 4; ++jj) {
    e[jj] = (a[jj] > -1.0e38f) ? expf(a[jj] - m) : 0.f;
    lsum += e[jj];
  }
  red[tid] = lsum; __syncthreads();
  for (int st = 128; st > 0; st >>= 1) { if (tid < st) red[tid] += red[tid + st]; __syncthreads(); }
  const float rs = 1.f / red[0];
#pragma unroll
  for (int jj = 0; jj < 4; ++jj) {
    const int s = tid + 256 * jj;
    const float p = e[jj] * rs;
    out_at[((size_t)b * S_ + s) * T_ + t] = p;
    pbf[(size_t)r * S_ + s] = f2bf(p);
  }
}

// ---- F5c: ctx = P @ states via pure-register MFMA. 64 blocks, no LDS/atomics. ----
__global__ __launch_bounds__(256) void f5c_context(const u16* __restrict__ pbf, const u16* __restrict__ sbfT,
                                                   float* __restrict__ ctx) {
  const int b = blockIdx.x >> 4, dt = blockIdx.x & 15;
  const int wv = threadIdx.x >> 6, lane = threadIdx.x & 63;
  const int n0 = dt * 64 + wv * 16;
  const int fm = lane & 15, fq = lane >> 4;
  const floatx4 fz = {0.f, 0.f, 0.f, 0.f};
  floatx4 acc0 = fz, acc1 = fz;
  const u16* pa0 = pbf + ((size_t)b * T_ + fm) * S_ + fq * 8;
  const u16* pa1 = pbf + ((size_t)b * T_ + 16 + fm) * S_ + fq * 8;
  const u16* pb  = sbfT + ((size_t)b * D_ + n0 + fm) * S_ + fq * 8;
#pragma unroll 4
  for (int k0 = 0; k0 < S_; k0 += 32) {
    bf16x8 a0 = *(const bf16x8*)(pa0 + k0);
    bf16x8 a1 = *(const bf16x8*)(pa1 + k0);
    bf16x8 bb = *(const bf16x8*)(pb + k0);
    acc0 = __builtin_amdgcn_mfma_f32_16x16x32_bf16(a0, bb, acc0, 0, 0, 0);
    acc1 = __builtin_amdgcn_mfma_f32_16x16x32_bf16(a1, bb, acc1, 0, 0, 0);
  }
  const int col = n0 + fm;
#pragma unroll
  for (int r = 0; r < 4; ++r) {
    ctx[((size_t)b * T_ + fq * 4 + r) * D_ + col] = acc0[r];
    ctx[((size_t)b * T_ + 16 + fq * 4 + r) * D_ + col] = acc1[r];
  }
}

// ---- F6b: hidden += [ctx, query]_kslice @ Wc (+bc on slice 0). Split-K atomics. ----
__global__ __launch_bounds__(256) void f6b_outproj(const float* __restrict__ ctx, const float* __restrict__ query,
                                                   const float* __restrict__ Wc, const float* __restrict__ bc,
                                                   float* __restrict__ out_hid) {
  __shared__ float cq[16][128];
  const int c0 = blockIdx.x * 128, r0 = blockIdx.y * 16, k0 = blockIdx.z * 128;
  const int tid = threadIdx.x;
  const int cl = tid & 127, rh = tid >> 7;
  for (int i = tid; i < 16 * 128; i += 256) {
    const int rl = i >> 7, kk = i & 127;
    const int k = k0 + kk, row = r0 + rl;
    cq[rl][kk] = (k < D_) ? ctx[(size_t)row * D_ + k] : query[(size_t)row * H_ + k - D_];
  }
  __syncthreads();
  float acc[8] = {};
  for (int kk = 0; kk < 128; ++kk) {
    const float w = Wc[(size_t)(k0 + kk) * H_ + c0 + cl];
#pragma unroll
    for (int rr = 0; rr < 8; ++rr) acc[rr] = fmaf(cq[rh * 8 + rr][kk], w, acc[rr]);
  }
  const float bb = (blockIdx.z == 0) ? bc[c0 + cl] : 0.f;
#pragma unroll
  for (int rr = 0; rr < 8; ++rr)
    atomicAdd(&out_hid[(size_t)(r0 + rh * 8 + rr) * H_ + c0 + cl], acc[rr] + bb);
}

// ================= TIER-1/2 EXTRAS =================

__global__ __launch_bounds__(256) void kc_cvt(const float* __restrict__ in, u16* __restrict__ out) {
  const size_t i0 = ((size_t)blockIdx.x * 256 + threadIdx.x) * 8;
  float4 a = *(const float4*)(in + i0);
  float4 b = *(const float4*)(in + i0 + 4);
  union { uint4 v; u16 s[8]; } r;
  r.s[0] = f2bf(a.x); r.s[1] = f2bf(a.y); r.s[2] = f2bf(a.z); r.s[3] = f2bf(a.w);
  r.s[4] = f2bf(b.x); r.s[5] = f2bf(b.y); r.s[6] = f2bf(b.z); r.s[7] = f2bf(b.w);
  *(uint4*)(out + i0) = r.v;
}

__global__ __launch_bounds__(256) void f0_transpose(const float* __restrict__ Ws, u16* __restrict__ WsT) {
  __shared__ u16 tile[32][65];
  const int n0 = blockIdx.x * 64, k0 = blockIdx.y * 32;
  const int t = threadIdx.x;
  {
    const int kr = t >> 3, nc = (t & 7) * 8;
    const float* p = Ws + (size_t)(k0 + kr) * D_ + n0 + nc;
    float4 a = *(const float4*)p, b = *(const float4*)(p + 4);
    tile[kr][nc + 0] = f2bf(a.x); tile[kr][nc + 1] = f2bf(a.y);
    tile[kr][nc + 2] = f2bf(a.z); tile[kr][nc + 3] = f2bf(a.w);
    tile[kr][nc + 4] = f2bf(b.x); tile[kr][nc + 5] = f2bf(b.y);
    tile[kr][nc + 6] = f2bf(b.z); tile[kr][nc + 7] = f2bf(b.w);
  }
  __syncthreads();
  {
    const int nr = t >> 2, kc = (t & 3) * 8;
    union { uint4 v; u16 s[8]; } st;
#pragma unroll
    for (int i = 0; i < 8; ++i) st.s[i] = tile[kc + i][nr];
    *(uint4*)(WsT + (size_t)(n0 + nr) * D_ + k0 + kc) = st.v;
  }
}

__global__ __launch_bounds__(256) void f1b_qf(const float* __restrict__ query, const float* __restrict__ Wq,
                                              const float* __restrict__ bq, float* __restrict__ qf) {
  __shared__ float q[8][128];
  const int c0 = blockIdx.x * 256, r0 = blockIdx.y * 8, k0 = blockIdx.z * 128;
  const int tid = threadIdx.x;
  for (int i = tid; i < 8 * 128; i += 256) {
    const int rl = i >> 7, kk = i & 127;
    q[rl][kk] = query[(size_t)(r0 + rl) * H_ + k0 + kk];
  }
  __syncthreads();
  const int col = c0 + tid;
  float acc[8] = {};
  for (int kk = 0; kk < 128; ++kk) {
    const float w = Wq[(size_t)(k0 + kk) * D_ + col];
#pragma unroll
    for (int r = 0; r < 8; ++r) acc[r] = fmaf(q[r][kk], w, acc[r]);
  }
  const float bb = (blockIdx.z == 0) ? bq[col] : 0.f;
#pragma unroll
  for (int r = 0; r < 8; ++r)
    atomicAdd(&qf[(size_t)(r0 + r) * D_ + col], TWO_LOG2E * (acc[r] + bb));
}

__global__ __launch_bounds__(256) void f2c_sfgemm(const u16* __restrict__ A, const u16* __restrict__ BT,
                                                  u16* __restrict__ Cb) {
  __shared__ __align__(16) u16 sA[128 * 40];
  __shared__ __align__(16) u16 sB[64 * 40];
  const int bm0 = blockIdx.y * 128, bn0 = blockIdx.x * 64;
  const int t = threadIdx.x;
  const int wv = t >> 6, lane = t & 63;
  const int wm = (wv >> 1) * 64, wn = (wv & 1) * 32;
  const int fm = lane & 15, fq = lane >> 4;
  const int arow = t >> 1, akc = (t & 1) * 16;
  const int brow = t >> 2, bkc = (t & 3) * 8;
  floatx4 acc[4][2];
  const floatx4 fz = {0.f, 0.f, 0.f, 0.f};
#pragma unroll
  for (int i = 0; i < 4; ++i) { acc[i][0] = fz; acc[i][1] = fz; }
  const uint4* gA = (const uint4*)(A + (size_t)(bm0 + arow) * D_ + akc);
  const uint4* gB = (const uint4*)(BT + (size_t)(bn0 + brow) * D_ + bkc);
  for (int k0 = 0; k0 < D_; k0 += 32) {
    uint4 va0 = gA[k0 >> 3];
    uint4 va1 = gA[(k0 >> 3) + 1];
    uint4 vb = gB[k0 >> 3];
    __syncthreads();
    *(uint4*)&sA[arow * 40 + akc] = va0;
    *(uint4*)&sA[arow * 40 + akc + 8] = va1;
    *(uint4*)&sB[brow * 40 + bkc] = vb;
    __syncthreads();
    bf16x8 af[4], bfr[2];
#pragma unroll
    for (int i = 0; i < 4; ++i) af[i] = *(const bf16x8*)&sA[(wm + i * 16 + fm) * 40 + fq * 8];
#pragma unroll
    for (int j = 0; j < 2; ++j) bfr[j] = *(const bf16x8*)&sB[(wn + j * 16 + fm) * 40 + fq * 8];
#pragma unroll
    for (int i = 0; i < 4; ++i)
#pragma unroll
      for (int j = 0; j < 2; ++j)
        acc[i][j] = __builtin_amdgcn_mfma_f32_16x16x32_bf16(af[i], bfr[j], acc[i][j], 0, 0, 0);
  }
#pragma unroll
  for (int i = 0; i < 4; ++i)
#pragma unroll
    for (int j = 0; j < 2; ++j)
#pragma unroll
      for (int r = 0; r < 4; ++r) {
        const int row = bm0 + wm + i * 16 + fq * 4 + r;
        const int col = bn0 + wn + j * 16 + fm;
        Cb[(size_t)row * D_ + col] = f2bf(TWO_LOG2E * acc[i][j][r]);
      }
}

__global__ __launch_bounds__(256) void f2d_sfgemm(const float* __restrict__ A, const u16* __restrict__ BT,
                                                  u16* __restrict__ Cb) {
  __shared__ __align__(16) u16 sA[128 * 40];
  __shared__ __align__(16) u16 sB[64 * 40];
  const int bm0 = blockIdx.y * 128, bn0 = blockIdx.x * 64;
  const int t = threadIdx.x;
  const int wv = t >> 6, lane = t & 63;
  const int wm = (wv >> 1) * 64, wn = (wv & 1) * 32;
  const int fm = lane & 15, fq = lane >> 4;
  const int arow = t >> 1, akc = (t & 1) * 16;
  const int brow = t >> 2, bkc = (t & 3) * 8;
  floatx4 acc[4][2];
  const floatx4 fz = {0.f, 0.f, 0.f, 0.f};
#pragma unroll
  for (int i = 0; i < 4; ++i) { acc[i][0] = fz; acc[i][1] = fz; }
  const float* gA = A + (size_t)(bm0 + arow) * D_ + akc;
  const uint4* gB = (const uint4*)(BT + (size_t)(bn0 + brow) * D_ + bkc);
  for (int k0 = 0; k0 < D_; k0 += 32) {
    float4 a0 = *(const float4*)(gA + k0);
    float4 a1 = *(const float4*)(gA + k0 + 4);
    float4 a2 = *(const float4*)(gA + k0 + 8);
    float4 a3 = *(const float4*)(gA + k0 + 12);
    uint4 vb = gB[k0 >> 3];
    union { uint4 v[2]; u16 s[16]; } pa;
    pa.s[0] = f2bf(a0.x); pa.s[1] = f2bf(a0.y); pa.s[2] = f2bf(a0.z); pa.s[3] = f2bf(a0.w);
    pa.s[4] = f2bf(a1.x); pa.s[5] = f2bf(a1.y); pa.s[6] = f2bf(a1.z); pa.s[7] = f2bf(a1.w);
    pa.s[8] = f2bf(a2.x); pa.s[9] = f2bf(a2.y); pa.s[10] = f2bf(a2.z); pa.s[11] = f2bf(a2.w);
    pa.s[12] = f2bf(a3.x); pa.s[13] = f2bf(a3.y); pa.s[14] = f2bf(a3.z); pa.s[15] = f2bf(a3.w);
    __syncthreads();
    *(uint4*)&sA[arow * 40 + akc] = pa.v[0];
    *(uint4*)&sA[arow * 40 + akc + 8] = pa.v[1];
    *(uint4*)&sB[brow * 40 + bkc] = vb;
    __syncthreads();
    bf16x8 af[4], bfr[2];
#pragma unroll
    for (int i = 0; i < 4; ++i) af[i] = *(const bf16x8*)&sA[(wm + i * 16 + fm) * 40 + fq * 8];
#pragma unroll
    for (int j = 0; j < 2; ++j) bfr[j] = *(const bf16x8*)&sB[(wn + j * 16 + fm) * 40 + fq * 8];
#pragma unroll
    for (int i = 0; i < 4; ++i)
#pragma unroll
      for (int j = 0; j < 2; ++j)
        acc[i][j] = __builtin_amdgcn_mfma_f32_16x16x32_bf16(af[i], bfr[j], acc[i][j], 0, 0, 0);
  }
#pragma unroll
  for (int i = 0; i < 4; ++i)
#pragma unroll
    for (int j = 0; j < 2; ++j)
#pragma unroll
      for (int r = 0; r < 4; ++r) {
        const int row = bm0 + wm + i * 16 + fq * 4 + r;
        const int col = bn0 + wn + j * 16 + fm;
        Cb[(size_t)row * D_ + col] = f2bf(TWO_LOG2E * acc[i][j][r]);
      }
}

__global__ __launch_bounds__(256) void f4_softmax(const float* __restrict__ alg, const int* __restrict__ mask,
                                                  float* __restrict__ attn) {
  const int r = blockIdx.x;
  const int b = r >> 5;
  const int tid = threadIdx.x;
  __shared__ float red[256];
  float a[4];
#pragma unroll
  for (int jj = 0; jj < 4; ++jj) {
    const int s = tid + 256 * jj;
    const float x = alg[(size_t)r * S_ + s];
    a[jj] = (mask[(size_t)b * S_ + s] != 0) ? x : -3.0e38f;
  }
  float m = fmaxf(fmaxf(a[0], a[1]), fmaxf(a[2], a[3]));
  red[tid] = m; __syncthreads();
  for (int st = 128; st > 0; st >>= 1) { if (tid < st) red[tid] = fmaxf(red[tid], red[tid + st]); __syncthreads(); }
  m = red[0]; __syncthreads();
  float e[4], lsum = 0.f;
#pragma unroll
  for (int jj = 0; jj < 4; ++jj) {
    e[jj] = (a[jj] > -1.0e38f) ? expf(a[jj] - m) : 0.f;
    lsum += e[jj];
  }
  red[tid] = lsum; __syncthreads();
  for (int st = 128; st > 0; st >>= 1) { if (tid < st) red[tid] += red[tid + st]; __syncthreads(); }
  const float rs = 1.f / red[0];
#pragma unroll
  for (int jj = 0; jj < 4; ++jj)
    attn[(size_t)r * S_ + tid + 256 * jj] = e[jj] * rs;
}

__global__ __launch_bounds__(256) void f5b_context(const float* __restrict__ attn, const u16* __restrict__ sbf,
                                                   float* __restrict__ ctx, float* __restrict__ out_at) {
  __shared__ float at[16][64];
  const int s0 = blockIdx.x * 64, t0 = blockIdx.y * 16, b = blockIdx.z;
  const int tid = threadIdx.x;
  for (int i = tid; i < 16 * 64; i += 256) {
    const int tl = i >> 6, sl = i & 63;
    at[tl][sl] = attn[(size_t)(b * T_ + t0 + tl) * S_ + s0 + sl];
  }
  __syncthreads();
  for (int i = tid; i < 64 * 16; i += 256) {
    const int sl = i >> 4, tl = i & 15;
    out_at[((size_t)b * S_ + s0 + sl) * T_ + t0 + tl] = at[tl][sl];
  }
  float acc[16][4] = {};
  for (int sl = 0; sl < 64; ++sl) {
    const u16* srow = sbf + ((size_t)b * S_ + s0 + sl) * D_ + tid;
    float sv[4];
#pragma unroll
    for (int jj = 0; jj < 4; ++jj) sv[jj] = bf2f(srow[256 * jj]);
#pragma unroll
    for (int tl = 0; tl < 16; ++tl) {
      const float w = at[tl][sl];
#pragma unroll
      for (int jj = 0; jj < 4; ++jj) acc[tl][jj] = fmaf(w, sv[jj], acc[tl][jj]);
    }
  }
#pragma unroll
  for (int tl = 0; tl < 16; ++tl)
#pragma unroll
    for (int jj = 0; jj < 4; ++jj)
      atomicAdd(&ctx[(size_t)(b * T_ + t0 + tl) * D_ + tid + 256 * jj], acc[tl][jj]);
}

__global__ __launch_bounds__(256) void f5_context(const float* __restrict__ attn, const float* __restrict__ states,
                                                  float* __restrict__ ctx, float* __restrict__ out_at) {
  __shared__ float at[16][64];
  const int s0 = blockIdx.x * 64, t0 = blockIdx.y * 16, b = blockIdx.z;
  const int tid = threadIdx.x;
  for (int i = tid; i < 16 * 64; i += 256) {
    const int tl = i >> 6, sl = i & 63;
    at[tl][sl] = attn[(size_t)(b * T_ + t0 + tl) * S_ + s0 + sl];
  }
  __syncthreads();
  for (int i = tid; i < 64 * 16; i += 256) {
    const int sl = i >> 4, tl = i & 15;
    out_at[((size_t)b * S_ + s0 + sl) * T_ + t0 + tl] = at[tl][sl];
  }
  float acc[16][4] = {};
  for (int sl = 0; sl < 64; ++sl) {
    const float* srow = states + ((size_t)b * S_ + s0 + sl) * D_ + tid;
    float sv[4];
#pragma unroll
    for (int jj = 0; jj < 4; ++jj) sv[jj] = srow[256 * jj];
#pragma unroll
    for (int tl = 0; tl < 16; ++tl) {
      const float w = at[tl][sl];
#pragma unroll
      for (int jj = 0; jj < 4; ++jj) acc[tl][jj] = fmaf(w, sv[jj], acc[tl][jj]);
    }
  }
#pragma unroll
  for (int tl = 0; tl < 16; ++tl)
#pragma unroll
    for (int jj = 0; jj < 4; ++jj)
      atomicAdd(&ctx[(size_t)(b * T_ + t0 + tl) * D_ + tid + 256 * jj], acc[tl][jj]);
}

// ================= FALLBACK (round-7, passing) =================

__global__ __launch_bounds__(256) void k1_qf(const float* __restrict__ query, const float* __restrict__ Wq,
                                             const float* __restrict__ bq, float* __restrict__ qf) {
  const int r = blockIdx.x;
  const int tid = threadIdx.x;
  __shared__ float q[H_];
  for (int i = tid; i < H_; i += 256) q[i] = query[(size_t)r * H_ + i];
  __syncthreads();
#pragma unroll
  for (int jj = 0; jj < 4; ++jj) {
    const int j = tid + 256 * jj;
    float acc = bq[j];
    for (int k = 0; k < H_; ++k) acc = fmaf(q[k], Wq[(size_t)k * D_ + j], acc);
    qf[(size_t)r * D_ + j] = acc;
  }
}

__global__ __launch_bounds__(256) void k23_align(const float* __restrict__ states, const float* __restrict__ Ws,
                                                 const float* __restrict__ v, const float* __restrict__ qf,
                                                 float* __restrict__ alg) {
  const int b = blockIdx.x >> 6;
  const int s0 = (blockIdx.x & 63) * 16;
  const int tid = threadIdx.x, lane = tid & 63, wv = tid >> 6;
  __shared__ u16 stL[16 * D_];
  __shared__ float vvL[D_];
  __shared__ float red[16 * 4];
  for (int i = tid; i < 16 * D_; i += 256) {
    const int row = i >> 10, col = i & (D_ - 1);
    stL[i] = f2bf(states[((size_t)b * S_ + s0 + row) * D_ + col]);
  }
  for (int i = tid; i < D_; i += 256) vvL[i] = v[i];
  __syncthreads();
  float acc[64];
#pragma unroll
  for (int i = 0; i < 64; ++i) acc[i] = 0.f;
#pragma unroll 4
  for (int k = 0; k < D_; ++k) {
    float wsv[4];
#pragma unroll
    for (int jj = 0; jj < 4; ++jj) wsv[jj] = Ws[(size_t)k * D_ + tid + 256 * jj];
#pragma unroll
    for (int i = 0; i < 16; ++i) {
      const float sv = bf2f(stL[i * D_ + k]);
#pragma unroll
      for (int jj = 0; jj < 4; ++jj) acc[i * 4 + jj] = fmaf(sv, wsv[jj], acc[i * 4 + jj]);
    }
  }
  for (int t = 0; t < T_; ++t) {
    float qv[4];
#pragma unroll
    for (int jj = 0; jj < 4; ++jj) qv[jj] = qf[((size_t)b * T_ + t) * D_ + tid + 256 * jj];
    float part[16];
#pragma unroll
    for (int i = 0; i < 16; ++i) {
      float p = 0.f;
#pragma unroll
      for (int jj = 0; jj < 4; ++jj)
        p = fmaf(vvL[tid + 256 * jj], tanhf(qv[jj] + acc[i * 4 + jj]), p);
      part[i] = p;
    }
#pragma unroll
    for (int i = 0; i < 16; ++i) {
      float x = part[i];
#pragma unroll
      for (int off = 32; off > 0; off >>= 1) x += __shfl_xor(x, off);
      if (lane == 0) red[i * 4 + wv] = x;
    }
    __syncthreads();
    if (tid < 16)
      alg[((size_t)b * T_ + t) * S_ + s0 + tid] =
          red[tid * 4 + 0] + red[tid * 4 + 1] + red[tid * 4 + 2] + red[tid * 4 + 3];
    __syncthreads();
  }
}

__global__ __launch_bounds__(256) void k4_softmax(const float* __restrict__ alg, const int* __restrict__ mask,
                                                  float* __restrict__ attn) {
  const int r = blockIdx.x;
  const int b = r >> 5;
  const int tid = threadIdx.x;
  __shared__ float red[256];
  float a[4];
#pragma unroll
  for (int jj = 0; jj < 4; ++jj) {
    const int s = tid + 256 * jj;
    const float x = alg[(size_t)r * S_ + s];
    a[jj] = (mask[(size_t)b * S_ + s] != 0) ? x : -3.0e38f;
  }
  float m = fmaxf(fmaxf(a[0], a[1]), fmaxf(a[2], a[3]));
  red[tid] = m; __syncthreads();
  for (int st = 128; st > 0; st >>= 1) { if (tid < st) red[tid] = fmaxf(red[tid], red[tid + st]); __syncthreads(); }
  m = red[0]; __syncthreads();
  float e[4], lsum = 0.f;
#pragma unroll
  for (int jj = 0; jj < 4; ++jj) {
    e[jj] = (a[jj] > -1.0e38f) ? expf(a[jj] - m) : 0.f;
    lsum += e[jj];
  }
  red[tid] = lsum; __syncthreads();
  for (int st = 128; st > 0; st >>= 1) { if (tid < st) red[tid] += red[tid + st]; __syncthreads(); }
  const float rs = 1.f / red[0];
#pragma unroll
  for (int jj = 0; jj < 4; ++jj)
    attn[(size_t)r * S_ + tid + 256 * jj] = e[jj] * rs;
}

__global__ __launch_bounds__(256) void k56_ctx_proj(const float* __restrict__ attn, const float* __restrict__ states,
                                                    const float* __restrict__ query, const float* __restrict__ Wc,
                                                    const float* __restrict__ bc,
                                                    float* __restrict__ out_ctx, float* __restrict__ out_hid,
                                                    float* __restrict__ out_at) {
  const int r = blockIdx.x;
  const int b = r >> 5, t = r & (T_ - 1);
  const int tid = threadIdx.x;
  __shared__ float pr[S_];
  __shared__ float cq[D_ + H_];
  for (int s = tid; s < S_; s += 256) pr[s] = attn[(size_t)r * S_ + s];
  __syncthreads();
  for (int s = tid; s < S_; s += 256) out_at[((size_t)b * S_ + s) * T_ + t] = pr[s];
  float acc[4] = {0.f, 0.f, 0.f, 0.f};
  for (int s = 0; s < S_; ++s) {
    const float w = pr[s];
    const float* srow = states + ((size_t)b * S_ + s) * D_ + tid;
#pragma unroll
    for (int jj = 0; jj < 4; ++jj) acc[jj] = fmaf(w, srow[256 * jj], acc[jj]);
  }
#pragma unroll
  for (int jj = 0; jj < 4; ++jj) {
    cq[tid + 256 * jj] = acc[jj];
    out_ctx[(size_t)r * D_ + tid + 256 * jj] = acc[jj];
  }
  for (int i = tid; i < H_; i += 256) cq[D_ + i] = query[(size_t)r * H_ + i];
  __syncthreads();
#pragma unroll
  for (int jj = 0; jj < 2; ++jj) {
    const int n = tid + 256 * jj;
    float h = bc[n];
    for (int k = 0; k < D_ + H_; ++k) h = fmaf(cq[k], Wc[(size_t)k * H_ + n], h);
    out_hid[(size_t)r * H_ + n] = h;
  }
}

extern "C" void kernel_launch(void* const* d_in, const int* in_sizes, int n_in,
                              void* d_out, int out_size, void* d_ws, size_t ws_size,
                              hipStream_t stream) {
  const float* query  = (const float*)d_in[0];
  const float* states = (const float*)d_in[1];
  const int*   mask   = (const int*)d_in[2];
  const float* Wq     = (const float*)d_in[3];
  const float* bq     = (const float*)d_in[4];
  const float* Ws     = (const float*)d_in[5];
  const float* v      = (const float*)d_in[6];
  const float* Wc     = (const float*)d_in[7];
  const float* bc     = (const float*)d_in[8];

  float* A  = (float*)d_out;               // qf -> ctx(final)
  float* Bh = A + (size_t)BT_ * D_;        // hidden
  float* C  = Bh + (size_t)BT_ * H_;       // attn_t (tier3) / alg->attn_t (tier1/2)

  char* ws = (char*)d_ws;
  u16*   sfb  = (u16*)(ws + 0);
  u16*   WsT  = (u16*)(ws + 8388608);
  float* alg  = (float*)(ws + 10485760);
  u16*   sbf  = (u16*)(ws + 11010048);
  u16*   sbfT = (u16*)(ws + 19398656);
  u16*   pbf  = (u16*)(ws + 27787264);

  const size_t WS_T1 = 11010048;
  const size_t WS_T2 = 19398656;
  const size_t WS_T3 = 28049408;

  if (ws_size >= WS_T3) {
    // ---------- tier 3 ----------
    (void)hipMemsetAsync(A, 0, (size_t)(BT_ * D_ + BT_ * H_) * 4, stream);  // qf + hidden zero
    prep_fused<<<2816, 256, 0, stream>>>(states, Ws, query, Wq, bq, sbf, sbfT, WsT, A);
    f2e_sfgemm<<<dim3(16, 32), 256, 0, stream>>>(sbf, WsT, sfb);
    f3f_align<<<dim3(1024, 2), 256, 0, stream>>>(A, sfb, v, alg);
    f4b_softmax<<<BT_, 256, 0, stream>>>(alg, mask, C, pbf);
    f5c_context<<<64, 256, 0, stream>>>(pbf, sbfT, A);
    f6b_outproj<<<dim3(4, 8, 12), 256, 0, stream>>>(A, query, Wc, bc, Bh);
  } else if (ws_size >= WS_T1) {
    // ---------- tier 1/2 ----------
    float* attn = alg;
    (void)hipMemsetAsync(A, 0, (size_t)(BT_ * D_ + BT_ * H_) * 4, stream);
    f1b_qf<<<dim3(4, 16, 4), 256, 0, stream>>>(query, Wq, bq, A);
    f0_transpose<<<dim3(16, 32), 256, 0, stream>>>(Ws, WsT);
    const int tier2 = (ws_size >= WS_T2);
    if (tier2) {
      kc_cvt<<<2048, 256, 0, stream>>>(states, sbf);
      f2c_sfgemm<<<dim3(16, 32), 256, 0, stream>>>(sbf, WsT, sfb);
    } else {
      f2d_sfgemm<<<dim3(16, 32), 256, 0, stream>>>(states, WsT, sfb);
    }
    f3f_align<<<dim3(1024, 2), 256, 0, stream>>>(A, sfb, v, C);
    (void)hipMemsetAsync(A, 0, (size_t)BT_ * D_ * 4, stream);
    f4_softmax<<<BT_, 256, 0, stream>>>(C, mask, attn);
    if (tier2)
      f5b_context<<<dim3(16, 2, 4), 256, 0, stream>>>(attn, sbf, A, C);
    else
      f5_context<<<dim3(16, 2, 4), 256, 0, stream>>>(attn, states, A, C);
    f6b_outproj<<<dim3(4, 8, 12), 256, 0, stream>>>(A, query, Wc, bc, Bh);
  } else {
    // ---------- fallback ----------
    k1_qf<<<BT_, 256, 0, stream>>>(query, Wq, bq, A);
    k23_align<<<B_ * (S_ / 16), 256, 0, stream>>>(states, Ws, v, A, C);
    k4_softmax<<<BT_, 256, 0, stream>>>(C, mask, A);
    k56_ctx_proj<<<BT_, 256, 0, stream>>>(A, states, query, Wc, bc, A, Bh, C);
  }
}